// Round 2
// baseline (1980.033 us; speedup 1.0000x reference)
//
#include <hip/hip_runtime.h>
#include <math.h>

// Problem constants
namespace {
constexpr int Bn   = 8;
constexpr int CIN  = 32;
constexpr int CI   = 16;
constexpr int Lp   = 961;     // 31*31 patches
constexpr int FIN  = 784;     // 16*49
constexpr int FOUT = 196;
constexpr int F62  = 1568;    // 32*49
}

// ---------------------------------------------------------------------------
// 3x3 conv with reflect-pad(1). 32 in-ch -> 16 out-ch.
// DUAL: compute two convs (g and w) reading input once.
// ---------------------------------------------------------------------------
template<bool DUAL, bool BIAS, bool LEAKY>
__global__ __launch_bounds__(256)
void conv3x3_k(const float* __restrict__ x,
               const float* __restrict__ w1, const float* __restrict__ b1,
               const float* __restrict__ w2, const float* __restrict__ b2,
               float* __restrict__ o1, float* __restrict__ o2)
{
    int idx = blockIdx.x * 256 + threadIdx.x;     // B*16*128*128 exact
    int wc = idx & 127;
    int hr = (idx >> 7) & 127;
    int co = (idx >> 14) & 15;
    int b  = idx >> 18;
    int hm = (hr == 0)   ? 1   : hr - 1;
    int hp = (hr == 127) ? 126 : hr + 1;
    int wm = (wc == 0)   ? 1   : wc - 1;
    int wp = (wc == 127) ? 126 : wc + 1;
    float acc1 = BIAS ? b1[co] : 0.0f;
    float acc2 = 0.0f;
    if constexpr (DUAL) acc2 = b2[co];
    const float* xb  = x + (size_t)b * CIN * 16384;
    const float* w1c = w1 + co * CIN * 9;
    const float* w2c = DUAL ? (w2 + co * CIN * 9) : nullptr;
    #pragma unroll 4
    for (int ci = 0; ci < CIN; ++ci) {
        const float* xc = xb + ci * 16384;
        float v00 = xc[hm*128+wm], v01 = xc[hm*128+wc], v02 = xc[hm*128+wp];
        float v10 = xc[hr*128+wm], v11 = xc[hr*128+wc], v12 = xc[hr*128+wp];
        float v20 = xc[hp*128+wm], v21 = xc[hp*128+wc], v22 = xc[hp*128+wp];
        const float* q1 = w1c + ci * 9;
        acc1 += v00*q1[0] + v01*q1[1] + v02*q1[2]
              + v10*q1[3] + v11*q1[4] + v12*q1[5]
              + v20*q1[6] + v21*q1[7] + v22*q1[8];
        if constexpr (DUAL) {
            const float* q2 = w2c + ci * 9;
            acc2 += v00*q2[0] + v01*q2[1] + v02*q2[2]
                  + v10*q2[3] + v11*q2[4] + v12*q2[5]
                  + v20*q2[6] + v21*q2[7] + v22*q2[8];
        }
    }
    if constexpr (LEAKY) acc1 = (acc1 >= 0.0f) ? acc1 : 0.2f * acc1;
    o1[idx] = acc1;
    if constexpr (DUAL) o2[idx] = acc2;
}

// ---------------------------------------------------------------------------
// 1x1 conv, 16 in-ch -> 32 out-ch, optional bias/leaky/residual.
// ---------------------------------------------------------------------------
template<bool BIAS, bool LEAKY, bool RESID>
__global__ __launch_bounds__(256)
void conv1x1_k(const float* __restrict__ src,   // (B,16,128,128)
               const float* __restrict__ wgt,   // (32,16)
               const float* __restrict__ bias,  // (32) or null
               const float* __restrict__ resid, // (B,32,128,128) or null
               float* __restrict__ out)         // (B,32,128,128)
{
    int idx = blockIdx.x * 256 + threadIdx.x;   // B*32*16384 exact
    int sp = idx & 16383;
    int co = (idx >> 14) & 31;
    int b  = idx >> 19;
    const float* sb   = src + (size_t)b * CI * 16384 + sp;
    const float* wrow = wgt + co * CI;
    float acc = BIAS ? bias[co] : 0.0f;
    #pragma unroll
    for (int ci = 0; ci < CI; ++ci) acc += wrow[ci] * sb[ci * 16384];
    if constexpr (LEAKY) acc = (acc >= 0.0f) ? acc : 0.2f * acc;
    if constexpr (RESID) acc += resid[idx];
    out[idx] = acc;
}

// ---------------------------------------------------------------------------
// 64x64x16 tiled GEMM (4x4/thread) for the fc projections.
// C[m,n] = sum_k A(m,k) * B(n,k)^T + bias[n]
//   GATHERA: A(m,k) gathered from an unfold view of src (B,16,128,128):
//            m = b*961 + pi (pi=ih*31+iw), k = c*49 + kh*7 + kw
//   TRANSC: write C transposed per batch: CT[b*196*961 + n*961 + l] (l=m%961)
// ---------------------------------------------------------------------------
#define BM 64
#define BN 64
#define BK 16

template<bool GATHERA, bool TRANSC>
__global__ __launch_bounds__(256)
void gemm64_k(const float* __restrict__ Ag, const float* __restrict__ Bg,
              const float* __restrict__ bias, float* __restrict__ Cg,
              int M, int N, int Kd)
{
    __shared__ float As[BM][BK + 1];
    __shared__ float Bs[BN][BK + 1];
    const int tm0 = blockIdx.y * BM;
    const int tn0 = blockIdx.x * BN;
    const int tid = threadIdx.x;
    const int ty = tid >> 4, tx = tid & 15;
    float acc[4][4] = {};

    // A-loader coords (fixed): thread -> row m=tid/4, k-chunk (tid%4)*4
    const int lm  = tid >> 2;
    const int lk  = (tid & 3) * 4;
    const int gm_l = tm0 + lm;
    int gb = 0, goff = 0;
    if constexpr (GATHERA) {
        int b  = gm_l / 961;
        int pi = gm_l - b * 961;
        int ih = pi / 31, iw = pi - ih * 31;
        gb   = b * 262144;                 // b*16*16384
        goff = (ih * 4) * 128 + iw * 4;    // pixel base inside channel 0
    }

    for (int k0 = 0; k0 < Kd; k0 += BK) {
        if constexpr (GATHERA) {
            #pragma unroll
            for (int j = 0; j < 4; ++j) {
                int gk = k0 + lk + j;
                float v = 0.0f;
                if (gm_l < M) {
                    int c  = gk / 49, r = gk - c * 49;
                    int kh = r / 7,  kw = r - kh * 7;
                    v = Ag[gb + c * 16384 + goff + kh * 128 + kw];
                }
                As[lm][lk + j] = v;
            }
        } else {
            #pragma unroll
            for (int j = 0; j < 4; ++j) {
                int gk = k0 + lk + j;
                As[lm][lk + j] = (gm_l < M && gk < Kd)
                               ? Ag[(long long)gm_l * Kd + gk] : 0.0f;
            }
        }
        { // B tile (n,k) row-major, ld=Kd
            int gn = tn0 + lm;
            #pragma unroll
            for (int j = 0; j < 4; ++j) {
                int gk = k0 + lk + j;
                Bs[lm][lk + j] = (gn < N && gk < Kd)
                               ? Bg[(long long)gn * Kd + gk] : 0.0f;
            }
        }
        __syncthreads();
        #pragma unroll
        for (int kk = 0; kk < BK; ++kk) {
            float a[4], bv[4];
            #pragma unroll
            for (int i = 0; i < 4; ++i) a[i]  = As[ty * 4 + i][kk];
            #pragma unroll
            for (int j = 0; j < 4; ++j) bv[j] = Bs[tx * 4 + j][kk];
            #pragma unroll
            for (int i = 0; i < 4; ++i)
                #pragma unroll
                for (int j = 0; j < 4; ++j)
                    acc[i][j] += a[i] * bv[j];
        }
        __syncthreads();
    }

    #pragma unroll
    for (int i = 0; i < 4; ++i) {
        int gm = tm0 + ty * 4 + i;
        if (gm >= M) continue;
        int b = 0, l = gm;
        if constexpr (TRANSC) { b = gm / 961; l = gm - b * 961; }
        #pragma unroll
        for (int j = 0; j < 4; ++j) {
            int gn = tn0 + tx * 4 + j;
            if (gn >= N) continue;
            float v = acc[i][j] + bias[gn];
            if constexpr (TRANSC)
                Cg[(long long)b * 188356 + (long long)gn * 961 + l] = v;
            else
                Cg[(long long)gm * N + gn] = v;
        }
    }
}

// ---------------------------------------------------------------------------
// 128x128x16 tiled GEMM (8x8/thread, K-major LDS -> ds_read_b128), batched NN.
//   C[m,n] = sum_k A[m,k]*B[k,n] (+ bias[m])
//   GATHERB: B[k,n] gathered from unfold of x3 (B,32,128,128):
//            k = patch = ih*31+iw, n = c*49 + kh*7 + kw  (N space = 1568)
// ---------------------------------------------------------------------------
template<bool GATHERB, bool BIASM>
__global__ __launch_bounds__(256)
void gemm128_k(const float* __restrict__ Ag, const float* __restrict__ Bg,
               const float* __restrict__ bias, float* __restrict__ Cg,
               int M, int N, int Kd, int ldb,
               long long sA, long long sB, long long sC)
{
    constexpr int TM = 128, TN = 128, TK = 16;
    __shared__ float As[TK][TM + 4];
    __shared__ float Bs[TK][TN + 4];
    const float* Ab = Ag + blockIdx.z * sA;
    const float* Bb = Bg + blockIdx.z * sB;
    float*       Cb = Cg + blockIdx.z * sC;
    const int tm0 = blockIdx.y * TM;
    const int tn0 = blockIdx.x * TN;
    const int tid = threadIdx.x;
    const int ty = tid >> 4, tx = tid & 15;

    // A loader: thread -> m=tid/2, 8 consecutive k at (tid&1)*8
    const int am  = tid >> 1;
    const int ak0 = (tid & 1) * 8;
    // B loader: thread -> kk=tid/16, 8 consecutive n at (tid&15)*8
    const int bkk = tid >> 4;
    const int bn0 = (tid & 15) * 8;

    int pn[8];
    if constexpr (GATHERB) {
        #pragma unroll
        for (int j = 0; j < 8; ++j) {
            int n = tn0 + bn0 + j;
            if (n < F62) {
                int c  = n / 49, r = n - c * 49;
                int kh = r / 7,  kw = r - kh * 7;
                pn[j] = c * 16384 + kh * 128 + kw;
            } else pn[j] = -1;
        }
    }

    float acc[8][8] = {};

    for (int k0 = 0; k0 < Kd; k0 += TK) {
        { // A tile -> K-major LDS
            int gm = tm0 + am;
            #pragma unroll
            for (int j = 0; j < 8; ++j) {
                int gk = k0 + ak0 + j;
                As[ak0 + j][am] = (gm < M && gk < Kd)
                                ? Ab[(long long)gm * Kd + gk] : 0.0f;
            }
        }
        if constexpr (GATHERB) {
            int k = k0 + bkk;
            if (k < Kd) {
                int ih = k / 31, iw = k - ih * 31;
                int boff = ih * 512 + iw * 4;   // (ih*4)*128 + iw*4
                #pragma unroll
                for (int j = 0; j < 8; ++j)
                    Bs[bkk][bn0 + j] = (pn[j] >= 0) ? Bb[boff + pn[j]] : 0.0f;
            } else {
                #pragma unroll
                for (int j = 0; j < 8; ++j) Bs[bkk][bn0 + j] = 0.0f;
            }
        } else {
            int k = k0 + bkk;
            #pragma unroll
            for (int j = 0; j < 8; ++j) {
                int gn = tn0 + bn0 + j;
                Bs[bkk][bn0 + j] = (k < Kd && gn < N)
                                 ? Bb[(long long)k * ldb + gn] : 0.0f;
            }
        }
        __syncthreads();
        #pragma unroll
        for (int kk = 0; kk < TK; ++kk) {
            float a[8], bv[8];
            *(float4*)&a[0]  = *(const float4*)&As[kk][ty * 8];
            *(float4*)&a[4]  = *(const float4*)&As[kk][ty * 8 + 4];
            *(float4*)&bv[0] = *(const float4*)&Bs[kk][tx * 8];
            *(float4*)&bv[4] = *(const float4*)&Bs[kk][tx * 8 + 4];
            #pragma unroll
            for (int i = 0; i < 8; ++i)
                #pragma unroll
                for (int j = 0; j < 8; ++j)
                    acc[i][j] += a[i] * bv[j];
        }
        __syncthreads();
    }

    #pragma unroll
    for (int i = 0; i < 8; ++i) {
        int gm = tm0 + ty * 8 + i;
        if (gm >= M) continue;
        float bm = BIASM ? bias[gm] : 0.0f;
        #pragma unroll
        for (int j = 0; j < 8; ++j) {
            int gn = tn0 + tx * 8 + j;
            if (gn >= N) continue;
            Cb[(long long)gm * N + gn] = acc[i][j] + bm;
        }
    }
}

// ---------------------------------------------------------------------------
// Mw = mconv_w + mfc_w etc.
// ---------------------------------------------------------------------------
__global__ __launch_bounds__(256)
void add_k(const float* __restrict__ a, const float* __restrict__ b,
           float* __restrict__ c, int n)
{
    int i = blockIdx.x * 256 + threadIdx.x;
    if (i < n) c[i] = a[i] + b[i];
}

// ---------------------------------------------------------------------------
// Am = softmax(A * sigmoid(Ti) * scale, axis=-1) * (sigmoid(Ti) != 0)
// One block per row of 961. sigmoid exp-form; mask==0 exactly when expf
// overflows to inf (Ti < ~-88.7) -> mask_b = 0, matching the reference.
// ---------------------------------------------------------------------------
__global__ __launch_bounds__(256)
void softmax_mask_k(const float* __restrict__ Abuf, const float* __restrict__ Ti,
                    float* __restrict__ Am)
{
    long long row = blockIdx.x;              // b*961 + l
    const float* arow = Abuf + row * Lp;
    const float* trow = Ti   + row * Lp;
    float*       orow = Am   + row * Lp;
    int tid = threadIdx.x;
    const float scale = 0.07142857142857142f; // 196^-0.5

    float s[4], mb[4];
    float lmax = -INFINITY;
    #pragma unroll
    for (int j = 0; j < 4; ++j) {
        int m = tid + j * 256;
        if (m < Lp) {
            float t = trow[m];
            float mask = 1.0f / (1.0f + expf(-t));
            float v = arow[m] * mask * scale;
            s[j]  = v;
            mb[j] = (mask != 0.0f) ? 1.0f : 0.0f;
            lmax  = fmaxf(lmax, v);
        } else { s[j] = -INFINITY; mb[j] = 0.0f; }
    }
    __shared__ float red[256];
    red[tid] = lmax; __syncthreads();
    #pragma unroll
    for (int off = 128; off > 0; off >>= 1) {
        if (tid < off) red[tid] = fmaxf(red[tid], red[tid + off]);
        __syncthreads();
    }
    float rmax = red[0];
    __syncthreads();

    float e[4];
    float lsum = 0.0f;
    #pragma unroll
    for (int j = 0; j < 4; ++j) {
        int m = tid + j * 256;
        e[j] = (m < Lp) ? expf(s[j] - rmax) : 0.0f;
        lsum += e[j];
    }
    red[tid] = lsum; __syncthreads();
    #pragma unroll
    for (int off = 128; off > 0; off >>= 1) {
        if (tid < off) red[tid] += red[tid + off];
        __syncthreads();
    }
    float inv = 1.0f / red[0];
    #pragma unroll
    for (int j = 0; j < 4; ++j) {
        int m = tid + j * 256;
        if (m < Lp) orow[m] = e[j] * inv * mb[j];
    }
}

// ---------------------------------------------------------------------------
// fold y (B, L, 1568) back to (B,32,128,128) with overlap-add (gather form).
// ---------------------------------------------------------------------------
__global__ __launch_bounds__(256)
void fold_k(const float* __restrict__ y, float* __restrict__ out)
{
    int idx = blockIdx.x * 256 + threadIdx.x;   // B*32*16384 exact
    int wc = idx & 127;
    int hr = (idx >> 7) & 127;
    int c  = (idx >> 14) & 31;
    int b  = idx >> 19;
    int ih_lo = (hr >= 6) ? ((hr - 3) >> 2) : 0;
    int ih_hi = min(hr >> 2, 30);
    int iw_lo = (wc >= 6) ? ((wc - 3) >> 2) : 0;
    int iw_hi = min(wc >> 2, 30);
    float acc = 0.0f;
    for (int ih = ih_lo; ih <= ih_hi; ++ih) {
        int kh = hr - 4 * ih;
        for (int iw = iw_lo; iw <= iw_hi; ++iw) {
            int kw = wc - 4 * iw;
            acc += y[((size_t)b * Lp + ih * 31 + iw) * F62 + c * 49 + kh * 7 + kw];
        }
    }
    out[idx] = acc;
}

// ---------------------------------------------------------------------------
// Launch
// ---------------------------------------------------------------------------
extern "C" void kernel_launch(void* const* d_in, const int* in_sizes, int n_in,
                              void* d_out, int out_size, void* d_ws, size_t ws_size,
                              hipStream_t stream)
{
    const float* x       = (const float*)d_in[0];
    const float* g_w     = (const float*)d_in[1];
    const float* g_b     = (const float*)d_in[2];
    const float* w_w     = (const float*)d_in[3];
    const float* w_b     = (const float*)d_in[4];
    const float* theta_w = (const float*)d_in[5];
    const float* theta_b = (const float*)d_in[6];
    const float* fc1_w   = (const float*)d_in[7];
    const float* fc1_b   = (const float*)d_in[8];
    const float* mconv_w = (const float*)d_in[9];
    const float* mconv_b = (const float*)d_in[10];
    const float* mfc_w   = (const float*)d_in[11];
    const float* mfc_b   = (const float*)d_in[12];
    const float* c1_w    = (const float*)d_in[13];
    const float* c2_w    = (const float*)d_in[14];

    float* Am_out    = (float*)d_out;                       // 8*961*961
    float* final_out = Am_out + (size_t)Bn * Lp * Lp;       // + 8*32*128*128

    // Workspace layout (floats), total ~27.1M floats = ~108 MB
    float* ws = (float*)d_ws;
    size_t off = 0;
    float* x1    = ws + off; off += 2097152;   // (8,16,128,128)
    float* x2    = ws + off; off += 2097152;   // (8,16,128,128)
    float* x3    = ws + off; off += 4194304;   // (8,32,128,128); later fold out
    float* wfxf  = ws + off; off += 3013696;   // [xfT (8,196,961); wf (8,961,196)]
    float* Abuf  = ws + off; off += 7388168;   // (8,961,961); later aliased by y
    float* Tibuf = ws + off; off += 7388168;   // (8,961,961)
    float* Mw    = ws + off; off += 923648;
    float* Mb    = ws + off; off += 1024;
    float* xfT   = wfxf;
    float* wf    = wfxf + 1506848;
    float* ybuf  = Abuf;                       // (8,961,1568) aliases A+Ti after softmax

    // Mw = mconv_w + mfc_w ; Mb = mconv_b + mfc_b
    add_k<<<3608, 256, 0, stream>>>(mconv_w, mfc_w, Mw, 923521);
    add_k<<<4, 256, 0, stream>>>(mconv_b, mfc_b, Mb, 961);

    // x1 = conv3x3(refpad(x), g_w)+g_b ; x2 = conv3x3(refpad(x), w_w)+w_b
    conv3x3_k<true, true, false><<<8192, 256, 0, stream>>>(
        x, g_w, g_b, w_w, w_b, x1, x2);

    // x3 = conv1x1(x1, theta_w)+theta_b
    conv1x1_k<true, false, false><<<16384, 256, 0, stream>>>(
        x1, theta_w, theta_b, nullptr, x3);

    // xfT = (unfold(x1) @ fc1_w^T + fc1_b) transposed per batch (196x961)
    gemm64_k<true, true><<<dim3(4, 121, 1), 256, 0, stream>>>(
        x1, fc1_w, fc1_b, xfT, 7688, FOUT, FIN);
    // wf = unfold(x2) @ fc1_w^T + fc1_b (row-major 7688x196)
    gemm64_k<true, false><<<dim3(4, 121, 1), 256, 0, stream>>>(
        x2, fc1_w, fc1_b, wf, 7688, FOUT, FIN);

    // A[b] = wf[b] (961x196) @ xfT[b] (196x961)  [NN]
    gemm128_k<false, false><<<dim3(8, 8, 8), 256, 0, stream>>>(
        wf, xfT, nullptr, Abuf, Lp, Lp, FOUT, Lp, 188356, 188356, 923521);

    // Ti[b] = Mw @ A[b] + Mb[row]  [NN, bias-m]
    gemm128_k<false, true><<<dim3(8, 8, 8), 256, 0, stream>>>(
        Mw, Abuf, Mb, Tibuf, Lp, Lp, Lp, Lp, 0, 923521, 923521);

    // Am = softmax(A*sigmoid(Ti)*scale) * mask_b  -> d_out
    softmax_mask_k<<<7688, 256, 0, stream>>>(Abuf, Tibuf, Am_out);

    // y[b] = Am[b] @ unfold(x3)[b]  [NN, B gathered from x3]  (A/Ti now dead)
    gemm128_k<true, false><<<dim3(13, 8, 8), 256, 0, stream>>>(
        Am_out, x3, nullptr, ybuf, Lp, F62, Lp, 0, 923521, 524288, 1506848);

    // fold y -> x3
    fold_k<<<16384, 256, 0, stream>>>(ybuf, x3);

    // o1 = leaky_relu(conv3x3(refpad(fold), c1_w))  -> reuse x1
    conv3x3_k<false, false, true><<<8192, 256, 0, stream>>>(
        x3, c1_w, nullptr, nullptr, nullptr, x1, nullptr);

    // final = x + leaky_relu(conv1x1(o1, c2_w))
    conv1x1_k<false, true, true><<<16384, 256, 0, stream>>>(
        x1, c2_w, nullptr, x, final_out);
}

// Round 3
// 1270.491 us; speedup vs baseline: 1.5585x; 1.5585x over previous
//
#include <hip/hip_runtime.h>
#include <math.h>

namespace {
constexpr int Bn   = 8;
constexpr int CIN  = 32;
constexpr int CI   = 16;
constexpr int Lp   = 961;     // 31*31 patches
constexpr int FIN  = 784;     // 16*49
constexpr int FOUT = 196;
constexpr int F62  = 1568;    // 32*49

// padded leading dims (float4 / 16B alignment)
constexpr int AP  = 968;                 // A/Ti row stride (floats)
constexpr long long APB = 961LL * AP;    // per-batch A/Ti
constexpr int MWP = 964;                 // Mw row stride
constexpr int XFP = 968;                 // xfT row stride
constexpr long long XFB = 196LL * XFP;
constexpr int KP  = 992;                 // bf16 K-pad (31 tiles of 32)
constexpr long long AMBB = 961LL * KP;   // Am_bf16 per-batch (shorts)
constexpr long long PBTB = 1568LL * KP;  // p62bT per-batch (shorts)
}

typedef __attribute__((ext_vector_type(8))) short short8x;
typedef __attribute__((ext_vector_type(4))) float floatx4;

static __device__ __forceinline__ unsigned short f2bf(float x) {
    unsigned int u = __builtin_bit_cast(unsigned int, x);
    u += 0x7fffu + ((u >> 16) & 1u);           // RNE
    return (unsigned short)(u >> 16);
}

// ---------------------------------------------------------------------------
// 3x3 conv with reflect-pad(1). 32 in-ch -> 16 out-ch. DUAL computes two.
// ---------------------------------------------------------------------------
template<bool DUAL, bool BIAS, bool LEAKY>
__global__ __launch_bounds__(256)
void conv3x3_k(const float* __restrict__ x,
               const float* __restrict__ w1, const float* __restrict__ b1,
               const float* __restrict__ w2, const float* __restrict__ b2,
               float* __restrict__ o1, float* __restrict__ o2)
{
    int idx = blockIdx.x * 256 + threadIdx.x;     // B*16*128*128 exact
    int wc = idx & 127;
    int hr = (idx >> 7) & 127;
    int co = (idx >> 14) & 15;
    int b  = idx >> 18;
    int hm = (hr == 0)   ? 1   : hr - 1;
    int hp = (hr == 127) ? 126 : hr + 1;
    int wm = (wc == 0)   ? 1   : wc - 1;
    int wp = (wc == 127) ? 126 : wc + 1;
    float acc1 = BIAS ? b1[co] : 0.0f;
    float acc2 = 0.0f;
    if constexpr (DUAL) acc2 = b2[co];
    const float* xb  = x + (size_t)b * CIN * 16384;
    const float* w1c = w1 + co * CIN * 9;
    const float* w2c = DUAL ? (w2 + co * CIN * 9) : nullptr;
    #pragma unroll 4
    for (int ci = 0; ci < CIN; ++ci) {
        const float* xc = xb + ci * 16384;
        float v00 = xc[hm*128+wm], v01 = xc[hm*128+wc], v02 = xc[hm*128+wp];
        float v10 = xc[hr*128+wm], v11 = xc[hr*128+wc], v12 = xc[hr*128+wp];
        float v20 = xc[hp*128+wm], v21 = xc[hp*128+wc], v22 = xc[hp*128+wp];
        const float* q1 = w1c + ci * 9;
        acc1 += v00*q1[0] + v01*q1[1] + v02*q1[2]
              + v10*q1[3] + v11*q1[4] + v12*q1[5]
              + v20*q1[6] + v21*q1[7] + v22*q1[8];
        if constexpr (DUAL) {
            const float* q2 = w2c + ci * 9;
            acc2 += v00*q2[0] + v01*q2[1] + v02*q2[2]
                  + v10*q2[3] + v11*q2[4] + v12*q2[5]
                  + v20*q2[6] + v21*q2[7] + v22*q2[8];
        }
    }
    if constexpr (LEAKY) acc1 = (acc1 >= 0.0f) ? acc1 : 0.2f * acc1;
    o1[idx] = acc1;
    if constexpr (DUAL) o2[idx] = acc2;
}

// ---------------------------------------------------------------------------
// 1x1 conv, 16 in-ch -> 32 out-ch, optional bias/leaky/residual.
// ---------------------------------------------------------------------------
template<bool BIAS, bool LEAKY, bool RESID>
__global__ __launch_bounds__(256)
void conv1x1_k(const float* __restrict__ src, const float* __restrict__ wgt,
               const float* __restrict__ bias, const float* __restrict__ resid,
               float* __restrict__ out)
{
    int idx = blockIdx.x * 256 + threadIdx.x;   // B*32*16384 exact
    int sp = idx & 16383;
    int co = (idx >> 14) & 31;
    int b  = idx >> 19;
    const float* sb   = src + (size_t)b * CI * 16384 + sp;
    const float* wrow = wgt + co * CI;
    float acc = BIAS ? bias[co] : 0.0f;
    #pragma unroll
    for (int ci = 0; ci < CI; ++ci) acc += wrow[ci] * sb[ci * 16384];
    if constexpr (LEAKY) acc = (acc >= 0.0f) ? acc : 0.2f * acc;
    if constexpr (RESID) acc += resid[idx];
    out[idx] = acc;
}

// ---------------------------------------------------------------------------
// 64x64x16 fc GEMM (4x4/thread): C = unfold(src) @ fc1_w^T + fc1_b
// TRANSC: write per-batch transposed with row stride XFP.
// ---------------------------------------------------------------------------
template<bool TRANSC>
__global__ __launch_bounds__(256)
void gemm64_k(const float* __restrict__ Ag, const float* __restrict__ Bg,
              const float* __restrict__ bias, float* __restrict__ Cg,
              int M, int N, int Kd)
{
    __shared__ float As[64][17];
    __shared__ float Bs[64][17];
    const int tm0 = blockIdx.y * 64;
    const int tn0 = blockIdx.x * 64;
    const int tid = threadIdx.x;
    const int ty = tid >> 4, tx = tid & 15;
    float acc[4][4] = {};

    const int lm  = tid >> 2;
    const int lk  = (tid & 3) * 4;
    const int gm_l = tm0 + lm;
    int gb = 0, goff = 0;
    {
        int b  = gm_l / 961;
        int pi = gm_l - b * 961;
        int ih = pi / 31, iw = pi - ih * 31;
        gb   = b * 262144;
        goff = (ih * 4) * 128 + iw * 4;
    }

    for (int k0 = 0; k0 < Kd; k0 += 16) {
        #pragma unroll
        for (int j = 0; j < 4; ++j) {
            int gk = k0 + lk + j;
            float v = 0.0f;
            if (gm_l < M) {
                int c  = gk / 49, r = gk - c * 49;
                int kh = r / 7,  kw = r - kh * 7;
                v = Ag[gb + c * 16384 + goff + kh * 128 + kw];
            }
            As[lm][lk + j] = v;
        }
        {
            int gn = tn0 + lm;
            #pragma unroll
            for (int j = 0; j < 4; ++j) {
                int gk = k0 + lk + j;
                Bs[lm][lk + j] = (gn < N && gk < Kd)
                               ? Bg[(long long)gn * Kd + gk] : 0.0f;
            }
        }
        __syncthreads();
        #pragma unroll
        for (int kk = 0; kk < 16; ++kk) {
            float a[4], bv[4];
            #pragma unroll
            for (int i = 0; i < 4; ++i) a[i]  = As[ty * 4 + i][kk];
            #pragma unroll
            for (int j = 0; j < 4; ++j) bv[j] = Bs[tx * 4 + j][kk];
            #pragma unroll
            for (int i = 0; i < 4; ++i)
                #pragma unroll
                for (int j = 0; j < 4; ++j)
                    acc[i][j] += a[i] * bv[j];
        }
        __syncthreads();
    }

    #pragma unroll
    for (int i = 0; i < 4; ++i) {
        int gm = tm0 + ty * 4 + i;
        if (gm >= M) continue;
        int b = gm / 961, l = gm - b * 961;
        #pragma unroll
        for (int j = 0; j < 4; ++j) {
            int gn = tn0 + tx * 4 + j;
            if (gn >= N) continue;
            float v = acc[i][j] + bias[gn];
            if constexpr (TRANSC)
                Cg[(long long)b * XFB + (long long)gn * XFP + l] = v;
            else
                Cg[(long long)gm * N + gn] = v;
        }
    }
}

// ---------------------------------------------------------------------------
// fp32 128x128x16 NN GEMM, 8x8/thread, K-major LDS, swizzled Bs (2-way=free),
// register prefetch of the next K-tile overlapping compute.
// ---------------------------------------------------------------------------
template<bool BIASM>
__global__ __launch_bounds__(256)
void gemm128f_k(const float* __restrict__ Ag, const float* __restrict__ Bg,
                const float* __restrict__ bias, float* __restrict__ Cg,
                int M, int N, int Kd, int lda, int ldb, int ldc,
                long long sA, long long sB, long long sC)
{
    __shared__ float As[16][132];
    __shared__ float Bs[16][144];   // phys col = n + ((n>>5)<<2)
    const float* Ab = Ag + blockIdx.z * sA;
    const float* Bb = Bg + blockIdx.z * sB;
    float*       Cb = Cg + blockIdx.z * sC;
    const int tm0 = blockIdx.y * 128;
    const int tn0 = blockIdx.x * 128;
    const int tid = threadIdx.x;
    const int ty = tid >> 4, tx = tid & 15;

    const int am = tid >> 1, ak = (tid & 1) * 8;
    const int bk = tid >> 4, bn = (tid & 15) * 8;
    const bool a_ok = (tm0 + am) < M;
    const float* Arow = Ab + (long long)(tm0 + am) * lda;
    const int bphys = bn + ((bn >> 5) << 2);
    const int tp = tx * 8 + ((tx >> 2) << 2);

    float pa[8], pb[8];
    auto loadA = [&](int k0) {
        int g0 = k0 + ak;
        if (a_ok && g0 + 7 < Kd) {
            *(float4*)&pa[0] = *(const float4*)(Arow + g0);
            *(float4*)&pa[4] = *(const float4*)(Arow + g0 + 4);
        } else {
            #pragma unroll
            for (int j = 0; j < 8; ++j)
                pa[j] = (a_ok && g0 + j < Kd) ? Arow[g0 + j] : 0.0f;
        }
    };
    auto loadB = [&](int k0) {
        int gk = k0 + bk;
        const float* Brow = Bb + (long long)gk * ldb + tn0 + bn;
        if (gk < Kd && tn0 + bn + 7 < N) {
            *(float4*)&pb[0] = *(const float4*)(Brow);
            *(float4*)&pb[4] = *(const float4*)(Brow + 4);
        } else {
            #pragma unroll
            for (int j = 0; j < 8; ++j)
                pb[j] = (gk < Kd && tn0 + bn + j < N) ? Brow[j] : 0.0f;
        }
    };

    float acc[8][8] = {};
    loadA(0); loadB(0);
    for (int k0 = 0; k0 < Kd; k0 += 16) {
        #pragma unroll
        for (int j = 0; j < 8; ++j) As[ak + j][am] = pa[j];
        *(float4*)&Bs[bk][bphys]     = *(float4*)&pb[0];
        *(float4*)&Bs[bk][bphys + 4] = *(float4*)&pb[4];
        __syncthreads();
        if (k0 + 16 < Kd) { loadA(k0 + 16); loadB(k0 + 16); }
        #pragma unroll
        for (int kk = 0; kk < 16; ++kk) {
            float a[8], bv[8];
            *(float4*)&a[0]  = *(const float4*)&As[kk][ty * 8];
            *(float4*)&a[4]  = *(const float4*)&As[kk][ty * 8 + 4];
            *(float4*)&bv[0] = *(const float4*)&Bs[kk][tp];
            *(float4*)&bv[4] = *(const float4*)&Bs[kk][tp + 4];
            #pragma unroll
            for (int i = 0; i < 8; ++i)
                #pragma unroll
                for (int j = 0; j < 8; ++j)
                    acc[i][j] += a[i] * bv[j];
        }
        __syncthreads();
    }

    #pragma unroll
    for (int i = 0; i < 8; ++i) {
        int gm = tm0 + ty * 8 + i;
        if (gm >= M) continue;
        float bm = BIASM ? bias[gm] : 0.0f;
        #pragma unroll
        for (int j = 0; j < 8; ++j) {
            int gn = tn0 + tx * 8 + j;
            if (gn >= N) continue;
            Cb[(long long)gm * ldc + gn] = acc[i][j] + bm;
        }
    }
}

// ---------------------------------------------------------------------------
// add kernels
// ---------------------------------------------------------------------------
__global__ __launch_bounds__(256)
void add_mw_k(const float* __restrict__ a, const float* __restrict__ b,
              float* __restrict__ c)
{
    int i = blockIdx.x * 256 + threadIdx.x;
    if (i < 923521) {
        int n = i / 961, cc = i - n * 961;
        c[n * MWP + cc] = a[i] + b[i];
    }
}
__global__ __launch_bounds__(256)
void add_k(const float* __restrict__ a, const float* __restrict__ b,
           float* __restrict__ c, int n)
{
    int i = blockIdx.x * 256 + threadIdx.x;
    if (i < n) c[i] = a[i] + b[i];
}

// ---------------------------------------------------------------------------
// softmax(A*sigmoid(Ti)*scale)*mask_b -> Am fp32 (d_out) + Am bf16 (K-padded)
// A/Ti rows have stride AP; bias Mb added here is already in Ti (GEMM).
// ---------------------------------------------------------------------------
__global__ __launch_bounds__(256)
void softmax_mask_k(const float* __restrict__ Abuf, const float* __restrict__ Ti,
                    float* __restrict__ Am, unsigned short* __restrict__ Amb)
{
    int row = blockIdx.x;                // b*961 + l
    int b = row / 961, l = row - b * 961;
    const float* arow = Abuf + (long long)b * APB + (long long)l * AP;
    const float* trow = Ti   + (long long)b * APB + (long long)l * AP;
    float*       orow = Am   + (long long)row * Lp;
    unsigned short* brow = Amb + (long long)row * KP;
    int tid = threadIdx.x;
    const float scale = 0.07142857142857142f; // 196^-0.5

    float s[4], mb[4];
    float lmax = -INFINITY;
    #pragma unroll
    for (int j = 0; j < 4; ++j) {
        int m = tid + j * 256;
        if (m < Lp) {
            float t = trow[m];
            float mask = 1.0f / (1.0f + expf(-t));
            float v = arow[m] * mask * scale;
            s[j]  = v;
            mb[j] = (mask != 0.0f) ? 1.0f : 0.0f;
            lmax  = fmaxf(lmax, v);
        } else { s[j] = -INFINITY; mb[j] = 0.0f; }
    }
    __shared__ float red[256];
    red[tid] = lmax; __syncthreads();
    #pragma unroll
    for (int off = 128; off > 0; off >>= 1) {
        if (tid < off) red[tid] = fmaxf(red[tid], red[tid + off]);
        __syncthreads();
    }
    float rmax = red[0];
    __syncthreads();

    float e[4];
    float lsum = 0.0f;
    #pragma unroll
    for (int j = 0; j < 4; ++j) {
        int m = tid + j * 256;
        e[j] = (m < Lp) ? expf(s[j] - rmax) : 0.0f;
        lsum += e[j];
    }
    red[tid] = lsum; __syncthreads();
    #pragma unroll
    for (int off = 128; off > 0; off >>= 1) {
        if (tid < off) red[tid] += red[tid + off];
        __syncthreads();
    }
    float inv = 1.0f / red[0];
    #pragma unroll
    for (int j = 0; j < 4; ++j) {
        int m = tid + j * 256;
        if (m < Lp) {
            float v = e[j] * inv * mb[j];
            orow[m] = v;
            brow[m] = f2bf(v);
        } else if (m < KP) {
            brow[m] = 0;                 // zero K-pad
        }
    }
}

// ---------------------------------------------------------------------------
// Build p62^T in bf16: out[b][n][k] = x3[b, c(n), ih(k)*4+kh(n), iw(k)*4+kw(n)]
// n-major rows of KP shorts (K zero-padded).
// ---------------------------------------------------------------------------
__global__ __launch_bounds__(256)
void p62bt_k(const float* __restrict__ x3, unsigned short* __restrict__ out)
{
    int idx = blockIdx.x * 256 + threadIdx.x;      // 8*1568*124
    if (idx >= 8 * 1568 * 124) return;
    int ck = idx % 124;
    int t  = idx / 124;
    int n  = t % 1568;
    int b  = t / 1568;
    int c = n / 49, rr = n - c * 49;
    int kh = rr / 7, kw = rr - kh * 7;
    const float* src = x3 + (long long)b * 524288 + c * 16384 + kh * 128 + kw;
    int k = ck * 8;
    unsigned short v[8];
    #pragma unroll
    for (int j = 0; j < 8; ++j) {
        int kk = k + j;
        if (kk < Lp) {
            int ih = kk / 31, iw = kk - ih * 31;
            v[j] = f2bf(src[ih * 512 + iw * 4]);
        } else v[j] = 0;
    }
    *(short8x*)(out + ((long long)b * 1568 + n) * KP + k) = *(short8x*)v;
}

__global__ __launch_bounds__(256)
void zero_k(float* __restrict__ p, int n4)   // n4 = count of float4
{
    int i = blockIdx.x * 256 + threadIdx.x;
    if (i < n4) ((float4*)p)[i] = make_float4(0.f, 0.f, 0.f, 0.f);
}

// ---------------------------------------------------------------------------
// y = Am @ p62 via bf16 MFMA (16x16x32), 128x128 tile, 4 waves (2x2 of 64x64),
// XOR-swizzled LDS (2-way = free). Epilogue folds y directly into the
// (B,32,128,128) image with atomicAdd (<=4 contributions per pixel).
// ---------------------------------------------------------------------------
__global__ __launch_bounds__(256)
void ymfma_k(const unsigned short* __restrict__ Amb,
             const unsigned short* __restrict__ Pbt,
             float* __restrict__ fold)
{
    __shared__ unsigned short As[128 * 32];
    __shared__ unsigned short Bs[128 * 32];
    const int b   = blockIdx.z;
    const int tm0 = blockIdx.y * 128;   // l
    const int tn0 = blockIdx.x * 128;   // n
    const unsigned short* Ab = Amb + (long long)b * AMBB;
    const unsigned short* Bb = Pbt + (long long)b * PBTB;
    const int tid = threadIdx.x;

    const int sr  = tid >> 1;                  // staged row 0..127
    const int sc0 = (tid & 1) * 2;             // chunk pair
    const bool aok = (tm0 + sr) < Lp;
    const bool bok = (tn0 + sr) < F62;
    const unsigned short* Arow = Ab + (long long)(tm0 + sr) * KP;
    const unsigned short* Brow = Bb + (long long)(tn0 + sr) * KP;
    const int swz = (sr >> 1) & 3;

    const int lane = tid & 63;
    const int wv   = tid >> 6;
    const int wm   = (wv >> 1) * 64, wn = (wv & 1) * 64;
    const int fr   = lane & 15;
    const int kq   = lane >> 4;

    floatx4 acc[4][4];
    #pragma unroll
    for (int i = 0; i < 4; ++i)
        #pragma unroll
        for (int j = 0; j < 4; ++j)
            acc[i][j] = (floatx4){0.f, 0.f, 0.f, 0.f};

    const short8x zz = {0,0,0,0,0,0,0,0};

    for (int k0 = 0; k0 < Lp; k0 += 32) {
        #pragma unroll
        for (int c = 0; c < 2; ++c) {
            int kc = sc0 + c;
            short8x va = zz, vb = zz;
            if (aok) va = *(const short8x*)(Arow + k0 + kc * 8);
            if (bok) vb = *(const short8x*)(Brow + k0 + kc * 8);
            int pc = kc ^ swz;
            *(short8x*)&As[sr * 32 + pc * 8] = va;
            *(short8x*)&Bs[sr * 32 + pc * 8] = vb;
        }
        __syncthreads();
        short8x af[4], bfr[4];
        #pragma unroll
        for (int i = 0; i < 4; ++i) {
            int mr = wm + i * 16 + fr;
            af[i] = *(const short8x*)&As[mr * 32 + ((kq ^ ((mr >> 1) & 3)) * 8)];
        }
        #pragma unroll
        for (int j = 0; j < 4; ++j) {
            int nr = wn + j * 16 + fr;
            bfr[j] = *(const short8x*)&Bs[nr * 32 + ((kq ^ ((nr >> 1) & 3)) * 8)];
        }
        #pragma unroll
        for (int i = 0; i < 4; ++i)
            #pragma unroll
            for (int j = 0; j < 4; ++j)
                acc[i][j] = __builtin_amdgcn_mfma_f32_16x16x32_bf16(
                                af[i], bfr[j], acc[i][j], 0, 0, 0);
        __syncthreads();
    }

    // epilogue: y[l][n] -> atomicAdd into fold image
    float* Fb = fold + (long long)b * 524288;
    #pragma unroll
    for (int j = 0; j < 4; ++j) {
        int col = tn0 + wn + j * 16 + fr;          // n
        if (col >= F62) continue;
        int c = col / 49, rr = col - c * 49;
        int kh = rr / 7, kw = rr - kh * 7;
        int pbase = c * 16384 + kh * 128 + kw;
        #pragma unroll
        for (int i = 0; i < 4; ++i) {
            #pragma unroll
            for (int r = 0; r < 4; ++r) {
                int l = tm0 + wm + i * 16 + kq * 4 + r;   // row
                if (l >= Lp) continue;
                int ih = l / 31, iw = l - ih * 31;
                atomicAdd(Fb + pbase + ih * 512 + iw * 4, acc[i][j][r]);
            }
        }
    }
}

// ---------------------------------------------------------------------------
// Launch
// ---------------------------------------------------------------------------
extern "C" void kernel_launch(void* const* d_in, const int* in_sizes, int n_in,
                              void* d_out, int out_size, void* d_ws, size_t ws_size,
                              hipStream_t stream)
{
    const float* x       = (const float*)d_in[0];
    const float* g_w     = (const float*)d_in[1];
    const float* g_b     = (const float*)d_in[2];
    const float* w_w     = (const float*)d_in[3];
    const float* w_b     = (const float*)d_in[4];
    const float* theta_w = (const float*)d_in[5];
    const float* theta_b = (const float*)d_in[6];
    const float* fc1_w   = (const float*)d_in[7];
    const float* fc1_b   = (const float*)d_in[8];
    const float* mconv_w = (const float*)d_in[9];
    const float* mconv_b = (const float*)d_in[10];
    const float* mfc_w   = (const float*)d_in[11];
    const float* mfc_b   = (const float*)d_in[12];
    const float* c1_w    = (const float*)d_in[13];
    const float* c2_w    = (const float*)d_in[14];

    float* Am_out    = (float*)d_out;                    // 8*961*961
    float* final_out = Am_out + (size_t)Bn * Lp * Lp;    // + 8*32*128*128

    // Workspace layout (floats). Total ~27.23M floats (~109 MB), same as R2.
    float* ws = (float*)d_ws;
    float* x1    = ws;                       // 2,097,152
    float* x2    = ws + 2097152;             // 2,097,152
    float* x3    = ws + 4194304;             // 4,194,304 (later fold target)
    float* wf    = ws + 8388608;             // 1,506,848 (8 x 961x196)
    float* xfT   = ws + 9895456;             // 1,517,824 (8 x 196xXFP)
    float* AbufP = ws + 11413280;            // 7,441,984 (8 x 961xAP)
    float* TibufP= ws + 18855264;            // 7,441,984
    float* Mw    = ws + 26297248;            // 926,404 (961xMWP)
    float* Mb    = ws + 27223652;            // 1,024
    // aliases
    unsigned short* Am_bf16 = (unsigned short*)x1;       // 7,627,776 shorts (< x1+x2)
    unsigned short* p62bT   = (unsigned short*)AbufP;    // 12,443,648 shorts (< AbufP)

    // Mw (padded) = mconv_w + mfc_w ; Mb = mconv_b + mfc_b
    add_mw_k<<<3608, 256, 0, stream>>>(mconv_w, mfc_w, Mw);
    add_k<<<4, 256, 0, stream>>>(mconv_b, mfc_b, Mb, 961);

    // x1, x2 = dual 3x3 convs on reflect-pad(x)
    conv3x3_k<true, true, false><<<8192, 256, 0, stream>>>(
        x, g_w, g_b, w_w, w_b, x1, x2);

    // x3 = conv1x1(x1)
    conv1x1_k<true, false, false><<<16384, 256, 0, stream>>>(
        x1, theta_w, theta_b, nullptr, x3);

    // xfT = (unfold(x1) @ fc1_w^T + b) transposed (196 x 961, stride XFP)
    gemm64_k<true><<<dim3(4, 121, 1), 256, 0, stream>>>(
        x1, fc1_w, fc1_b, xfT, 7688, FOUT, FIN);
    // wf = unfold(x2) @ fc1_w^T + b (row-major 7688x196)
    gemm64_k<false><<<dim3(4, 121, 1), 256, 0, stream>>>(
        x2, fc1_w, fc1_b, wf, 7688, FOUT, FIN);

    // A[b] = wf[b] @ xfT[b]   (961x961, ldc=AP)
    gemm128f_k<false><<<dim3(8, 8, 8), 256, 0, stream>>>(
        wf, xfT, nullptr, AbufP, Lp, Lp, FOUT, FOUT, XFP, AP,
        188356LL, XFB, APB);

    // Ti[b] = Mw @ A[b] + Mb[row]
    gemm128f_k<true><<<dim3(8, 8, 8), 256, 0, stream>>>(
        Mw, AbufP, Mb, TibufP, Lp, Lp, Lp, MWP, AP, AP,
        0LL, APB, APB);

    // Am (fp32 -> d_out, bf16 K-padded -> ws)
    softmax_mask_k<<<7688, 256, 0, stream>>>(AbufP, TibufP, Am_out, Am_bf16);

    // p62^T bf16 (aliases AbufP; A dead after softmax)
    p62bt_k<<<6077, 256, 0, stream>>>(x3, p62bT);

    // zero fold target (x3 dead after p62bt)
    zero_k<<<4096, 256, 0, stream>>>(x3, 1048576);

    // y = Am @ p62, folded into x3 via atomics
    ymfma_k<<<dim3(13, 8, 8), 256, 0, stream>>>(Am_bf16, p62bT, x3);

    // o1 = leaky(conv3x3(refpad(fold)))
    conv3x3_k<false, false, true><<<8192, 256, 0, stream>>>(
        x3, c1_w, nullptr, nullptr, nullptr, x1, nullptr);

    // final = x + leaky(conv1x1(o1))
    conv1x1_k<false, true, true><<<16384, 256, 0, stream>>>(
        x1, c2_w, nullptr, x, final_out);
}

// Round 4
// 1076.004 us; speedup vs baseline: 1.8402x; 1.1807x over previous
//
#include <hip/hip_runtime.h>
#include <math.h>

namespace {
constexpr int Bn   = 8;
constexpr int CIN  = 32;
constexpr int CI   = 16;
constexpr int Lp   = 961;     // 31*31 patches
constexpr int FIN  = 784;     // 16*49
constexpr int FOUT = 196;
constexpr int F62  = 1568;    // 32*49

constexpr int FCP  = 224;                 // fc K-pad (196 -> 7*32)
constexpr long long FCB = 961LL * FCP;    // per-batch fc rows (shorts)
constexpr int KP   = 992;                 // L K-pad (961 -> 31*32)
constexpr long long ATB  = 961LL * KP;    // AT per-batch (shorts)
constexpr long long AMBB = 961LL * KP;    // Am_bf16 per-batch (shorts)
constexpr long long PBTB = 1568LL * KP;   // p62bT per-batch (shorts)
constexpr long long AB   = 961LL * 961;   // A/S per-batch (floats)
}

typedef __attribute__((ext_vector_type(8))) short short8x;
typedef __attribute__((ext_vector_type(4))) float floatx4;
typedef __attribute__((ext_vector_type(4))) unsigned short ushort4x;

static __device__ __forceinline__ unsigned short f2bf(float x) {
    unsigned int u = __builtin_bit_cast(unsigned int, x);
    u += 0x7fffu + ((u >> 16) & 1u);           // RNE
    return (unsigned short)(u >> 16);
}
static __device__ __forceinline__ float bf2f(unsigned short h) {
    return __builtin_bit_cast(float, ((unsigned int)h) << 16);
}

// ---------------------------------------------------------------------------
// 3x3 conv, reflect-pad(1), 32ch -> 16ch, 4-pixel strip per thread.
// Per channel-row: one aligned float4 + 2 scalars feed 12 taps (x2 if DUAL).
// Reflect: left of w=0 is x[1] (in-strip); right of w=127 is x[126] (in-strip).
// ---------------------------------------------------------------------------
template<bool DUAL, bool BIAS, bool LEAKY>
__global__ __launch_bounds__(256)
void conv3x3s_k(const float* __restrict__ x,
                const float* __restrict__ w1, const float* __restrict__ b1,
                const float* __restrict__ w2, const float* __restrict__ b2,
                float* __restrict__ o1, float* __restrict__ o2)
{
    int idx = blockIdx.x * 256 + threadIdx.x;   // 8*16*128*32 = 524288 exact
    int w0 = (idx & 31) * 4;
    int h  = (idx >> 5) & 127;
    int co = (idx >> 12) & 15;
    int b  = idx >> 16;
    int hm = (h == 0)   ? 1   : h - 1;
    int hp = (h == 127) ? 126 : h + 1;
    int lw = (w0 == 0)   ? 1   : w0 - 1;        // reflect -> x[1]
    int rw = (w0 == 124) ? 126 : w0 + 4;        // reflect -> x[126]
    int rows[3] = { hm * 128, h * 128, hp * 128 };

    float a1[4], a2[4];
    float bb1 = BIAS ? b1[co] : 0.0f;
    float bb2 = (DUAL && BIAS) ? b2[co] : 0.0f;
    #pragma unroll
    for (int o = 0; o < 4; ++o) { a1[o] = bb1; a2[o] = bb2; }

    const float* xb  = x + (size_t)b * CIN * 16384;
    const float* w1c = w1 + co * CIN * 9;
    const float* w2c = DUAL ? (w2 + co * CIN * 9) : nullptr;

    for (int ci = 0; ci < CIN; ++ci) {
        const float* xc = xb + ci * 16384;
        const float* q1 = w1c + ci * 9;
        const float* q2 = DUAL ? (w2c + ci * 9) : nullptr;
        #pragma unroll
        for (int r = 0; r < 3; ++r) {
            int ro = rows[r];
            float4 m4 = *(const float4*)(xc + ro + w0);
            float v[6];
            v[0] = xc[ro + lw];
            v[1] = m4.x; v[2] = m4.y; v[3] = m4.z; v[4] = m4.w;
            v[5] = xc[ro + rw];
            float c0 = q1[r*3+0], c1 = q1[r*3+1], c2 = q1[r*3+2];
            #pragma unroll
            for (int o = 0; o < 4; ++o)
                a1[o] += v[o]*c0 + v[o+1]*c1 + v[o+2]*c2;
            if constexpr (DUAL) {
                float d0 = q2[r*3+0], d1 = q2[r*3+1], d2 = q2[r*3+2];
                #pragma unroll
                for (int o = 0; o < 4; ++o)
                    a2[o] += v[o]*d0 + v[o+1]*d1 + v[o+2]*d2;
            }
        }
    }
    size_t ob = (((size_t)b * 16 + co) * 128 + h) * 128 + w0;
    if constexpr (LEAKY) {
        #pragma unroll
        for (int o = 0; o < 4; ++o) a1[o] = (a1[o] >= 0.f) ? a1[o] : 0.2f * a1[o];
    }
    *(float4*)(o1 + ob) = make_float4(a1[0], a1[1], a1[2], a1[3]);
    if constexpr (DUAL)
        *(float4*)(o2 + ob) = make_float4(a2[0], a2[1], a2[2], a2[3]);
}

// ---------------------------------------------------------------------------
// 1x1 conv, 16ch -> 32ch, optional bias/leaky/residual.
// ---------------------------------------------------------------------------
template<bool BIAS, bool LEAKY, bool RESID>
__global__ __launch_bounds__(256)
void conv1x1_k(const float* __restrict__ src, const float* __restrict__ wgt,
               const float* __restrict__ bias, const float* __restrict__ resid,
               float* __restrict__ out)
{
    int idx = blockIdx.x * 256 + threadIdx.x;   // B*32*16384 exact
    int sp = idx & 16383;
    int co = (idx >> 14) & 31;
    int b  = idx >> 19;
    const float* sb   = src + (size_t)b * CI * 16384 + sp;
    const float* wrow = wgt + co * CI;
    float acc = BIAS ? bias[co] : 0.0f;
    #pragma unroll
    for (int ci = 0; ci < CI; ++ci) acc += wrow[ci] * sb[ci * 16384];
    if constexpr (LEAKY) acc = (acc >= 0.0f) ? acc : 0.2f * acc;
    if constexpr (RESID) acc += resid[idx];
    out[idx] = acc;
}

// ---------------------------------------------------------------------------
// fc GEMM 64x64x16 (4x4/thread): C = unfold(src) @ fc1_w^T + fc1_b,
// emitted as bf16 hi/lo rows (8,961,FCP) with zero K-pad cols [196,224).
// ---------------------------------------------------------------------------
__global__ __launch_bounds__(256)
void gemm64_k(const float* __restrict__ Ag, const float* __restrict__ Bg,
              const float* __restrict__ bias,
              unsigned short* __restrict__ Dh, unsigned short* __restrict__ Dl,
              int M, int N, int Kd)
{
    __shared__ float As[64][17];
    __shared__ float Bs[64][17];
    const int tm0 = blockIdx.y * 64;
    const int tn0 = blockIdx.x * 64;
    const int tid = threadIdx.x;
    const int ty = tid >> 4, tx = tid & 15;
    float acc[4][4] = {};

    const int lm  = tid >> 2;
    const int lk  = (tid & 3) * 4;
    const int gm_l = tm0 + lm;
    int gb = 0, goff = 0;
    {
        int b  = gm_l / 961;
        int pi = gm_l - b * 961;
        int ih = pi / 31, iw = pi - ih * 31;
        gb   = b * 262144;
        goff = (ih * 4) * 128 + iw * 4;
    }

    for (int k0 = 0; k0 < Kd; k0 += 16) {
        #pragma unroll
        for (int j = 0; j < 4; ++j) {
            int gk = k0 + lk + j;
            float v = 0.0f;
            if (gm_l < M) {
                int c  = gk / 49, r = gk - c * 49;
                int kh = r / 7,  kw = r - kh * 7;
                v = Ag[gb + c * 16384 + goff + kh * 128 + kw];
            }
            As[lm][lk + j] = v;
        }
        {
            int gn = tn0 + lm;
            #pragma unroll
            for (int j = 0; j < 4; ++j) {
                int gk = k0 + lk + j;
                Bs[lm][lk + j] = (gn < N && gk < Kd)
                               ? Bg[(long long)gn * Kd + gk] : 0.0f;
            }
        }
        __syncthreads();
        #pragma unroll
        for (int kk = 0; kk < 16; ++kk) {
            float a[4], bv[4];
            #pragma unroll
            for (int i = 0; i < 4; ++i) a[i]  = As[ty * 4 + i][kk];
            #pragma unroll
            for (int j = 0; j < 4; ++j) bv[j] = Bs[tx * 4 + j][kk];
            #pragma unroll
            for (int i = 0; i < 4; ++i)
                #pragma unroll
                for (int j = 0; j < 4; ++j)
                    acc[i][j] += a[i] * bv[j];
        }
        __syncthreads();
    }

    #pragma unroll
    for (int i = 0; i < 4; ++i) {
        int gm = tm0 + ty * 4 + i;
        if (gm >= M) continue;
        int b = gm / 961, l = gm - b * 961;
        long long base = (long long)b * FCB + (long long)l * FCP;
        #pragma unroll
        for (int j = 0; j < 4; ++j) {
            int gn = tn0 + tx * 4 + j;
            if (gn >= FCP) continue;
            float v = (gn < 196) ? (acc[i][j] + bias[gn]) : 0.0f;
            unsigned short h = f2bf(v);
            Dh[base + gn] = h;
            Dl[base + gn] = f2bf(v - bf2f(h));
        }
    }
}

// ---------------------------------------------------------------------------
// Split-bf16 MFMA GEMM (3-term: hi*hi + hi*lo + lo*hi ~ fp32), 128x128 tile,
// 4 waves, XOR-swizzled LDS. X rows (M,k) and Y rows (N,k), k contiguous,
// Kd multiple of 32 (zero-padded).
// MODE 0 (A):  write A fp32 [l][m] + AT hi/lo bf16 [m][l] (ld KP, pre-zeroed)
// MODE 1 (Ti): ti = acc + Mb[l]; S[l][m] = A[l][m] * sigmoid(ti) * scale
//              (in-place over A; each element touched by exactly one lane)
// ---------------------------------------------------------------------------
template<int MODE>
__global__ __launch_bounds__(256)
void mfma3_k(const unsigned short* __restrict__ Xhi,
             const unsigned short* __restrict__ Xlo,
             const unsigned short* __restrict__ Yhi,
             const unsigned short* __restrict__ Ylo,
             int Mrows, int Nrows, int Kd,
             long long sX, long long sY,
             float* __restrict__ Afp,
             unsigned short* __restrict__ AThi,
             unsigned short* __restrict__ ATlo,
             const float* __restrict__ Mb)
{
    __shared__ unsigned short XsH[128 * 32], XsL[128 * 32];
    __shared__ unsigned short YsH[128 * 32], YsL[128 * 32];
    const int b   = blockIdx.z;
    const int tm0 = blockIdx.y * 128;
    const int tn0 = blockIdx.x * 128;
    const unsigned short* Xbh = Xhi + (long long)b * sX;
    const unsigned short* Xbl = Xlo + (long long)b * sX;
    const unsigned short* Ybh = Yhi + (long long)b * sY;
    const unsigned short* Ybl = Ylo + (long long)b * sY;
    const int tid = threadIdx.x;

    const int sr  = tid >> 1;
    const int sc0 = (tid & 1) * 2;
    const bool xok = (tm0 + sr) < Mrows;
    const bool yok = (tn0 + sr) < Nrows;
    const unsigned short* Xrh = Xbh + (long long)(tm0 + sr) * Kd;
    const unsigned short* Xrl = Xbl + (long long)(tm0 + sr) * Kd;
    const unsigned short* Yrh = Ybh + (long long)(tn0 + sr) * Kd;
    const unsigned short* Yrl = Ybl + (long long)(tn0 + sr) * Kd;
    const int swz = (sr >> 1) & 3;

    const int lane = tid & 63;
    const int wv   = tid >> 6;
    const int wm   = (wv >> 1) * 64, wn = (wv & 1) * 64;
    const int fr   = lane & 15;
    const int kq   = lane >> 4;

    floatx4 acc[4][4];
    #pragma unroll
    for (int i = 0; i < 4; ++i)
        #pragma unroll
        for (int j = 0; j < 4; ++j)
            acc[i][j] = (floatx4){0.f, 0.f, 0.f, 0.f};

    const short8x zz = {0,0,0,0,0,0,0,0};

    for (int k0 = 0; k0 < Kd; k0 += 32) {
        #pragma unroll
        for (int c = 0; c < 2; ++c) {
            int kc = sc0 + c;
            short8x xh = zz, xl = zz, yh = zz, yl = zz;
            if (xok) {
                xh = *(const short8x*)(Xrh + k0 + kc * 8);
                xl = *(const short8x*)(Xrl + k0 + kc * 8);
            }
            if (yok) {
                yh = *(const short8x*)(Yrh + k0 + kc * 8);
                yl = *(const short8x*)(Yrl + k0 + kc * 8);
            }
            int pc = kc ^ swz;
            *(short8x*)&XsH[sr * 32 + pc * 8] = xh;
            *(short8x*)&XsL[sr * 32 + pc * 8] = xl;
            *(short8x*)&YsH[sr * 32 + pc * 8] = yh;
            *(short8x*)&YsL[sr * 32 + pc * 8] = yl;
        }
        __syncthreads();
        short8x bh[4], bl[4];
        #pragma unroll
        for (int j = 0; j < 4; ++j) {
            int nr = wn + j * 16 + fr;
            int off = nr * 32 + ((kq ^ ((nr >> 1) & 3)) * 8);
            bh[j] = *(const short8x*)&YsH[off];
            bl[j] = *(const short8x*)&YsL[off];
        }
        #pragma unroll
        for (int i = 0; i < 4; ++i) {
            int mr = wm + i * 16 + fr;
            int off = mr * 32 + ((kq ^ ((mr >> 1) & 3)) * 8);
            short8x ah = *(const short8x*)&XsH[off];
            short8x al = *(const short8x*)&XsL[off];
            #pragma unroll
            for (int j = 0; j < 4; ++j) {
                acc[i][j] = __builtin_amdgcn_mfma_f32_16x16x32_bf16(ah, bh[j], acc[i][j], 0, 0, 0);
                acc[i][j] = __builtin_amdgcn_mfma_f32_16x16x32_bf16(ah, bl[j], acc[i][j], 0, 0, 0);
                acc[i][j] = __builtin_amdgcn_mfma_f32_16x16x32_bf16(al, bh[j], acc[i][j], 0, 0, 0);
            }
        }
        __syncthreads();
    }

    const float scale = 0.07142857142857142f;   // 196^-0.5
    if constexpr (MODE == 0) {
        float* Ab = Afp + (long long)b * AB;
        unsigned short* Th = AThi + (long long)b * ATB;
        unsigned short* Tl = ATlo + (long long)b * ATB;
        #pragma unroll
        for (int j = 0; j < 4; ++j) {
            int m = tn0 + wn + j * 16 + fr;
            if (m >= 961) continue;
            #pragma unroll
            for (int i = 0; i < 4; ++i) {
                int lb = tm0 + wm + i * 16 + kq * 4;
                if (lb >= 961) continue;
                ushort4x hv, lv;
                #pragma unroll
                for (int r = 0; r < 4; ++r) {
                    int l = lb + r;
                    float v = acc[i][j][r];
                    if (l < 961) {
                        Ab[(long long)l * 961 + m] = v;
                        unsigned short h = f2bf(v);
                        hv[r] = h;
                        lv[r] = f2bf(v - bf2f(h));
                    } else { hv[r] = 0; lv[r] = 0; }
                }
                long long toff = (long long)m * KP + lb;
                if (lb + 3 < 961) {
                    *(ushort4x*)(Th + toff) = hv;
                    *(ushort4x*)(Tl + toff) = lv;
                } else {
                    for (int r = 0; r < 4; ++r)
                        if (lb + r < 961) { Th[toff + r] = hv[r]; Tl[toff + r] = lv[r]; }
                }
            }
        }
    } else {
        float* Sb = Afp + (long long)b * AB;
        #pragma unroll
        for (int j = 0; j < 4; ++j) {
            int m = tn0 + wn + j * 16 + fr;
            if (m >= 961) continue;
            #pragma unroll
            for (int i = 0; i < 4; ++i) {
                int lb = tm0 + wm + i * 16 + kq * 4;
                #pragma unroll
                for (int r = 0; r < 4; ++r) {
                    int l = lb + r;
                    if (l >= 961) continue;
                    float ti = acc[i][j][r] + Mb[l];
                    float a  = Sb[(long long)l * 961 + m];
                    float mask = 1.0f / (1.0f + expf(-ti));
                    Sb[(long long)l * 961 + m] = a * mask * scale;
                }
            }
        }
    }
}

// ---------------------------------------------------------------------------
// Mw = mconv_w + mfc_w as bf16 hi/lo, rows KP-padded with zeros.
// ---------------------------------------------------------------------------
__global__ __launch_bounds__(256)
void add_mwbf_k(const float* __restrict__ a, const float* __restrict__ b,
                unsigned short* __restrict__ ch, unsigned short* __restrict__ cl)
{
    int i = blockIdx.x * 256 + threadIdx.x;     // 961*KP
    if (i >= 961 * KP) return;
    int n = i / KP, c = i - n * KP;
    float v = (c < 961) ? (a[n * 961 + c] + b[n * 961 + c]) : 0.0f;
    unsigned short h = f2bf(v);
    ch[i] = h;
    cl[i] = f2bf(v - bf2f(h));
}
__global__ __launch_bounds__(256)
void add_k(const float* __restrict__ a, const float* __restrict__ b,
           float* __restrict__ c, int n)
{
    int i = blockIdx.x * 256 + threadIdx.x;
    if (i < n) c[i] = a[i] + b[i];
}

// ---------------------------------------------------------------------------
// softmax over S rows (961): mb=(s!=0); Am fp32 -> d_out, bf16 (KP rows) -> ws
// ---------------------------------------------------------------------------
__global__ __launch_bounds__(256)
void softmax_mask_k(const float* __restrict__ S, float* __restrict__ Am,
                    unsigned short* __restrict__ Amb)
{
    int row = blockIdx.x;                // b*961 + l
    const float* srow = S + (long long)row * Lp;
    float*       orow = Am + (long long)row * Lp;
    unsigned short* brow = Amb + (long long)row * KP;
    int tid = threadIdx.x;

    float s[4], mb[4];
    float lmax = -INFINITY;
    #pragma unroll
    for (int j = 0; j < 4; ++j) {
        int m = tid + j * 256;
        if (m < Lp) {
            float v = srow[m];
            s[j]  = v;
            mb[j] = (v != 0.0f) ? 1.0f : 0.0f;
            lmax  = fmaxf(lmax, v);
        } else { s[j] = -INFINITY; mb[j] = 0.0f; }
    }
    __shared__ float red[256];
    red[tid] = lmax; __syncthreads();
    #pragma unroll
    for (int off = 128; off > 0; off >>= 1) {
        if (tid < off) red[tid] = fmaxf(red[tid], red[tid + off]);
        __syncthreads();
    }
    float rmax = red[0];
    __syncthreads();

    float e[4];
    float lsum = 0.0f;
    #pragma unroll
    for (int j = 0; j < 4; ++j) {
        int m = tid + j * 256;
        e[j] = (m < Lp) ? expf(s[j] - rmax) : 0.0f;
        lsum += e[j];
    }
    red[tid] = lsum; __syncthreads();
    #pragma unroll
    for (int off = 128; off > 0; off >>= 1) {
        if (tid < off) red[tid] += red[tid + off];
        __syncthreads();
    }
    float inv = 1.0f / red[0];
    #pragma unroll
    for (int j = 0; j < 4; ++j) {
        int m = tid + j * 256;
        if (m < Lp) {
            float v = e[j] * inv * mb[j];
            orow[m] = v;
            brow[m] = f2bf(v);
        } else if (m < KP) {
            brow[m] = 0;
        }
    }
}

// ---------------------------------------------------------------------------
// p62^T bf16: out[b][n][k] = x3[b, c(n), ih(k)*4+kh(n), iw(k)*4+kw(n)], ld KP.
// ---------------------------------------------------------------------------
__global__ __launch_bounds__(256)
void p62bt_k(const float* __restrict__ x3, unsigned short* __restrict__ out)
{
    int idx = blockIdx.x * 256 + threadIdx.x;      // 8*1568*124
    if (idx >= 8 * 1568 * 124) return;
    int ck = idx % 124;
    int t  = idx / 124;
    int n  = t % 1568;
    int b  = t / 1568;
    int c = n / 49, rr = n - c * 49;
    int kh = rr / 7, kw = rr - kh * 7;
    const float* src = x3 + (long long)b * 524288 + c * 16384 + kh * 128 + kw;
    int k = ck * 8;
    unsigned short v[8];
    #pragma unroll
    for (int j = 0; j < 8; ++j) {
        int kk = k + j;
        if (kk < Lp) {
            int ih = kk / 31, iw = kk - ih * 31;
            v[j] = f2bf(src[ih * 512 + iw * 4]);
        } else v[j] = 0;
    }
    *(short8x*)(out + ((long long)b * 1568 + n) * KP + k) = *(short8x*)v;
}

__global__ __launch_bounds__(256)
void zero_k(float* __restrict__ p, int n4)
{
    int i = blockIdx.x * 256 + threadIdx.x;
    if (i < n4) ((float4*)p)[i] = make_float4(0.f, 0.f, 0.f, 0.f);
}

// ---------------------------------------------------------------------------
// y = Am @ p62 via bf16 MFMA, fused fold (atomicAdd into image).
// ---------------------------------------------------------------------------
__global__ __launch_bounds__(256)
void ymfma_k(const unsigned short* __restrict__ Amb,
             const unsigned short* __restrict__ Pbt,
             float* __restrict__ fold)
{
    __shared__ unsigned short As[128 * 32];
    __shared__ unsigned short Bs[128 * 32];
    const int b   = blockIdx.z;
    const int tm0 = blockIdx.y * 128;   // l
    const int tn0 = blockIdx.x * 128;   // n
    const unsigned short* Ab = Amb + (long long)b * AMBB;
    const unsigned short* Bb = Pbt + (long long)b * PBTB;
    const int tid = threadIdx.x;

    const int sr  = tid >> 1;
    const int sc0 = (tid & 1) * 2;
    const bool aok = (tm0 + sr) < Lp;
    const bool bok = (tn0 + sr) < F62;
    const unsigned short* Arow = Ab + (long long)(tm0 + sr) * KP;
    const unsigned short* Brow = Bb + (long long)(tn0 + sr) * KP;
    const int swz = (sr >> 1) & 3;

    const int lane = tid & 63;
    const int wv   = tid >> 6;
    const int wm   = (wv >> 1) * 64, wn = (wv & 1) * 64;
    const int fr   = lane & 15;
    const int kq   = lane >> 4;

    floatx4 acc[4][4];
    #pragma unroll
    for (int i = 0; i < 4; ++i)
        #pragma unroll
        for (int j = 0; j < 4; ++j)
            acc[i][j] = (floatx4){0.f, 0.f, 0.f, 0.f};

    const short8x zz = {0,0,0,0,0,0,0,0};

    for (int k0 = 0; k0 < Lp; k0 += 32) {
        #pragma unroll
        for (int c = 0; c < 2; ++c) {
            int kc = sc0 + c;
            short8x va = zz, vb = zz;
            if (aok) va = *(const short8x*)(Arow + k0 + kc * 8);
            if (bok) vb = *(const short8x*)(Brow + k0 + kc * 8);
            int pc = kc ^ swz;
            *(short8x*)&As[sr * 32 + pc * 8] = va;
            *(short8x*)&Bs[sr * 32 + pc * 8] = vb;
        }
        __syncthreads();
        short8x af[4], bfr[4];
        #pragma unroll
        for (int i = 0; i < 4; ++i) {
            int mr = wm + i * 16 + fr;
            af[i] = *(const short8x*)&As[mr * 32 + ((kq ^ ((mr >> 1) & 3)) * 8)];
        }
        #pragma unroll
        for (int j = 0; j < 4; ++j) {
            int nr = wn + j * 16 + fr;
            bfr[j] = *(const short8x*)&Bs[nr * 32 + ((kq ^ ((nr >> 1) & 3)) * 8)];
        }
        #pragma unroll
        for (int i = 0; i < 4; ++i)
            #pragma unroll
            for (int j = 0; j < 4; ++j)
                acc[i][j] = __builtin_amdgcn_mfma_f32_16x16x32_bf16(
                                af[i], bfr[j], acc[i][j], 0, 0, 0);
        __syncthreads();
    }

    float* Fb = fold + (long long)b * 524288;
    #pragma unroll
    for (int j = 0; j < 4; ++j) {
        int col = tn0 + wn + j * 16 + fr;          // n
        if (col >= F62) continue;
        int c = col / 49, rr = col - c * 49;
        int kh = rr / 7, kw = rr - kh * 7;
        int pbase = c * 16384 + kh * 128 + kw;
        #pragma unroll
        for (int i = 0; i < 4; ++i) {
            #pragma unroll
            for (int r = 0; r < 4; ++r) {
                int l = tm0 + wm + i * 16 + kq * 4 + r;
                if (l >= Lp) continue;
                int ih = l / 31, iw = l - ih * 31;
                atomicAdd(Fb + pbase + ih * 512 + iw * 4, acc[i][j][r]);
            }
        }
    }
}

// ---------------------------------------------------------------------------
// Launch
// ---------------------------------------------------------------------------
extern "C" void kernel_launch(void* const* d_in, const int* in_sizes, int n_in,
                              void* d_out, int out_size, void* d_ws, size_t ws_size,
                              hipStream_t stream)
{
    const float* x       = (const float*)d_in[0];
    const float* g_w     = (const float*)d_in[1];
    const float* g_b     = (const float*)d_in[2];
    const float* w_w     = (const float*)d_in[3];
    const float* w_b     = (const float*)d_in[4];
    const float* theta_w = (const float*)d_in[5];
    const float* theta_b = (const float*)d_in[6];
    const float* fc1_w   = (const float*)d_in[7];
    const float* fc1_b   = (const float*)d_in[8];
    const float* mconv_w = (const float*)d_in[9];
    const float* mconv_b = (const float*)d_in[10];
    const float* mfc_w   = (const float*)d_in[11];
    const float* mfc_b   = (const float*)d_in[12];
    const float* c1_w    = (const float*)d_in[13];
    const float* c2_w    = (const float*)d_in[14];

    float* Am_out    = (float*)d_out;
    float* final_out = Am_out + (size_t)Bn * Lp * Lp;

    // Workspace (floats), total ~27.80M floats = ~111 MB
    float* ws = (float*)d_ws;
    float* x1    = ws;                        // 2,097,152
    float* x2    = ws + 2097152;              // 2,097,152
    float* x3    = ws + 4194304;              // 4,194,304
    unsigned short* xf_hi = (unsigned short*)(ws + 8388608);    // 1,722,112 shorts
    unsigned short* xf_lo = (unsigned short*)(ws + 9249664);
    unsigned short* wf_hi = (unsigned short*)(ws + 10110720);
    unsigned short* wf_lo = (unsigned short*)(ws + 10971776);
    float* Abuf  = ws + 11832832;             // 7,388,168 (A, then S, then p62bT)
    unsigned short* AT_hi = (unsigned short*)(ws + 19221000);   // 7,626,496 shorts
    unsigned short* AT_lo = (unsigned short*)(ws + 23034248);
    unsigned short* Mw_hi = (unsigned short*)(ws + 26847496);   // 953,312 shorts
    unsigned short* Mw_lo = (unsigned short*)(ws + 27324152);
    float* Mb    = ws + 27800808;             // 1,024
    unsigned short* Am_bf16 = (unsigned short*)x1;      // 7,626,496 shorts <= x1+x2
    unsigned short* p62bT   = (unsigned short*)Abuf;    // 12,443,648 shorts <= Abuf

    // Mw hi/lo (+pad), Mb, zero AT pads
    add_mwbf_k<<<3724, 256, 0, stream>>>(mconv_w, mfc_w, Mw_hi, Mw_lo);
    add_k<<<4, 256, 0, stream>>>(mconv_b, mfc_b, Mb, 961);
    zero_k<<<7448, 256, 0, stream>>>((float*)AT_hi, 1906624);   // AT hi+lo contiguous

    // x1, x2 = dual 3x3 convs (strip)
    conv3x3s_k<true, true, false><<<2048, 256, 0, stream>>>(
        x, g_w, g_b, w_w, w_b, x1, x2);

    // x3 = conv1x1(x1)
    conv1x1_k<true, false, false><<<16384, 256, 0, stream>>>(
        x1, theta_w, theta_b, nullptr, x3);

    // xf, wf as bf16 hi/lo (K-padded)
    gemm64_k<<<dim3(4, 121, 1), 256, 0, stream>>>(
        x1, fc1_w, fc1_b, xf_hi, xf_lo, 7688, FOUT, FIN);
    gemm64_k<<<dim3(4, 121, 1), 256, 0, stream>>>(
        x2, fc1_w, fc1_b, wf_hi, wf_lo, 7688, FOUT, FIN);

    // A = wf @ xf^T (split-bf16 MFMA); writes A fp32 + AT hi/lo
    mfma3_k<0><<<dim3(8, 8, 8), 256, 0, stream>>>(
        wf_hi, wf_lo, xf_hi, xf_lo, Lp, Lp, FCP, FCB, FCB,
        Abuf, AT_hi, AT_lo, nullptr);

    // Ti = Mw @ A + Mb; S = A*sigmoid(Ti)*scale in-place over A
    mfma3_k<1><<<dim3(8, 8, 8), 256, 0, stream>>>(
        Mw_hi, Mw_lo, AT_hi, AT_lo, Lp, Lp, KP, 0LL, ATB,
        Abuf, nullptr, nullptr, Mb);

    // Am = softmax(S)*(S!=0) -> d_out fp32 + bf16
    softmax_mask_k<<<7688, 256, 0, stream>>>(Abuf, Am_out, Am_bf16);

    // p62^T bf16 (aliases Abuf; S dead)
    p62bt_k<<<6077, 256, 0, stream>>>(x3, p62bT);

    // zero fold target
    zero_k<<<4096, 256, 0, stream>>>(x3, 1048576);

    // y = Am @ p62 folded into x3
    ymfma_k<<<dim3(13, 8, 8), 256, 0, stream>>>(Am_bf16, p62bT, x3);

    // o1 = leaky(conv3x3(refpad(fold)))
    conv3x3s_k<false, false, true><<<2048, 256, 0, stream>>>(
        x3, c1_w, nullptr, nullptr, nullptr, x1, nullptr);

    // final = x + leaky(conv1x1(o1))
    conv1x1_k<false, true, true><<<16384, 256, 0, stream>>>(
        x1, c2_w, nullptr, x, final_out);
}

// Round 5
// 786.519 us; speedup vs baseline: 2.5175x; 1.3681x over previous
//
#include <hip/hip_runtime.h>
#include <math.h>

namespace {
constexpr int Bn   = 8;
constexpr int CIN  = 32;
constexpr int CI   = 16;
constexpr int Lp   = 961;     // 31*31 patches
constexpr int FIN  = 784;     // 16*49
constexpr int FOUT = 196;
constexpr int F62  = 1568;    // 32*49

constexpr int FCP  = 224;                 // fc K-pad (196 -> 7*32)
constexpr long long FCB = 961LL * FCP;    // per-batch fc rows (shorts)
constexpr int KP   = 992;                 // L K-pad (961 -> 31*32)
constexpr long long ATB  = 961LL * KP;    // AT per-batch (shorts)
constexpr long long AMBB = 961LL * KP;    // Am_bf16 per-batch (shorts)
constexpr long long PBTB = 1568LL * KP;   // p62bT per-batch (shorts)
constexpr long long AB   = 961LL * 961;   // A/S per-batch (floats)
constexpr int YLD  = 964;                 // yT leading dim (shorts)
constexpr long long YB = 1568LL * YLD;    // yT per-batch (shorts)
}

typedef __attribute__((ext_vector_type(8))) short short8x;
typedef __attribute__((ext_vector_type(4))) float floatx4;
typedef __attribute__((ext_vector_type(4))) unsigned short ushort4x;

static __device__ __forceinline__ unsigned short f2bf(float x) {
    unsigned int u = __builtin_bit_cast(unsigned int, x);
    u += 0x7fffu + ((u >> 16) & 1u);           // RNE
    return (unsigned short)(u >> 16);
}
static __device__ __forceinline__ float bf2f(unsigned short h) {
    return __builtin_bit_cast(float, ((unsigned int)h) << 16);
}

// ---------------------------------------------------------------------------
// 3x3 conv, reflect-pad(1), 32ch -> 16ch, 4-pixel strip per thread.
// ---------------------------------------------------------------------------
template<bool DUAL, bool BIAS, bool LEAKY>
__global__ __launch_bounds__(256)
void conv3x3s_k(const float* __restrict__ x,
                const float* __restrict__ w1, const float* __restrict__ b1,
                const float* __restrict__ w2, const float* __restrict__ b2,
                float* __restrict__ o1, float* __restrict__ o2)
{
    int idx = blockIdx.x * 256 + threadIdx.x;   // 8*16*128*32 = 524288 exact
    int w0 = (idx & 31) * 4;
    int h  = (idx >> 5) & 127;
    int co = (idx >> 12) & 15;
    int b  = idx >> 16;
    int hm = (h == 0)   ? 1   : h - 1;
    int hp = (h == 127) ? 126 : h + 1;
    int lw = (w0 == 0)   ? 1   : w0 - 1;
    int rw = (w0 == 124) ? 126 : w0 + 4;
    int rows[3] = { hm * 128, h * 128, hp * 128 };

    float a1[4], a2[4];
    float bb1 = BIAS ? b1[co] : 0.0f;
    float bb2 = (DUAL && BIAS) ? b2[co] : 0.0f;
    #pragma unroll
    for (int o = 0; o < 4; ++o) { a1[o] = bb1; a2[o] = bb2; }

    const float* xb  = x + (size_t)b * CIN * 16384;
    const float* w1c = w1 + co * CIN * 9;
    const float* w2c = DUAL ? (w2 + co * CIN * 9) : nullptr;

    for (int ci = 0; ci < CIN; ++ci) {
        const float* xc = xb + ci * 16384;
        const float* q1 = w1c + ci * 9;
        const float* q2 = DUAL ? (w2c + ci * 9) : nullptr;
        #pragma unroll
        for (int r = 0; r < 3; ++r) {
            int ro = rows[r];
            float4 m4 = *(const float4*)(xc + ro + w0);
            float v[6];
            v[0] = xc[ro + lw];
            v[1] = m4.x; v[2] = m4.y; v[3] = m4.z; v[4] = m4.w;
            v[5] = xc[ro + rw];
            float c0 = q1[r*3+0], c1 = q1[r*3+1], c2 = q1[r*3+2];
            #pragma unroll
            for (int o = 0; o < 4; ++o)
                a1[o] += v[o]*c0 + v[o+1]*c1 + v[o+2]*c2;
            if constexpr (DUAL) {
                float d0 = q2[r*3+0], d1 = q2[r*3+1], d2 = q2[r*3+2];
                #pragma unroll
                for (int o = 0; o < 4; ++o)
                    a2[o] += v[o]*d0 + v[o+1]*d1 + v[o+2]*d2;
            }
        }
    }
    size_t ob = (((size_t)b * 16 + co) * 128 + h) * 128 + w0;
    if constexpr (LEAKY) {
        #pragma unroll
        for (int o = 0; o < 4; ++o) a1[o] = (a1[o] >= 0.f) ? a1[o] : 0.2f * a1[o];
    }
    *(float4*)(o1 + ob) = make_float4(a1[0], a1[1], a1[2], a1[3]);
    if constexpr (DUAL)
        *(float4*)(o2 + ob) = make_float4(a2[0], a2[1], a2[2], a2[3]);
}

// ---------------------------------------------------------------------------
// 1x1 conv, 16ch -> 32ch, optional bias/leaky/residual.
// ---------------------------------------------------------------------------
template<bool BIAS, bool LEAKY, bool RESID>
__global__ __launch_bounds__(256)
void conv1x1_k(const float* __restrict__ src, const float* __restrict__ wgt,
               const float* __restrict__ bias, const float* __restrict__ resid,
               float* __restrict__ out)
{
    int idx = blockIdx.x * 256 + threadIdx.x;   // B*32*16384 exact
    int sp = idx & 16383;
    int co = (idx >> 14) & 31;
    int b  = idx >> 19;
    const float* sb   = src + (size_t)b * CI * 16384 + sp;
    const float* wrow = wgt + co * CI;
    float acc = BIAS ? bias[co] : 0.0f;
    #pragma unroll
    for (int ci = 0; ci < CI; ++ci) acc += wrow[ci] * sb[ci * 16384];
    if constexpr (LEAKY) acc = (acc >= 0.0f) ? acc : 0.2f * acc;
    if constexpr (RESID) acc += resid[idx];
    out[idx] = acc;
}

// ---------------------------------------------------------------------------
// fc1_w -> hi/lo bf16, padded to (256 rows, 800 k).
// ---------------------------------------------------------------------------
__global__ __launch_bounds__(256)
void fc1w_prep_k(const float* __restrict__ w,
                 unsigned short* __restrict__ Wh, unsigned short* __restrict__ Wl)
{
    int i = blockIdx.x * 256 + threadIdx.x;     // 256*800 exact
    int n = i / 800, k = i - n * 800;
    float v = (n < 196 && k < 784) ? w[n * 784 + k] : 0.0f;
    unsigned short h = f2bf(v);
    Wh[i] = h;
    Wl[i] = f2bf(v - bf2f(h));
}

// ---------------------------------------------------------------------------
// fc GEMM via split-bf16 MFMA (3-term): D = unfold(xsrc) @ fc1_w^T + fc1_b,
// 64x64 tile (4 waves of 32x32), gather-A with on-the-fly hi/lo split.
// Emits hi/lo bf16 rows (8,961,FCP), zero pad cols [196,224).
// ---------------------------------------------------------------------------
__global__ __launch_bounds__(256)
void fcmfma_k(const float* __restrict__ xsrc,
              const unsigned short* __restrict__ Wh,
              const unsigned short* __restrict__ Wl,
              const float* __restrict__ bias,
              unsigned short* __restrict__ Dh, unsigned short* __restrict__ Dl)
{
    __shared__ unsigned short AsH[64*32], AsL[64*32], BsH[64*32], BsL[64*32];
    const int tid = threadIdx.x;
    const int tm0 = (blockIdx.x >> 2) * 64;     // 121 m-tiles (7744 >= 7688)
    const int tn0 = (blockIdx.x & 3) * 64;      // 4 n-tiles (256)

    const int lr = tid >> 2;          // staged row 0..63
    const int lc = tid & 3;           // k-chunk 0..3
    const int gm = tm0 + lr;
    const bool mok = gm < 7688;
    int gbase = 0;
    if (mok) {
        int b = gm / 961, pi = gm - b * 961;
        int ih = pi / 31, iw = pi - ih * 31;
        gbase = b * 262144 + ih * 512 + iw * 4;
    }
    const int pc = ((lc ^ ((lr >> 1) & 3))) * 8;
    const unsigned short* Whr = Wh + (tn0 + lr) * 800;
    const unsigned short* Wlr = Wl + (tn0 + lr) * 800;

    const int lane = tid & 63, wv = tid >> 6;
    const int wm = (wv >> 1) * 32, wn = (wv & 1) * 32;
    const int fr = lane & 15, kq = lane >> 4;

    floatx4 acc[2][2];
    #pragma unroll
    for (int i = 0; i < 2; ++i)
        #pragma unroll
        for (int j = 0; j < 2; ++j)
            acc[i][j] = (floatx4){0.f, 0.f, 0.f, 0.f};

    for (int k0 = 0; k0 < 800; k0 += 32) {
        unsigned short hv[8], lv[8];
        #pragma unroll
        for (int j = 0; j < 8; ++j) {
            int k = k0 + lc * 8 + j;
            float v = 0.0f;
            if (mok && k < 784) {
                int c  = k / 49, r = k - c * 49;
                int kh = r / 7,  kw = r - kh * 7;
                v = xsrc[gbase + c * 16384 + kh * 128 + kw];
            }
            unsigned short h = f2bf(v);
            hv[j] = h; lv[j] = f2bf(v - bf2f(h));
        }
        *(short8x*)&AsH[lr * 32 + pc] = *(short8x*)hv;
        *(short8x*)&AsL[lr * 32 + pc] = *(short8x*)lv;
        *(short8x*)&BsH[lr * 32 + pc] = *(const short8x*)(Whr + k0 + lc * 8);
        *(short8x*)&BsL[lr * 32 + pc] = *(const short8x*)(Wlr + k0 + lc * 8);
        __syncthreads();
        short8x ah[2], al[2], bh[2], bl[2];
        #pragma unroll
        for (int i = 0; i < 2; ++i) {
            int mr = wm + i * 16 + fr;
            int off = mr * 32 + ((kq ^ ((mr >> 1) & 3)) * 8);
            ah[i] = *(const short8x*)&AsH[off];
            al[i] = *(const short8x*)&AsL[off];
        }
        #pragma unroll
        for (int j = 0; j < 2; ++j) {
            int nr = wn + j * 16 + fr;
            int off = nr * 32 + ((kq ^ ((nr >> 1) & 3)) * 8);
            bh[j] = *(const short8x*)&BsH[off];
            bl[j] = *(const short8x*)&BsL[off];
        }
        #pragma unroll
        for (int i = 0; i < 2; ++i)
            #pragma unroll
            for (int j = 0; j < 2; ++j) {
                acc[i][j] = __builtin_amdgcn_mfma_f32_16x16x32_bf16(ah[i], bh[j], acc[i][j], 0, 0, 0);
                acc[i][j] = __builtin_amdgcn_mfma_f32_16x16x32_bf16(ah[i], bl[j], acc[i][j], 0, 0, 0);
                acc[i][j] = __builtin_amdgcn_mfma_f32_16x16x32_bf16(al[i], bh[j], acc[i][j], 0, 0, 0);
            }
        __syncthreads();
    }

    #pragma unroll
    for (int j = 0; j < 2; ++j) {
        int n = tn0 + wn + j * 16 + fr;
        if (n >= FCP) continue;
        float bn = (n < 196) ? bias[n] : 0.0f;
        #pragma unroll
        for (int i = 0; i < 2; ++i) {
            #pragma unroll
            for (int r = 0; r < 4; ++r) {
                int l = tm0 + wm + i * 16 + kq * 4 + r;
                if (l >= 7688) continue;
                int b = l / 961, pi = l - b * 961;
                float v = (n < 196) ? (acc[i][j][r] + bn) : 0.0f;
                long long base = (long long)b * FCB + (long long)pi * FCP + n;
                unsigned short h = f2bf(v);
                Dh[base] = h;
                Dl[base] = f2bf(v - bf2f(h));
            }
        }
    }
}

// ---------------------------------------------------------------------------
// Split-bf16 MFMA GEMM (3-term), 128x128 tile, flat grid (batch-per-XCD).
// MODE 0 (A):  write A fp32 [l][m] + AT hi/lo bf16 [m][l] (ld KP, pre-zeroed)
// MODE 1 (Ti): ti = acc + Mb[l]; S[l][m] = A[l][m] * sigmoid(ti) * scale
// ---------------------------------------------------------------------------
template<int MODE>
__global__ __launch_bounds__(256)
void mfma3_k(const unsigned short* __restrict__ Xhi,
             const unsigned short* __restrict__ Xlo,
             const unsigned short* __restrict__ Yhi,
             const unsigned short* __restrict__ Ylo,
             int Mrows, int Nrows, int Kd,
             long long sX, long long sY,
             float* __restrict__ Afp,
             unsigned short* __restrict__ AThi,
             unsigned short* __restrict__ ATlo,
             const float* __restrict__ Mb)
{
    __shared__ unsigned short XsH[128 * 32], XsL[128 * 32];
    __shared__ unsigned short YsH[128 * 32], YsL[128 * 32];
    const int b   = blockIdx.x & 7;             // batch-per-XCD swizzle
    const int t   = blockIdx.x >> 3;
    const int tm0 = (t >> 3) * 128;
    const int tn0 = (t & 7) * 128;
    const unsigned short* Xbh = Xhi + (long long)b * sX;
    const unsigned short* Xbl = Xlo + (long long)b * sX;
    const unsigned short* Ybh = Yhi + (long long)b * sY;
    const unsigned short* Ybl = Ylo + (long long)b * sY;
    const int tid = threadIdx.x;

    const int sr  = tid >> 1;
    const int sc0 = (tid & 1) * 2;
    const bool xok = (tm0 + sr) < Mrows;
    const bool yok = (tn0 + sr) < Nrows;
    const unsigned short* Xrh = Xbh + (long long)(tm0 + sr) * Kd;
    const unsigned short* Xrl = Xbl + (long long)(tm0 + sr) * Kd;
    const unsigned short* Yrh = Ybh + (long long)(tn0 + sr) * Kd;
    const unsigned short* Yrl = Ybl + (long long)(tn0 + sr) * Kd;
    const int swz = (sr >> 1) & 3;

    const int lane = tid & 63;
    const int wv   = tid >> 6;
    const int wm   = (wv >> 1) * 64, wn = (wv & 1) * 64;
    const int fr   = lane & 15;
    const int kq   = lane >> 4;

    floatx4 acc[4][4];
    #pragma unroll
    for (int i = 0; i < 4; ++i)
        #pragma unroll
        for (int j = 0; j < 4; ++j)
            acc[i][j] = (floatx4){0.f, 0.f, 0.f, 0.f};

    const short8x zz = {0,0,0,0,0,0,0,0};

    for (int k0 = 0; k0 < Kd; k0 += 32) {
        #pragma unroll
        for (int c = 0; c < 2; ++c) {
            int kc = sc0 + c;
            short8x xh = zz, xl = zz, yh = zz, yl = zz;
            if (xok) {
                xh = *(const short8x*)(Xrh + k0 + kc * 8);
                xl = *(const short8x*)(Xrl + k0 + kc * 8);
            }
            if (yok) {
                yh = *(const short8x*)(Yrh + k0 + kc * 8);
                yl = *(const short8x*)(Yrl + k0 + kc * 8);
            }
            int pc = kc ^ swz;
            *(short8x*)&XsH[sr * 32 + pc * 8] = xh;
            *(short8x*)&XsL[sr * 32 + pc * 8] = xl;
            *(short8x*)&YsH[sr * 32 + pc * 8] = yh;
            *(short8x*)&YsL[sr * 32 + pc * 8] = yl;
        }
        __syncthreads();
        short8x bh[4], bl[4];
        #pragma unroll
        for (int j = 0; j < 4; ++j) {
            int nr = wn + j * 16 + fr;
            int off = nr * 32 + ((kq ^ ((nr >> 1) & 3)) * 8);
            bh[j] = *(const short8x*)&YsH[off];
            bl[j] = *(const short8x*)&YsL[off];
        }
        #pragma unroll
        for (int i = 0; i < 4; ++i) {
            int mr = wm + i * 16 + fr;
            int off = mr * 32 + ((kq ^ ((mr >> 1) & 3)) * 8);
            short8x ah = *(const short8x*)&XsH[off];
            short8x al = *(const short8x*)&XsL[off];
            #pragma unroll
            for (int j = 0; j < 4; ++j) {
                acc[i][j] = __builtin_amdgcn_mfma_f32_16x16x32_bf16(ah, bh[j], acc[i][j], 0, 0, 0);
                acc[i][j] = __builtin_amdgcn_mfma_f32_16x16x32_bf16(ah, bl[j], acc[i][j], 0, 0, 0);
                acc[i][j] = __builtin_amdgcn_mfma_f32_16x16x32_bf16(al, bh[j], acc[i][j], 0, 0, 0);
            }
        }
        __syncthreads();
    }

    const float scale = 0.07142857142857142f;   // 196^-0.5
    if constexpr (MODE == 0) {
        float* Ab = Afp + (long long)b * AB;
        unsigned short* Th = AThi + (long long)b * ATB;
        unsigned short* Tl = ATlo + (long long)b * ATB;
        #pragma unroll
        for (int j = 0; j < 4; ++j) {
            int m = tn0 + wn + j * 16 + fr;
            if (m >= 961) continue;
            #pragma unroll
            for (int i = 0; i < 4; ++i) {
                int lb = tm0 + wm + i * 16 + kq * 4;
                if (lb >= 961) continue;
                ushort4x hv, lv;
                #pragma unroll
                for (int r = 0; r < 4; ++r) {
                    int l = lb + r;
                    float v = acc[i][j][r];
                    if (l < 961) {
                        Ab[(long long)l * 961 + m] = v;
                        unsigned short h = f2bf(v);
                        hv[r] = h;
                        lv[r] = f2bf(v - bf2f(h));
                    } else { hv[r] = 0; lv[r] = 0; }
                }
                long long toff = (long long)m * KP + lb;
                if (lb + 3 < 961) {
                    *(ushort4x*)(Th + toff) = hv;
                    *(ushort4x*)(Tl + toff) = lv;
                } else {
                    for (int r = 0; r < 4; ++r)
                        if (lb + r < 961) { Th[toff + r] = hv[r]; Tl[toff + r] = lv[r]; }
                }
            }
        }
    } else {
        float* Sb = Afp + (long long)b * AB;
        #pragma unroll
        for (int j = 0; j < 4; ++j) {
            int m = tn0 + wn + j * 16 + fr;
            if (m >= 961) continue;
            #pragma unroll
            for (int i = 0; i < 4; ++i) {
                int lb = tm0 + wm + i * 16 + kq * 4;
                #pragma unroll
                for (int r = 0; r < 4; ++r) {
                    int l = lb + r;
                    if (l >= 961) continue;
                    float ti = acc[i][j][r] + Mb[l];
                    float a  = Sb[(long long)l * 961 + m];
                    float mask = 1.0f / (1.0f + expf(-ti));
                    Sb[(long long)l * 961 + m] = a * mask * scale;
                }
            }
        }
    }
}

// ---------------------------------------------------------------------------
// Mw = mconv_w + mfc_w as bf16 hi/lo, rows KP-padded with zeros.
// ---------------------------------------------------------------------------
__global__ __launch_bounds__(256)
void add_mwbf_k(const float* __restrict__ a, const float* __restrict__ b,
                unsigned short* __restrict__ ch, unsigned short* __restrict__ cl)
{
    int i = blockIdx.x * 256 + threadIdx.x;     // 961*KP
    if (i >= 961 * KP) return;
    int n = i / KP, c = i - n * KP;
    float v = (c < 961) ? (a[n * 961 + c] + b[n * 961 + c]) : 0.0f;
    unsigned short h = f2bf(v);
    ch[i] = h;
    cl[i] = f2bf(v - bf2f(h));
}
__global__ __launch_bounds__(256)
void add_k(const float* __restrict__ a, const float* __restrict__ b,
           float* __restrict__ c, int n)
{
    int i = blockIdx.x * 256 + threadIdx.x;
    if (i < n) c[i] = a[i] + b[i];
}

// ---------------------------------------------------------------------------
// softmax over S rows (961): mb=(s!=0); Am fp32 -> d_out, bf16 (KP rows) -> ws
// ---------------------------------------------------------------------------
__global__ __launch_bounds__(256)
void softmax_mask_k(const float* __restrict__ S, float* __restrict__ Am,
                    unsigned short* __restrict__ Amb)
{
    int row = blockIdx.x;                // b*961 + l
    const float* srow = S + (long long)row * Lp;
    float*       orow = Am + (long long)row * Lp;
    unsigned short* brow = Amb + (long long)row * KP;
    int tid = threadIdx.x;

    float s[4], mb[4];
    float lmax = -INFINITY;
    #pragma unroll
    for (int j = 0; j < 4; ++j) {
        int m = tid + j * 256;
        if (m < Lp) {
            float v = srow[m];
            s[j]  = v;
            mb[j] = (v != 0.0f) ? 1.0f : 0.0f;
            lmax  = fmaxf(lmax, v);
        } else { s[j] = -INFINITY; mb[j] = 0.0f; }
    }
    __shared__ float red[256];
    red[tid] = lmax; __syncthreads();
    #pragma unroll
    for (int off = 128; off > 0; off >>= 1) {
        if (tid < off) red[tid] = fmaxf(red[tid], red[tid + off]);
        __syncthreads();
    }
    float rmax = red[0];
    __syncthreads();

    float e[4];
    float lsum = 0.0f;
    #pragma unroll
    for (int j = 0; j < 4; ++j) {
        int m = tid + j * 256;
        e[j] = (m < Lp) ? expf(s[j] - rmax) : 0.0f;
        lsum += e[j];
    }
    red[tid] = lsum; __syncthreads();
    #pragma unroll
    for (int off = 128; off > 0; off >>= 1) {
        if (tid < off) red[tid] += red[tid + off];
        __syncthreads();
    }
    float inv = 1.0f / red[0];
    #pragma unroll
    for (int j = 0; j < 4; ++j) {
        int m = tid + j * 256;
        if (m < Lp) {
            float v = e[j] * inv * mb[j];
            orow[m] = v;
            brow[m] = f2bf(v);
        } else if (m < KP) {
            brow[m] = 0;
        }
    }
}

// ---------------------------------------------------------------------------
// p62^T bf16: out[b][n][k] = x3[b, c(n), ih(k)*4+kh(n), iw(k)*4+kw(n)], ld KP.
// ---------------------------------------------------------------------------
__global__ __launch_bounds__(256)
void p62bt_k(const float* __restrict__ x3, unsigned short* __restrict__ out)
{
    int idx = blockIdx.x * 256 + threadIdx.x;      // 8*1568*124
    if (idx >= 8 * 1568 * 124) return;
    int ck = idx % 124;
    int t  = idx / 124;
    int n  = t % 1568;
    int b  = t / 1568;
    int c = n / 49, rr = n - c * 49;
    int kh = rr / 7, kw = rr - kh * 7;
    const float* src = x3 + (long long)b * 524288 + c * 16384 + kh * 128 + kw;
    int k = ck * 8;
    unsigned short v[8];
    #pragma unroll
    for (int j = 0; j < 8; ++j) {
        int kk = k + j;
        if (kk < Lp) {
            int ih = kk / 31, iw = kk - ih * 31;
            v[j] = f2bf(src[ih * 512 + iw * 4]);
        } else v[j] = 0;
    }
    *(short8x*)(out + ((long long)b * 1568 + n) * KP + k) = *(short8x*)v;
}

__global__ __launch_bounds__(256)
void zero_k(float* __restrict__ p, int n4)
{
    int i = blockIdx.x * 256 + threadIdx.x;
    if (i < n4) ((float4*)p)[i] = make_float4(0.f, 0.f, 0.f, 0.f);
}

// ---------------------------------------------------------------------------
// y = Am @ p62 via bf16 MFMA, writes yT bf16 [b][n][l] (ld YLD). Flat grid,
// batch-per-XCD swizzle. No atomics.
// ---------------------------------------------------------------------------
__global__ __launch_bounds__(256)
void ymfma_k(const unsigned short* __restrict__ Amb,
             const unsigned short* __restrict__ Pbt,
             unsigned short* __restrict__ yT)
{
    __shared__ unsigned short As[128 * 32];
    __shared__ unsigned short Bs[128 * 32];
    const int b   = blockIdx.x & 7;
    const int t   = blockIdx.x >> 3;            // 104 = 13 n x 8 m
    const int tn0 = (t % 13) * 128;
    const int tm0 = (t / 13) * 128;
    const unsigned short* Ab = Amb + (long long)b * AMBB;
    const unsigned short* Bb = Pbt + (long long)b * PBTB;
    const int tid = threadIdx.x;

    const int sr  = tid >> 1;
    const int sc0 = (tid & 1) * 2;
    const bool aok = (tm0 + sr) < Lp;
    const bool bok = (tn0 + sr) < F62;
    const unsigned short* Arow = Ab + (long long)(tm0 + sr) * KP;
    const unsigned short* Brow = Bb + (long long)(tn0 + sr) * KP;
    const int swz = (sr >> 1) & 3;

    const int lane = tid & 63;
    const int wv   = tid >> 6;
    const int wm   = (wv >> 1) * 64, wn = (wv & 1) * 64;
    const int fr   = lane & 15;
    const int kq   = lane >> 4;

    floatx4 acc[4][4];
    #pragma unroll
    for (int i = 0; i < 4; ++i)
        #pragma unroll
        for (int j = 0; j < 4; ++j)
            acc[i][j] = (floatx4){0.f, 0.f, 0.f, 0.f};

    const short8x zz = {0,0,0,0,0,0,0,0};

    for (int k0 = 0; k0 < Lp; k0 += 32) {
        #pragma unroll
        for (int c = 0; c < 2; ++c) {
            int kc = sc0 + c;
            short8x va = zz, vb = zz;
            if (aok) va = *(const short8x*)(Arow + k0 + kc * 8);
            if (bok) vb = *(const short8x*)(Brow + k0 + kc * 8);
            int pc = kc ^ swz;
            *(short8x*)&As[sr * 32 + pc * 8] = va;
            *(short8x*)&Bs[sr * 32 + pc * 8] = vb;
        }
        __syncthreads();
        short8x af[4], bfr[4];
        #pragma unroll
        for (int i = 0; i < 4; ++i) {
            int mr = wm + i * 16 + fr;
            af[i] = *(const short8x*)&As[mr * 32 + ((kq ^ ((mr >> 1) & 3)) * 8)];
        }
        #pragma unroll
        for (int j = 0; j < 4; ++j) {
            int nr = wn + j * 16 + fr;
            bfr[j] = *(const short8x*)&Bs[nr * 32 + ((kq ^ ((nr >> 1) & 3)) * 8)];
        }
        #pragma unroll
        for (int i = 0; i < 4; ++i)
            #pragma unroll
            for (int j = 0; j < 4; ++j)
                acc[i][j] = __builtin_amdgcn_mfma_f32_16x16x32_bf16(
                                af[i], bfr[j], acc[i][j], 0, 0, 0);
        __syncthreads();
    }

    unsigned short* Yb = yT + (long long)b * YB;
    #pragma unroll
    for (int j = 0; j < 4; ++j) {
        int n = tn0 + wn + j * 16 + fr;
        if (n >= F62) continue;
        unsigned short* Yr = Yb + (long long)n * YLD;
        #pragma unroll
        for (int i = 0; i < 4; ++i) {
            int lb = tm0 + wm + i * 16 + kq * 4;
            if (lb >= Lp) continue;
            ushort4x hv;
            #pragma unroll
            for (int r = 0; r < 4; ++r) hv[r] = f2bf(acc[i][j][r]);
            if (lb + 3 < Lp) {
                *(ushort4x*)(Yr + lb) = hv;
            } else {
                #pragma unroll
                for (int r = 0; r < 4; ++r)
                    if (lb + r < Lp) Yr[lb + r] = hv[r];
            }
        }
    }
}

// ---------------------------------------------------------------------------
// fold gather from yT bf16 -> (B,32,128,128) image. Full write, no atomics.
// ---------------------------------------------------------------------------
__global__ __launch_bounds__(256)
void foldg_k(const unsigned short* __restrict__ yT, float* __restrict__ out)
{
    int idx = blockIdx.x * 256 + threadIdx.x;   // B*32*16384 exact
    int wc = idx & 127;
    int hr = (idx >> 7) & 127;
    int c  = (idx >> 14) & 31;
    int b  = idx >> 19;
    int ih_lo = (hr >= 6) ? ((hr - 3) >> 2) : 0;
    int ih_hi = min(hr >> 2, 30);
    int iw_lo = (wc >= 6) ? ((wc - 3) >> 2) : 0;
    int iw_hi = min(wc >> 2, 30);
    const unsigned short* Yb = yT + (long long)b * YB + (long long)c * 49 * YLD;
    float acc = 0.0f;
    for (int ih = ih_lo; ih <= ih_hi; ++ih) {
        int kh = hr - 4 * ih;
        for (int iw = iw_lo; iw <= iw_hi; ++iw) {
            int kw = wc - 4 * iw;
            acc += bf2f(Yb[(kh * 7 + kw) * YLD + ih * 31 + iw]);
        }
    }
    out[idx] = acc;
}

// ---------------------------------------------------------------------------
// Launch
// ---------------------------------------------------------------------------
extern "C" void kernel_launch(void* const* d_in, const int* in_sizes, int n_in,
                              void* d_out, int out_size, void* d_ws, size_t ws_size,
                              hipStream_t stream)
{
    const float* x       = (const float*)d_in[0];
    const float* g_w     = (const float*)d_in[1];
    const float* g_b     = (const float*)d_in[2];
    const float* w_w     = (const float*)d_in[3];
    const float* w_b     = (const float*)d_in[4];
    const float* theta_w = (const float*)d_in[5];
    const float* theta_b = (const float*)d_in[6];
    const float* fc1_w   = (const float*)d_in[7];
    const float* fc1_b   = (const float*)d_in[8];
    const float* mconv_w = (const float*)d_in[9];
    const float* mconv_b = (const float*)d_in[10];
    const float* mfc_w   = (const float*)d_in[11];
    const float* mfc_b   = (const float*)d_in[12];
    const float* c1_w    = (const float*)d_in[13];
    const float* c2_w    = (const float*)d_in[14];

    float* Am_out    = (float*)d_out;
    float* final_out = Am_out + (size_t)Bn * Lp * Lp;

    // Workspace (floats), total ~28.0M floats = ~112 MB
    float* ws = (float*)d_ws;
    float* x1    = ws;                        // 2,097,152
    float* x2    = ws + 2097152;              // 2,097,152
    float* x3    = ws + 4194304;              // 4,194,304 (later fold target)
    unsigned short* xf_hi = (unsigned short*)(ws + 8388608);    // 1,722,112 shorts
    unsigned short* xf_lo = (unsigned short*)(ws + 9249664);
    unsigned short* wf_hi = (unsigned short*)(ws + 10110720);
    unsigned short* wf_lo = (unsigned short*)(ws + 10971776);
    float* Abuf  = ws + 11832832;             // 7,388,168 (A -> S -> p62bT alias)
    unsigned short* AT_hi = (unsigned short*)(ws + 19221000);   // 7,626,496 shorts
    unsigned short* AT_lo = (unsigned short*)(ws + 23034248);   // (AT region -> yT later)
    unsigned short* Mw_hi = (unsigned short*)(ws + 26847496);   // 953,312 shorts
    unsigned short* Mw_lo = (unsigned short*)(ws + 27324152);
    float* Mb    = ws + 27800808;             // 1,024
    unsigned short* fc1wh = (unsigned short*)(ws + 27801832);   // 204,800 shorts
    unsigned short* fc1wl = (unsigned short*)(ws + 27904232);   // 204,800 shorts
    unsigned short* Am_bf16 = (unsigned short*)x1;      // aliases x1/x2
    unsigned short* p62bT   = (unsigned short*)Abuf;    // aliases Abuf
    unsigned short* yT      = AT_hi;                    // aliases AT (dead then)

    // prep: Mw hi/lo, Mb, fc1_w hi/lo, zero AT pads
    add_mwbf_k<<<3724, 256, 0, stream>>>(mconv_w, mfc_w, Mw_hi, Mw_lo);
    add_k<<<4, 256, 0, stream>>>(mconv_b, mfc_b, Mb, 961);
    fc1w_prep_k<<<800, 256, 0, stream>>>(fc1_w, fc1wh, fc1wl);
    zero_k<<<7448, 256, 0, stream>>>((float*)AT_hi, 1906624);

    // x1, x2 = dual 3x3 convs (strip)
    conv3x3s_k<true, true, false><<<2048, 256, 0, stream>>>(
        x, g_w, g_b, w_w, w_b, x1, x2);

    // x3 = conv1x1(x1)
    conv1x1_k<true, false, false><<<16384, 256, 0, stream>>>(
        x1, theta_w, theta_b, nullptr, x3);

    // xf, wf as bf16 hi/lo via MFMA fc GEMM
    fcmfma_k<<<484, 256, 0, stream>>>(x1, fc1wh, fc1wl, fc1_b, xf_hi, xf_lo);
    fcmfma_k<<<484, 256, 0, stream>>>(x2, fc1wh, fc1wl, fc1_b, wf_hi, wf_lo);

    // A = wf @ xf^T; writes A fp32 + AT hi/lo
    mfma3_k<0><<<512, 256, 0, stream>>>(
        wf_hi, wf_lo, xf_hi, xf_lo, Lp, Lp, FCP, FCB, FCB,
        Abuf, AT_hi, AT_lo, nullptr);

    // Ti = Mw @ A + Mb; S = A*sigmoid(Ti)*scale in-place over A
    mfma3_k<1><<<512, 256, 0, stream>>>(
        Mw_hi, Mw_lo, AT_hi, AT_lo, Lp, Lp, KP, 0LL, ATB,
        Abuf, nullptr, nullptr, Mb);

    // Am = softmax(S)*(S!=0) -> d_out fp32 + bf16
    softmax_mask_k<<<7688, 256, 0, stream>>>(Abuf, Am_out, Am_bf16);

    // p62^T bf16 (aliases Abuf; S dead)
    p62bt_k<<<6077, 256, 0, stream>>>(x3, p62bT);

    // y = Am @ p62 -> yT bf16 (AT region dead after mfma3<1>)
    ymfma_k<<<832, 256, 0, stream>>>(Am_bf16, p62bT, yT);

    // fold gather yT -> x3
    foldg_k<<<16384, 256, 0, stream>>>(yT, x3);

    // o1 = leaky(conv3x3(refpad(fold)))
    conv3x3s_k<false, false, true><<<2048, 256, 0, stream>>>(
        x3, c1_w, nullptr, nullptr, nullptr, x1, nullptr);

    // final = x + leaky(conv1x1(o1))
    conv1x1_k<false, true, true><<<16384, 256, 0, stream>>>(
        x1, c2_w, nullptr, x, final_out);
}

// Round 6
// 605.741 us; speedup vs baseline: 3.2688x; 1.2984x over previous
//
#include <hip/hip_runtime.h>
#include <math.h>

namespace {
constexpr int Bn   = 8;
constexpr int CIN  = 32;
constexpr int CI   = 16;
constexpr int Lp   = 961;     // 31*31 patches
constexpr int FIN  = 784;     // 16*49
constexpr int FOUT = 196;
constexpr int F62  = 1568;    // 32*49

constexpr int FCP  = 224;                 // fc K-pad (196 -> 7*32)
constexpr long long FCB = 961LL * FCP;    // per-batch fc rows (shorts)
constexpr int KP   = 992;                 // L K-pad (961 -> 31*32)
constexpr long long ATB  = 961LL * KP;    // AT per-batch (shorts)
constexpr long long AMBB = 961LL * KP;    // Am_bf16 per-batch (shorts)
constexpr long long PBTB = 1568LL * KP;   // p62bT per-batch (shorts)
constexpr long long AB   = 961LL * 961;   // A/S per-batch (floats)
constexpr int YLD  = 964;                 // yT leading dim (shorts)
constexpr long long YB = 1568LL * YLD;    // yT per-batch (shorts)
}

typedef __attribute__((ext_vector_type(8))) short short8x;
typedef __attribute__((ext_vector_type(4))) float floatx4;
typedef __attribute__((ext_vector_type(4))) unsigned short ushort4x;

static __device__ __forceinline__ unsigned short f2bf(float x) {
    unsigned int u = __builtin_bit_cast(unsigned int, x);
    u += 0x7fffu + ((u >> 16) & 1u);           // RNE
    return (unsigned short)(u >> 16);
}
static __device__ __forceinline__ float bf2f(unsigned short h) {
    return __builtin_bit_cast(float, ((unsigned int)h) << 16);
}

// ---------------------------------------------------------------------------
// Weight transpose prep: w (16,32,3,3) -> wT[(ci*9+tap)*16 + co]
// sel 0/1/2 -> g_w / w_w / c1_w. 3*4608 elements.
// ---------------------------------------------------------------------------
__global__ __launch_bounds__(256)
void wprep_k(const float* __restrict__ wa, const float* __restrict__ wb,
             const float* __restrict__ wc,
             float* __restrict__ ta, float* __restrict__ tb,
             float* __restrict__ tc)
{
    int idx = blockIdx.x * 256 + threadIdx.x;   // 13824 padded to 13824/256=54
    if (idx >= 3 * 4608) return;
    int sel = idx / 4608, r = idx - sel * 4608;
    int tapidx = r >> 4, co = r & 15;            // tapidx = ci*9+tap
    int src = co * 288 + tapidx;
    const float* w = (sel == 0) ? wa : (sel == 1) ? wb : wc;
    float* t = (sel == 0) ? ta : (sel == 1) ? tb : tc;
    t[r] = w[src];
}

// ---------------------------------------------------------------------------
// 3x3 conv, reflect-pad(1), 32ch -> 16ch, LDS-tiled (32x8 pixels + halo,
// all 32 in-ch staged once). Each thread: 1 pixel, all 16 co (x2 if DUAL).
// Weights pre-transposed: wT[(ci*9+tap)*16 + co] (wave-uniform s_loads).
// ---------------------------------------------------------------------------
template<bool DUAL, bool BIAS, bool LEAKY>
__global__ __launch_bounds__(256)
void conv3x3t_k(const float* __restrict__ x,
                const float* __restrict__ wT1, const float* __restrict__ b1,
                const float* __restrict__ wT2, const float* __restrict__ b2,
                float* __restrict__ o1, float* __restrict__ o2)
{
    __shared__ float Ls[10880];                 // 32ch x 10 x 34
    const int tid = threadIdx.x;
    const int t  = blockIdx.x;                  // 512 = 4w x 16h x 8b
    const int wt = t & 3, ht = (t >> 2) & 15, b = t >> 6;
    const int h0 = ht * 8, w0 = wt * 32;
    const float* xb = x + (size_t)b * CIN * 16384;

    for (int i = tid; i < 10880; i += 256) {
        int ci  = i / 340;
        int rem = i - ci * 340;
        int row = rem / 34;
        int col = rem - row * 34;
        int gh = h0 + row - 1; gh = (gh < 0) ? 1 : (gh > 127 ? 126 : gh);
        int gw = w0 + col - 1; gw = (gw < 0) ? 1 : (gw > 127 ? 126 : gw);
        Ls[i] = xb[ci * 16384 + gh * 128 + gw];
    }
    __syncthreads();

    const int px = tid & 31, py = tid >> 5;
    float acc1[16], acc2[16];
    #pragma unroll
    for (int co = 0; co < 16; ++co) {
        acc1[co] = BIAS ? b1[co] : 0.0f;
        acc2[co] = (DUAL && BIAS) ? b2[co] : 0.0f;
    }

    for (int ci = 0; ci < 32; ++ci) {
        const float* lp = &Ls[ci * 340 + py * 34 + px];
        float vv[9];
        #pragma unroll
        for (int r = 0; r < 3; ++r)
            #pragma unroll
            for (int c = 0; c < 3; ++c)
                vv[r * 3 + c] = lp[r * 34 + c];
        const float* wr1 = wT1 + ci * 144;
        const float* wr2 = DUAL ? (wT2 + ci * 144) : nullptr;
        #pragma unroll
        for (int tp = 0; tp < 9; ++tp) {
            float v = vv[tp];
            #pragma unroll
            for (int co = 0; co < 16; ++co) {
                acc1[co] += v * wr1[tp * 16 + co];
                if constexpr (DUAL) acc2[co] += v * wr2[tp * 16 + co];
            }
        }
    }

    const int h = h0 + py, w = w0 + px;
    size_t ob = (((size_t)b * 16) * 128 + h) * 128 + w;
    #pragma unroll
    for (int co = 0; co < 16; ++co) {
        float v = acc1[co];
        if constexpr (LEAKY) v = (v >= 0.0f) ? v : 0.2f * v;
        o1[ob + (size_t)co * 16384] = v;
        if constexpr (DUAL) o2[ob + (size_t)co * 16384] = acc2[co];
    }
}

// ---------------------------------------------------------------------------
// 1x1 conv, 16ch -> 32ch, pixel-per-thread (reads 16 ci once, writes 32 co).
// ---------------------------------------------------------------------------
template<bool BIAS, bool LEAKY, bool RESID>
__global__ __launch_bounds__(256)
void conv1x1p_k(const float* __restrict__ src, const float* __restrict__ wgt,
                const float* __restrict__ bias, const float* __restrict__ resid,
                float* __restrict__ out)
{
    int idx = blockIdx.x * 256 + threadIdx.x;   // 131072 exact (512 blocks)
    int pix = idx & 16383;
    int b   = idx >> 14;
    const float* sb = src + (size_t)b * CI * 16384 + pix;
    float s[16];
    #pragma unroll
    for (int ci = 0; ci < CI; ++ci) s[ci] = sb[ci * 16384];
    size_t ob = (size_t)b * 32 * 16384 + pix;
    #pragma unroll
    for (int co = 0; co < 32; ++co) {
        const float* wrow = wgt + co * CI;
        float acc = BIAS ? bias[co] : 0.0f;
        #pragma unroll
        for (int ci = 0; ci < CI; ++ci) acc += wrow[ci] * s[ci];
        if constexpr (LEAKY) acc = (acc >= 0.0f) ? acc : 0.2f * acc;
        if constexpr (RESID) acc += resid[ob + (size_t)co * 16384];
        out[ob + (size_t)co * 16384] = acc;
    }
}

// ---------------------------------------------------------------------------
// fc1_w -> hi/lo bf16, padded to (256 rows, 800 k).
// ---------------------------------------------------------------------------
__global__ __launch_bounds__(256)
void fc1w_prep_k(const float* __restrict__ w,
                 unsigned short* __restrict__ Wh, unsigned short* __restrict__ Wl)
{
    int i = blockIdx.x * 256 + threadIdx.x;     // 256*800 exact
    int n = i / 800, k = i - n * 800;
    float v = (n < 196 && k < 784) ? w[n * 784 + k] : 0.0f;
    unsigned short h = f2bf(v);
    Wh[i] = h;
    Wl[i] = f2bf(v - bf2f(h));
}

// ---------------------------------------------------------------------------
// fc GEMM via split-bf16 MFMA (3-term): D = unfold(xsrc) @ fc1_w^T + fc1_b,
// 64x64 tile (4 waves of 32x32), gather-A with on-the-fly hi/lo split.
// ---------------------------------------------------------------------------
__global__ __launch_bounds__(256)
void fcmfma_k(const float* __restrict__ xsrc,
              const unsigned short* __restrict__ Wh,
              const unsigned short* __restrict__ Wl,
              const float* __restrict__ bias,
              unsigned short* __restrict__ Dh, unsigned short* __restrict__ Dl)
{
    __shared__ unsigned short AsH[64*32], AsL[64*32], BsH[64*32], BsL[64*32];
    const int tid = threadIdx.x;
    const int tm0 = (blockIdx.x >> 2) * 64;     // 121 m-tiles
    const int tn0 = (blockIdx.x & 3) * 64;      // 4 n-tiles

    const int lr = tid >> 2;
    const int lc = tid & 3;
    const int gm = tm0 + lr;
    const bool mok = gm < 7688;
    int gbase = 0;
    if (mok) {
        int b = gm / 961, pi = gm - b * 961;
        int ih = pi / 31, iw = pi - ih * 31;
        gbase = b * 262144 + ih * 512 + iw * 4;
    }
    const int pc = ((lc ^ ((lr >> 1) & 3))) * 8;
    const unsigned short* Whr = Wh + (tn0 + lr) * 800;
    const unsigned short* Wlr = Wl + (tn0 + lr) * 800;

    const int lane = tid & 63, wv = tid >> 6;
    const int wm = (wv >> 1) * 32, wn = (wv & 1) * 32;
    const int fr = lane & 15, kq = lane >> 4;

    floatx4 acc[2][2];
    #pragma unroll
    for (int i = 0; i < 2; ++i)
        #pragma unroll
        for (int j = 0; j < 2; ++j)
            acc[i][j] = (floatx4){0.f, 0.f, 0.f, 0.f};

    for (int k0 = 0; k0 < 800; k0 += 32) {
        unsigned short hv[8], lv[8];
        #pragma unroll
        for (int j = 0; j < 8; ++j) {
            int k = k0 + lc * 8 + j;
            float v = 0.0f;
            if (mok && k < 784) {
                int c  = k / 49, r = k - c * 49;
                int kh = r / 7,  kw = r - kh * 7;
                v = xsrc[gbase + c * 16384 + kh * 128 + kw];
            }
            unsigned short h = f2bf(v);
            hv[j] = h; lv[j] = f2bf(v - bf2f(h));
        }
        *(short8x*)&AsH[lr * 32 + pc] = *(short8x*)hv;
        *(short8x*)&AsL[lr * 32 + pc] = *(short8x*)lv;
        *(short8x*)&BsH[lr * 32 + pc] = *(const short8x*)(Whr + k0 + lc * 8);
        *(short8x*)&BsL[lr * 32 + pc] = *(const short8x*)(Wlr + k0 + lc * 8);
        __syncthreads();
        short8x ah[2], al[2], bh[2], bl[2];
        #pragma unroll
        for (int i = 0; i < 2; ++i) {
            int mr = wm + i * 16 + fr;
            int off = mr * 32 + ((kq ^ ((mr >> 1) & 3)) * 8);
            ah[i] = *(const short8x*)&AsH[off];
            al[i] = *(const short8x*)&AsL[off];
        }
        #pragma unroll
        for (int j = 0; j < 2; ++j) {
            int nr = wn + j * 16 + fr;
            int off = nr * 32 + ((kq ^ ((nr >> 1) & 3)) * 8);
            bh[j] = *(const short8x*)&BsH[off];
            bl[j] = *(const short8x*)&BsL[off];
        }
        #pragma unroll
        for (int i = 0; i < 2; ++i)
            #pragma unroll
            for (int j = 0; j < 2; ++j) {
                acc[i][j] = __builtin_amdgcn_mfma_f32_16x16x32_bf16(ah[i], bh[j], acc[i][j], 0, 0, 0);
                acc[i][j] = __builtin_amdgcn_mfma_f32_16x16x32_bf16(ah[i], bl[j], acc[i][j], 0, 0, 0);
                acc[i][j] = __builtin_amdgcn_mfma_f32_16x16x32_bf16(al[i], bh[j], acc[i][j], 0, 0, 0);
            }
        __syncthreads();
    }

    #pragma unroll
    for (int j = 0; j < 2; ++j) {
        int n = tn0 + wn + j * 16 + fr;
        if (n >= FCP) continue;
        float bn = (n < 196) ? bias[n] : 0.0f;
        #pragma unroll
        for (int i = 0; i < 2; ++i) {
            #pragma unroll
            for (int r = 0; r < 4; ++r) {
                int l = tm0 + wm + i * 16 + kq * 4 + r;
                if (l >= 7688) continue;
                int b = l / 961, pi = l - b * 961;
                float v = (n < 196) ? (acc[i][j][r] + bn) : 0.0f;
                long long base = (long long)b * FCB + (long long)pi * FCP + n;
                unsigned short h = f2bf(v);
                Dh[base] = h;
                Dl[base] = f2bf(v - bf2f(h));
            }
        }
    }
}

// ---------------------------------------------------------------------------
// Split-bf16 MFMA GEMM (3-term), 128x128 tile, flat grid (batch-per-XCD).
// MODE 0 (A):  write A fp32 [l][m] + AT hi/lo bf16 [m][l] (ld KP, pre-zeroed)
// MODE 1 (Ti): ti = acc + Mb[l]; S[l][m] = A[l][m] * sigmoid(ti) * scale
// ---------------------------------------------------------------------------
template<int MODE>
__global__ __launch_bounds__(256)
void mfma3_k(const unsigned short* __restrict__ Xhi,
             const unsigned short* __restrict__ Xlo,
             const unsigned short* __restrict__ Yhi,
             const unsigned short* __restrict__ Ylo,
             int Mrows, int Nrows, int Kd,
             long long sX, long long sY,
             float* __restrict__ Afp,
             unsigned short* __restrict__ AThi,
             unsigned short* __restrict__ ATlo,
             const float* __restrict__ Mb)
{
    __shared__ unsigned short XsH[128 * 32], XsL[128 * 32];
    __shared__ unsigned short YsH[128 * 32], YsL[128 * 32];
    const int b   = blockIdx.x & 7;
    const int t   = blockIdx.x >> 3;
    const int tm0 = (t >> 3) * 128;
    const int tn0 = (t & 7) * 128;
    const unsigned short* Xbh = Xhi + (long long)b * sX;
    const unsigned short* Xbl = Xlo + (long long)b * sX;
    const unsigned short* Ybh = Yhi + (long long)b * sY;
    const unsigned short* Ybl = Ylo + (long long)b * sY;
    const int tid = threadIdx.x;

    const int sr  = tid >> 1;
    const int sc0 = (tid & 1) * 2;
    const bool xok = (tm0 + sr) < Mrows;
    const bool yok = (tn0 + sr) < Nrows;
    const unsigned short* Xrh = Xbh + (long long)(tm0 + sr) * Kd;
    const unsigned short* Xrl = Xbl + (long long)(tm0 + sr) * Kd;
    const unsigned short* Yrh = Ybh + (long long)(tn0 + sr) * Kd;
    const unsigned short* Yrl = Ybl + (long long)(tn0 + sr) * Kd;
    const int swz = (sr >> 1) & 3;

    const int lane = tid & 63;
    const int wv   = tid >> 6;
    const int wm   = (wv >> 1) * 64, wn = (wv & 1) * 64;
    const int fr   = lane & 15;
    const int kq   = lane >> 4;

    floatx4 acc[4][4];
    #pragma unroll
    for (int i = 0; i < 4; ++i)
        #pragma unroll
        for (int j = 0; j < 4; ++j)
            acc[i][j] = (floatx4){0.f, 0.f, 0.f, 0.f};

    const short8x zz = {0,0,0,0,0,0,0,0};

    for (int k0 = 0; k0 < Kd; k0 += 32) {
        #pragma unroll
        for (int c = 0; c < 2; ++c) {
            int kc = sc0 + c;
            short8x xh = zz, xl = zz, yh = zz, yl = zz;
            if (xok) {
                xh = *(const short8x*)(Xrh + k0 + kc * 8);
                xl = *(const short8x*)(Xrl + k0 + kc * 8);
            }
            if (yok) {
                yh = *(const short8x*)(Yrh + k0 + kc * 8);
                yl = *(const short8x*)(Yrl + k0 + kc * 8);
            }
            int pc = kc ^ swz;
            *(short8x*)&XsH[sr * 32 + pc * 8] = xh;
            *(short8x*)&XsL[sr * 32 + pc * 8] = xl;
            *(short8x*)&YsH[sr * 32 + pc * 8] = yh;
            *(short8x*)&YsL[sr * 32 + pc * 8] = yl;
        }
        __syncthreads();
        short8x bh[4], bl[4];
        #pragma unroll
        for (int j = 0; j < 4; ++j) {
            int nr = wn + j * 16 + fr;
            int off = nr * 32 + ((kq ^ ((nr >> 1) & 3)) * 8);
            bh[j] = *(const short8x*)&YsH[off];
            bl[j] = *(const short8x*)&YsL[off];
        }
        #pragma unroll
        for (int i = 0; i < 4; ++i) {
            int mr = wm + i * 16 + fr;
            int off = mr * 32 + ((kq ^ ((mr >> 1) & 3)) * 8);
            short8x ah = *(const short8x*)&XsH[off];
            short8x al = *(const short8x*)&XsL[off];
            #pragma unroll
            for (int j = 0; j < 4; ++j) {
                acc[i][j] = __builtin_amdgcn_mfma_f32_16x16x32_bf16(ah, bh[j], acc[i][j], 0, 0, 0);
                acc[i][j] = __builtin_amdgcn_mfma_f32_16x16x32_bf16(ah, bl[j], acc[i][j], 0, 0, 0);
                acc[i][j] = __builtin_amdgcn_mfma_f32_16x16x32_bf16(al, bh[j], acc[i][j], 0, 0, 0);
            }
        }
        __syncthreads();
    }

    const float scale = 0.07142857142857142f;   // 196^-0.5
    if constexpr (MODE == 0) {
        float* Ab = Afp + (long long)b * AB;
        unsigned short* Th = AThi + (long long)b * ATB;
        unsigned short* Tl = ATlo + (long long)b * ATB;
        #pragma unroll
        for (int j = 0; j < 4; ++j) {
            int m = tn0 + wn + j * 16 + fr;
            if (m >= 961) continue;
            #pragma unroll
            for (int i = 0; i < 4; ++i) {
                int lb = tm0 + wm + i * 16 + kq * 4;
                if (lb >= 961) continue;
                ushort4x hv, lv;
                #pragma unroll
                for (int r = 0; r < 4; ++r) {
                    int l = lb + r;
                    float v = acc[i][j][r];
                    if (l < 961) {
                        Ab[(long long)l * 961 + m] = v;
                        unsigned short h = f2bf(v);
                        hv[r] = h;
                        lv[r] = f2bf(v - bf2f(h));
                    } else { hv[r] = 0; lv[r] = 0; }
                }
                long long toff = (long long)m * KP + lb;
                if (lb + 3 < 961) {
                    *(ushort4x*)(Th + toff) = hv;
                    *(ushort4x*)(Tl + toff) = lv;
                } else {
                    for (int r = 0; r < 4; ++r)
                        if (lb + r < 961) { Th[toff + r] = hv[r]; Tl[toff + r] = lv[r]; }
                }
            }
        }
    } else {
        float* Sb = Afp + (long long)b * AB;
        #pragma unroll
        for (int j = 0; j < 4; ++j) {
            int m = tn0 + wn + j * 16 + fr;
            if (m >= 961) continue;
            #pragma unroll
            for (int i = 0; i < 4; ++i) {
                int lb = tm0 + wm + i * 16 + kq * 4;
                #pragma unroll
                for (int r = 0; r < 4; ++r) {
                    int l = lb + r;
                    if (l >= 961) continue;
                    float ti = acc[i][j][r] + Mb[l];
                    float a  = Sb[(long long)l * 961 + m];
                    float mask = 1.0f / (1.0f + expf(-ti));
                    Sb[(long long)l * 961 + m] = a * mask * scale;
                }
            }
        }
    }
}

// ---------------------------------------------------------------------------
// Mw = mconv_w + mfc_w as bf16 hi/lo, rows KP-padded with zeros.
// ---------------------------------------------------------------------------
__global__ __launch_bounds__(256)
void add_mwbf_k(const float* __restrict__ a, const float* __restrict__ b,
                unsigned short* __restrict__ ch, unsigned short* __restrict__ cl)
{
    int i = blockIdx.x * 256 + threadIdx.x;     // 961*KP
    if (i >= 961 * KP) return;
    int n = i / KP, c = i - n * KP;
    float v = (c < 961) ? (a[n * 961 + c] + b[n * 961 + c]) : 0.0f;
    unsigned short h = f2bf(v);
    ch[i] = h;
    cl[i] = f2bf(v - bf2f(h));
}
__global__ __launch_bounds__(256)
void add_k(const float* __restrict__ a, const float* __restrict__ b,
           float* __restrict__ c, int n)
{
    int i = blockIdx.x * 256 + threadIdx.x;
    if (i < n) c[i] = a[i] + b[i];
}

// ---------------------------------------------------------------------------
// softmax over S rows (961): mb=(s!=0); Am fp32 -> d_out, bf16 (KP rows) -> ws
// ---------------------------------------------------------------------------
__global__ __launch_bounds__(256)
void softmax_mask_k(const float* __restrict__ S, float* __restrict__ Am,
                    unsigned short* __restrict__ Amb)
{
    int row = blockIdx.x;                // b*961 + l
    const float* srow = S + (long long)row * Lp;
    float*       orow = Am + (long long)row * Lp;
    unsigned short* brow = Amb + (long long)row * KP;
    int tid = threadIdx.x;

    float s[4], mb[4];
    float lmax = -INFINITY;
    #pragma unroll
    for (int j = 0; j < 4; ++j) {
        int m = tid + j * 256;
        if (m < Lp) {
            float v = srow[m];
            s[j]  = v;
            mb[j] = (v != 0.0f) ? 1.0f : 0.0f;
            lmax  = fmaxf(lmax, v);
        } else { s[j] = -INFINITY; mb[j] = 0.0f; }
    }
    __shared__ float red[256];
    red[tid] = lmax; __syncthreads();
    #pragma unroll
    for (int off = 128; off > 0; off >>= 1) {
        if (tid < off) red[tid] = fmaxf(red[tid], red[tid + off]);
        __syncthreads();
    }
    float rmax = red[0];
    __syncthreads();

    float e[4];
    float lsum = 0.0f;
    #pragma unroll
    for (int j = 0; j < 4; ++j) {
        int m = tid + j * 256;
        e[j] = (m < Lp) ? expf(s[j] - rmax) : 0.0f;
        lsum += e[j];
    }
    red[tid] = lsum; __syncthreads();
    #pragma unroll
    for (int off = 128; off > 0; off >>= 1) {
        if (tid < off) red[tid] += red[tid + off];
        __syncthreads();
    }
    float inv = 1.0f / red[0];
    #pragma unroll
    for (int j = 0; j < 4; ++j) {
        int m = tid + j * 256;
        if (m < Lp) {
            float v = e[j] * inv * mb[j];
            orow[m] = v;
            brow[m] = f2bf(v);
        } else if (m < KP) {
            brow[m] = 0;
        }
    }
}

// ---------------------------------------------------------------------------
// p62^T bf16: out[b][n][k] = x3[b, c(n), ih(k)*4+kh(n), iw(k)*4+kw(n)], ld KP.
// ---------------------------------------------------------------------------
__global__ __launch_bounds__(256)
void p62bt_k(const float* __restrict__ x3, unsigned short* __restrict__ out)
{
    int idx = blockIdx.x * 256 + threadIdx.x;      // 8*1568*124
    if (idx >= 8 * 1568 * 124) return;
    int ck = idx % 124;
    int t  = idx / 124;
    int n  = t % 1568;
    int b  = t / 1568;
    int c = n / 49, rr = n - c * 49;
    int kh = rr / 7, kw = rr - kh * 7;
    const float* src = x3 + (long long)b * 524288 + c * 16384 + kh * 128 + kw;
    int k = ck * 8;
    unsigned short v[8];
    #pragma unroll
    for (int j = 0; j < 8; ++j) {
        int kk = k + j;
        if (kk < Lp) {
            int ih = kk / 31, iw = kk - ih * 31;
            v[j] = f2bf(src[ih * 512 + iw * 4]);
        } else v[j] = 0;
    }
    *(short8x*)(out + ((long long)b * 1568 + n) * KP + k) = *(short8x*)v;
}

__global__ __launch_bounds__(256)
void zero_k(float* __restrict__ p, int n4)
{
    int i = blockIdx.x * 256 + threadIdx.x;
    if (i < n4) ((float4*)p)[i] = make_float4(0.f, 0.f, 0.f, 0.f);
}

// ---------------------------------------------------------------------------
// y = Am @ p62 via bf16 MFMA, writes yT bf16 [b][n][l] (ld YLD).
// ---------------------------------------------------------------------------
__global__ __launch_bounds__(256)
void ymfma_k(const unsigned short* __restrict__ Amb,
             const unsigned short* __restrict__ Pbt,
             unsigned short* __restrict__ yT)
{
    __shared__ unsigned short As[128 * 32];
    __shared__ unsigned short Bs[128 * 32];
    const int b   = blockIdx.x & 7;
    const int t   = blockIdx.x >> 3;            // 104 = 13 n x 8 m
    const int tn0 = (t % 13) * 128;
    const int tm0 = (t / 13) * 128;
    const unsigned short* Ab = Amb + (long long)b * AMBB;
    const unsigned short* Bb = Pbt + (long long)b * PBTB;
    const int tid = threadIdx.x;

    const int sr  = tid >> 1;
    const int sc0 = (tid & 1) * 2;
    const bool aok = (tm0 + sr) < Lp;
    const bool bok = (tn0 + sr) < F62;
    const unsigned short* Arow = Ab + (long long)(tm0 + sr) * KP;
    const unsigned short* Brow = Bb + (long long)(tn0 + sr) * KP;
    const int swz = (sr >> 1) & 3;

    const int lane = tid & 63;
    const int wv   = tid >> 6;
    const int wm   = (wv >> 1) * 64, wn = (wv & 1) * 64;
    const int fr   = lane & 15;
    const int kq   = lane >> 4;

    floatx4 acc[4][4];
    #pragma unroll
    for (int i = 0; i < 4; ++i)
        #pragma unroll
        for (int j = 0; j < 4; ++j)
            acc[i][j] = (floatx4){0.f, 0.f, 0.f, 0.f};

    const short8x zz = {0,0,0,0,0,0,0,0};

    for (int k0 = 0; k0 < Lp; k0 += 32) {
        #pragma unroll
        for (int c = 0; c < 2; ++c) {
            int kc = sc0 + c;
            short8x va = zz, vb = zz;
            if (aok) va = *(const short8x*)(Arow + k0 + kc * 8);
            if (bok) vb = *(const short8x*)(Brow + k0 + kc * 8);
            int pc = kc ^ swz;
            *(short8x*)&As[sr * 32 + pc * 8] = va;
            *(short8x*)&Bs[sr * 32 + pc * 8] = vb;
        }
        __syncthreads();
        short8x af[4], bfr[4];
        #pragma unroll
        for (int i = 0; i < 4; ++i) {
            int mr = wm + i * 16 + fr;
            af[i] = *(const short8x*)&As[mr * 32 + ((kq ^ ((mr >> 1) & 3)) * 8)];
        }
        #pragma unroll
        for (int j = 0; j < 4; ++j) {
            int nr = wn + j * 16 + fr;
            bfr[j] = *(const short8x*)&Bs[nr * 32 + ((kq ^ ((nr >> 1) & 3)) * 8)];
        }
        #pragma unroll
        for (int i = 0; i < 4; ++i)
            #pragma unroll
            for (int j = 0; j < 4; ++j)
                acc[i][j] = __builtin_amdgcn_mfma_f32_16x16x32_bf16(
                                af[i], bfr[j], acc[i][j], 0, 0, 0);
        __syncthreads();
    }

    unsigned short* Yb = yT + (long long)b * YB;
    #pragma unroll
    for (int j = 0; j < 4; ++j) {
        int n = tn0 + wn + j * 16 + fr;
        if (n >= F62) continue;
        unsigned short* Yr = Yb + (long long)n * YLD;
        #pragma unroll
        for (int i = 0; i < 4; ++i) {
            int lb = tm0 + wm + i * 16 + kq * 4;
            if (lb >= Lp) continue;
            ushort4x hv;
            #pragma unroll
            for (int r = 0; r < 4; ++r) hv[r] = f2bf(acc[i][j][r]);
            if (lb + 3 < Lp) {
                *(ushort4x*)(Yr + lb) = hv;
            } else {
                #pragma unroll
                for (int r = 0; r < 4; ++r)
                    if (lb + r < Lp) Yr[lb + r] = hv[r];
            }
        }
    }
}

// ---------------------------------------------------------------------------
// fold gather from yT bf16 -> (B,32,128,128) image.
// ---------------------------------------------------------------------------
__global__ __launch_bounds__(256)
void foldg_k(const unsigned short* __restrict__ yT, float* __restrict__ out)
{
    int idx = blockIdx.x * 256 + threadIdx.x;   // B*32*16384 exact
    int wc = idx & 127;
    int hr = (idx >> 7) & 127;
    int c  = (idx >> 14) & 31;
    int b  = idx >> 19;
    int ih_lo = (hr >= 6) ? ((hr - 3) >> 2) : 0;
    int ih_hi = min(hr >> 2, 30);
    int iw_lo = (wc >= 6) ? ((wc - 3) >> 2) : 0;
    int iw_hi = min(wc >> 2, 30);
    const unsigned short* Yb = yT + (long long)b * YB + (long long)c * 49 * YLD;
    float acc = 0.0f;
    for (int ih = ih_lo; ih <= ih_hi; ++ih) {
        int kh = hr - 4 * ih;
        for (int iw = iw_lo; iw <= iw_hi; ++iw) {
            int kw = wc - 4 * iw;
            acc += bf2f(Yb[(kh * 7 + kw) * YLD + ih * 31 + iw]);
        }
    }
    out[idx] = acc;
}

// ---------------------------------------------------------------------------
// Launch
// ---------------------------------------------------------------------------
extern "C" void kernel_launch(void* const* d_in, const int* in_sizes, int n_in,
                              void* d_out, int out_size, void* d_ws, size_t ws_size,
                              hipStream_t stream)
{
    const float* x       = (const float*)d_in[0];
    const float* g_w     = (const float*)d_in[1];
    const float* g_b     = (const float*)d_in[2];
    const float* w_w     = (const float*)d_in[3];
    const float* w_b     = (const float*)d_in[4];
    const float* theta_w = (const float*)d_in[5];
    const float* theta_b = (const float*)d_in[6];
    const float* fc1_w   = (const float*)d_in[7];
    const float* fc1_b   = (const float*)d_in[8];
    const float* mconv_w = (const float*)d_in[9];
    const float* mconv_b = (const float*)d_in[10];
    const float* mfc_w   = (const float*)d_in[11];
    const float* mfc_b   = (const float*)d_in[12];
    const float* c1_w    = (const float*)d_in[13];
    const float* c2_w    = (const float*)d_in[14];

    float* Am_out    = (float*)d_out;
    float* final_out = Am_out + (size_t)Bn * Lp * Lp;

    // Workspace (floats), total ~28.03M floats = ~112 MB
    float* ws = (float*)d_ws;
    float* x1    = ws;                        // 2,097,152
    float* x2    = ws + 2097152;              // 2,097,152
    float* x3    = ws + 4194304;              // 4,194,304 (later fold target)
    unsigned short* xf_hi = (unsigned short*)(ws + 8388608);    // 1,722,112 shorts
    unsigned short* xf_lo = (unsigned short*)(ws + 9249664);
    unsigned short* wf_hi = (unsigned short*)(ws + 10110720);
    unsigned short* wf_lo = (unsigned short*)(ws + 10971776);
    float* Abuf  = ws + 11832832;             // 7,388,168 (A -> S -> p62bT alias)
    unsigned short* AT_hi = (unsigned short*)(ws + 19221000);   // 7,626,496 shorts
    unsigned short* AT_lo = (unsigned short*)(ws + 23034248);   // (AT region -> yT later)
    unsigned short* Mw_hi = (unsigned short*)(ws + 26847496);   // 953,312 shorts
    unsigned short* Mw_lo = (unsigned short*)(ws + 27324152);
    float* Mb    = ws + 27800808;             // 1,024
    unsigned short* fc1wh = (unsigned short*)(ws + 27801832);   // 204,800 shorts
    unsigned short* fc1wl = (unsigned short*)(ws + 27904232);   // 204,800 shorts
    float* wT1   = ws + 28006632;             // 4,608
    float* wT2   = ws + 28011240;             // 4,608
    float* wTc   = ws + 28015848;             // 4,608
    unsigned short* Am_bf16 = (unsigned short*)x1;      // aliases x1/x2
    unsigned short* p62bT   = (unsigned short*)Abuf;    // aliases Abuf
    unsigned short* yT      = AT_hi;                    // aliases AT (dead then)

    // prep: conv weight transposes, Mw hi/lo, Mb, fc1_w hi/lo, zero AT pads
    wprep_k<<<54, 256, 0, stream>>>(g_w, w_w, c1_w, wT1, wT2, wTc);
    add_mwbf_k<<<3724, 256, 0, stream>>>(mconv_w, mfc_w, Mw_hi, Mw_lo);
    add_k<<<4, 256, 0, stream>>>(mconv_b, mfc_b, Mb, 961);
    fc1w_prep_k<<<800, 256, 0, stream>>>(fc1_w, fc1wh, fc1wl);
    zero_k<<<7448, 256, 0, stream>>>((float*)AT_hi, 1906624);

    // x1, x2 = dual 3x3 convs (LDS-tiled)
    conv3x3t_k<true, true, false><<<512, 256, 0, stream>>>(
        x, wT1, g_b, wT2, w_b, x1, x2);

    // x3 = conv1x1(x1)
    conv1x1p_k<true, false, false><<<512, 256, 0, stream>>>(
        x1, theta_w, theta_b, nullptr, x3);

    // xf, wf as bf16 hi/lo via MFMA fc GEMM
    fcmfma_k<<<484, 256, 0, stream>>>(x1, fc1wh, fc1wl, fc1_b, xf_hi, xf_lo);
    fcmfma_k<<<484, 256, 0, stream>>>(x2, fc1wh, fc1wl, fc1_b, wf_hi, wf_lo);

    // A = wf @ xf^T; writes A fp32 + AT hi/lo
    mfma3_k<0><<<512, 256, 0, stream>>>(
        wf_hi, wf_lo, xf_hi, xf_lo, Lp, Lp, FCP, FCB, FCB,
        Abuf, AT_hi, AT_lo, nullptr);

    // Ti = Mw @ A + Mb; S = A*sigmoid(Ti)*scale in-place over A
    mfma3_k<1><<<512, 256, 0, stream>>>(
        Mw_hi, Mw_lo, AT_hi, AT_lo, Lp, Lp, KP, 0LL, ATB,
        Abuf, nullptr, nullptr, Mb);

    // Am = softmax(S)*(S!=0) -> d_out fp32 + bf16
    softmax_mask_k<<<7688, 256, 0, stream>>>(Abuf, Am_out, Am_bf16);

    // p62^T bf16 (aliases Abuf; S dead)
    p62bt_k<<<6077, 256, 0, stream>>>(x3, p62bT);

    // y = Am @ p62 -> yT bf16 (AT region dead after mfma3<1>)
    ymfma_k<<<832, 256, 0, stream>>>(Am_bf16, p62bT, yT);

    // fold gather yT -> x3
    foldg_k<<<16384, 256, 0, stream>>>(yT, x3);

    // o1 = leaky(conv3x3(refpad(fold)))
    conv3x3t_k<false, false, true><<<512, 256, 0, stream>>>(
        x3, wTc, nullptr, nullptr, nullptr, x1, nullptr);

    // final = x + leaky(conv1x1(o1))
    conv1x1p_k<false, true, true><<<512, 256, 0, stream>>>(
        x1, c2_w, nullptr, x, final_out);
}

// Round 7
// 577.474 us; speedup vs baseline: 3.4288x; 1.0489x over previous
//
#include <hip/hip_runtime.h>
#include <math.h>

namespace {
constexpr int Bn   = 8;
constexpr int CIN  = 32;
constexpr int CI   = 16;
constexpr int Lp   = 961;     // 31*31 patches
constexpr int FIN  = 784;     // 16*49
constexpr int FOUT = 196;
constexpr int F62  = 1568;    // 32*49

constexpr int FCP  = 224;                 // fc K-pad (196 -> 7*32)
constexpr long long FCB = 961LL * FCP;    // per-batch fc rows (shorts)
constexpr int KP   = 992;                 // L K-pad (961 -> 31*32)
constexpr long long ATB  = 961LL * KP;    // AT per-batch (shorts)
constexpr long long AMBB = 961LL * KP;    // Am_bf16 per-batch (shorts)
constexpr long long PBTB = 1568LL * KP;   // p62bT per-batch (shorts)
constexpr long long AB   = 961LL * 961;   // A/S per-batch (floats)
constexpr int YLD  = 964;                 // yT leading dim (shorts)
constexpr long long YB = 1568LL * YLD;    // yT per-batch (shorts)
}

typedef __attribute__((ext_vector_type(8))) short short8x;
typedef __attribute__((ext_vector_type(4))) float floatx4;
typedef __attribute__((ext_vector_type(4))) unsigned short ushort4x;

static __device__ __forceinline__ unsigned short f2bf(float x) {
    unsigned int u = __builtin_bit_cast(unsigned int, x);
    u += 0x7fffu + ((u >> 16) & 1u);           // RNE
    return (unsigned short)(u >> 16);
}
static __device__ __forceinline__ float bf2f(unsigned short h) {
    return __builtin_bit_cast(float, ((unsigned int)h) << 16);
}

// ---------------------------------------------------------------------------
// Merged prep: conv weight transposes + Mw hi/lo (KP-padded) + Mb + fc1_w hi/lo
// ---------------------------------------------------------------------------
__global__ __launch_bounds__(256)
void prep_k(const float* __restrict__ g_w, const float* __restrict__ w_w,
            const float* __restrict__ c1_w,
            float* __restrict__ wT1, float* __restrict__ wT2,
            float* __restrict__ wTc,
            const float* __restrict__ mconv_w, const float* __restrict__ mfc_w,
            unsigned short* __restrict__ Mwh, unsigned short* __restrict__ Mwl,
            const float* __restrict__ mconv_b, const float* __restrict__ mfc_b,
            float* __restrict__ Mb,
            const float* __restrict__ fc1w,
            unsigned short* __restrict__ Wh, unsigned short* __restrict__ Wl)
{
    int i = blockIdx.x * 256 + threadIdx.x;
    if (i < 13824) {
        int sel = i / 4608, r = i - sel * 4608;
        int tapidx = r >> 4, co = r & 15;
        const float* w = (sel == 0) ? g_w : (sel == 1) ? w_w : c1_w;
        float* t = (sel == 0) ? wT1 : (sel == 1) ? wT2 : wTc;
        t[r] = w[co * 288 + tapidx];
    } else if (i < 967136) {
        int k = i - 13824;                      // 961*KP
        int n = k / KP, c = k - n * KP;
        float v = (c < 961) ? (mconv_w[n * 961 + c] + mfc_w[n * 961 + c]) : 0.0f;
        unsigned short h = f2bf(v);
        Mwh[k] = h; Mwl[k] = f2bf(v - bf2f(h));
    } else if (i < 968097) {
        int k = i - 967136;
        Mb[k] = mconv_b[k] + mfc_b[k];
    } else if (i < 1172897) {
        int k = i - 968097;                     // 256*800
        int n = k / 800, kk = k - n * 800;
        float v = (n < 196 && kk < 784) ? fc1w[n * 784 + kk] : 0.0f;
        unsigned short h = f2bf(v);
        Wh[k] = h; Wl[k] = f2bf(v - bf2f(h));
    }
}

// ---------------------------------------------------------------------------
// 3x3 conv, reflect-pad(1), 32ch -> 16ch, LDS-tiled.
// ---------------------------------------------------------------------------
template<bool DUAL, bool BIAS, bool LEAKY>
__global__ __launch_bounds__(256)
void conv3x3t_k(const float* __restrict__ x,
                const float* __restrict__ wT1, const float* __restrict__ b1,
                const float* __restrict__ wT2, const float* __restrict__ b2,
                float* __restrict__ o1, float* __restrict__ o2)
{
    __shared__ float Ls[10880];                 // 32ch x 10 x 34
    const int tid = threadIdx.x;
    const int t  = blockIdx.x;                  // 512 = 4w x 16h x 8b
    const int wt = t & 3, ht = (t >> 2) & 15, b = t >> 6;
    const int h0 = ht * 8, w0 = wt * 32;
    const float* xb = x + (size_t)b * CIN * 16384;

    for (int i = tid; i < 10880; i += 256) {
        int ci  = i / 340;
        int rem = i - ci * 340;
        int row = rem / 34;
        int col = rem - row * 34;
        int gh = h0 + row - 1; gh = (gh < 0) ? 1 : (gh > 127 ? 126 : gh);
        int gw = w0 + col - 1; gw = (gw < 0) ? 1 : (gw > 127 ? 126 : gw);
        Ls[i] = xb[ci * 16384 + gh * 128 + gw];
    }
    __syncthreads();

    const int px = tid & 31, py = tid >> 5;
    float acc1[16], acc2[16];
    #pragma unroll
    for (int co = 0; co < 16; ++co) {
        acc1[co] = BIAS ? b1[co] : 0.0f;
        acc2[co] = (DUAL && BIAS) ? b2[co] : 0.0f;
    }

    for (int ci = 0; ci < 32; ++ci) {
        const float* lp = &Ls[ci * 340 + py * 34 + px];
        float vv[9];
        #pragma unroll
        for (int r = 0; r < 3; ++r)
            #pragma unroll
            for (int c = 0; c < 3; ++c)
                vv[r * 3 + c] = lp[r * 34 + c];
        const float* wr1 = wT1 + ci * 144;
        const float* wr2 = DUAL ? (wT2 + ci * 144) : nullptr;
        #pragma unroll
        for (int tp = 0; tp < 9; ++tp) {
            float v = vv[tp];
            #pragma unroll
            for (int co = 0; co < 16; ++co) {
                acc1[co] += v * wr1[tp * 16 + co];
                if constexpr (DUAL) acc2[co] += v * wr2[tp * 16 + co];
            }
        }
    }

    const int h = h0 + py, w = w0 + px;
    size_t ob = (((size_t)b * 16) * 128 + h) * 128 + w;
    #pragma unroll
    for (int co = 0; co < 16; ++co) {
        float v = acc1[co];
        if constexpr (LEAKY) v = (v >= 0.0f) ? v : 0.2f * v;
        o1[ob + (size_t)co * 16384] = v;
        if constexpr (DUAL) o2[ob + (size_t)co * 16384] = acc2[co];
    }
}

// ---------------------------------------------------------------------------
// 1x1 conv, 16ch -> 32ch, pixel-per-thread.
// ---------------------------------------------------------------------------
template<bool BIAS, bool LEAKY, bool RESID>
__global__ __launch_bounds__(256)
void conv1x1p_k(const float* __restrict__ src, const float* __restrict__ wgt,
                const float* __restrict__ bias, const float* __restrict__ resid,
                float* __restrict__ out)
{
    int idx = blockIdx.x * 256 + threadIdx.x;   // 131072 exact (512 blocks)
    int pix = idx & 16383;
    int b   = idx >> 14;
    const float* sb = src + (size_t)b * CI * 16384 + pix;
    float s[16];
    #pragma unroll
    for (int ci = 0; ci < CI; ++ci) s[ci] = sb[ci * 16384];
    size_t ob = (size_t)b * 32 * 16384 + pix;
    #pragma unroll
    for (int co = 0; co < 32; ++co) {
        const float* wrow = wgt + co * CI;
        float acc = BIAS ? bias[co] : 0.0f;
        #pragma unroll
        for (int ci = 0; ci < CI; ++ci) acc += wrow[ci] * s[ci];
        if constexpr (LEAKY) acc = (acc >= 0.0f) ? acc : 0.2f * acc;
        if constexpr (RESID) acc += resid[ob + (size_t)co * 16384];
        out[ob + (size_t)co * 16384] = acc;
    }
}

// ---------------------------------------------------------------------------
// fc GEMM via split-bf16 MFMA (3-term), 64x64 tile, gather-A, prefetched.
// ---------------------------------------------------------------------------
__global__ __launch_bounds__(256)
void fcmfma_k(const float* __restrict__ xsrc,
              const unsigned short* __restrict__ Wh,
              const unsigned short* __restrict__ Wl,
              const float* __restrict__ bias,
              unsigned short* __restrict__ Dh, unsigned short* __restrict__ Dl)
{
    __shared__ unsigned short AsH[64*32], AsL[64*32], BsH[64*32], BsL[64*32];
    const int tid = threadIdx.x;
    const int tm0 = (blockIdx.x >> 2) * 64;     // 121 m-tiles
    const int tn0 = (blockIdx.x & 3) * 64;      // 4 n-tiles

    const int lr = tid >> 2;
    const int lc = tid & 3;
    const int gm = tm0 + lr;
    const bool mok = gm < 7688;
    int gbase = 0;
    if (mok) {
        int b = gm / 961, pi = gm - b * 961;
        int ih = pi / 31, iw = pi - ih * 31;
        gbase = b * 262144 + ih * 512 + iw * 4;
    }
    const int pc = ((lc ^ ((lr >> 1) & 3))) * 8;
    const unsigned short* Whr = Wh + (tn0 + lr) * 800;
    const unsigned short* Wlr = Wl + (tn0 + lr) * 800;

    const int lane = tid & 63, wv = tid >> 6;
    const int wm = (wv >> 1) * 32, wn = (wv & 1) * 32;
    const int fr = lane & 15, kq = lane >> 4;

    floatx4 acc[2][2];
    #pragma unroll
    for (int i = 0; i < 2; ++i)
        #pragma unroll
        for (int j = 0; j < 2; ++j)
            acc[i][j] = (floatx4){0.f, 0.f, 0.f, 0.f};

    float pv[8];
    short8x pwh, pwl;
    auto loadA = [&](int k0) {
        #pragma unroll
        for (int j = 0; j < 8; ++j) {
            int k = k0 + lc * 8 + j;
            float v = 0.0f;
            if (mok && k < 784) {
                int c  = k / 49, r = k - c * 49;
                int kh = r / 7,  kw = r - kh * 7;
                v = xsrc[gbase + c * 16384 + kh * 128 + kw];
            }
            pv[j] = v;
        }
    };
    auto loadW = [&](int k0) {
        pwh = *(const short8x*)(Whr + k0 + lc * 8);
        pwl = *(const short8x*)(Wlr + k0 + lc * 8);
    };

    loadA(0); loadW(0);
    for (int k0 = 0; k0 < 800; k0 += 32) {
        unsigned short hv[8], lv[8];
        #pragma unroll
        for (int j = 0; j < 8; ++j) {
            unsigned short h = f2bf(pv[j]);
            hv[j] = h; lv[j] = f2bf(pv[j] - bf2f(h));
        }
        *(short8x*)&AsH[lr * 32 + pc] = *(short8x*)hv;
        *(short8x*)&AsL[lr * 32 + pc] = *(short8x*)lv;
        *(short8x*)&BsH[lr * 32 + pc] = pwh;
        *(short8x*)&BsL[lr * 32 + pc] = pwl;
        __syncthreads();
        if (k0 + 32 < 800) { loadA(k0 + 32); loadW(k0 + 32); }
        short8x ah[2], al[2], bh[2], bl[2];
        #pragma unroll
        for (int i = 0; i < 2; ++i) {
            int mr = wm + i * 16 + fr;
            int off = mr * 32 + ((kq ^ ((mr >> 1) & 3)) * 8);
            ah[i] = *(const short8x*)&AsH[off];
            al[i] = *(const short8x*)&AsL[off];
        }
        #pragma unroll
        for (int j = 0; j < 2; ++j) {
            int nr = wn + j * 16 + fr;
            int off = nr * 32 + ((kq ^ ((nr >> 1) & 3)) * 8);
            bh[j] = *(const short8x*)&BsH[off];
            bl[j] = *(const short8x*)&BsL[off];
        }
        #pragma unroll
        for (int i = 0; i < 2; ++i)
            #pragma unroll
            for (int j = 0; j < 2; ++j) {
                acc[i][j] = __builtin_amdgcn_mfma_f32_16x16x32_bf16(ah[i], bh[j], acc[i][j], 0, 0, 0);
                acc[i][j] = __builtin_amdgcn_mfma_f32_16x16x32_bf16(ah[i], bl[j], acc[i][j], 0, 0, 0);
                acc[i][j] = __builtin_amdgcn_mfma_f32_16x16x32_bf16(al[i], bh[j], acc[i][j], 0, 0, 0);
            }
        __syncthreads();
    }

    #pragma unroll
    for (int j = 0; j < 2; ++j) {
        int n = tn0 + wn + j * 16 + fr;
        if (n >= FCP) continue;
        float bn = (n < 196) ? bias[n] : 0.0f;
        #pragma unroll
        for (int i = 0; i < 2; ++i) {
            #pragma unroll
            for (int r = 0; r < 4; ++r) {
                int l = tm0 + wm + i * 16 + kq * 4 + r;
                if (l >= 7688) continue;
                int b = l / 961, pi = l - b * 961;
                float v = (n < 196) ? (acc[i][j][r] + bn) : 0.0f;
                long long base = (long long)b * FCB + (long long)pi * FCP + n;
                unsigned short h = f2bf(v);
                Dh[base] = h;
                Dl[base] = f2bf(v - bf2f(h));
            }
        }
    }
}

// ---------------------------------------------------------------------------
// Split-bf16 MFMA GEMM (3-term), 128x128 tile, prefetched K-loop.
// MODE 0 (A):  write A fp32 [l][m] + AT hi/lo bf16 [m][l] via LDS transpose
//              (writes full KP rows incl. zero pad — no pre-zero needed)
// MODE 1 (Ti): ti = acc + Mb[l]; S[l][m] = A[l][m] * sigmoid(ti) * scale
// ---------------------------------------------------------------------------
template<int MODE>
__global__ __launch_bounds__(256)
void mfma3_k(const unsigned short* __restrict__ Xhi,
             const unsigned short* __restrict__ Xlo,
             const unsigned short* __restrict__ Yhi,
             const unsigned short* __restrict__ Ylo,
             int Mrows, int Nrows, int Kd,
             long long sX, long long sY,
             float* __restrict__ Afp,
             unsigned short* __restrict__ AThi,
             unsigned short* __restrict__ ATlo,
             const float* __restrict__ Mb)
{
    __shared__ unsigned short smem[17408];      // staging 16384 / transpose 128x136
    unsigned short* XsH = smem;
    unsigned short* XsL = smem + 4096;
    unsigned short* YsH = smem + 8192;
    unsigned short* YsL = smem + 12288;

    const int b   = blockIdx.x & 7;
    const int t   = blockIdx.x >> 3;
    const int tm0 = (t >> 3) * 128;
    const int tn0 = (t & 7) * 128;
    const unsigned short* Xbh = Xhi + (long long)b * sX;
    const unsigned short* Xbl = Xlo + (long long)b * sX;
    const unsigned short* Ybh = Yhi + (long long)b * sY;
    const unsigned short* Ybl = Ylo + (long long)b * sY;
    const int tid = threadIdx.x;

    const int sr  = tid >> 1;
    const int sc0 = (tid & 1) * 2;
    const bool xok = (tm0 + sr) < Mrows;
    const bool yok = (tn0 + sr) < Nrows;
    const unsigned short* Xrh = Xbh + (long long)(tm0 + sr) * Kd;
    const unsigned short* Xrl = Xbl + (long long)(tm0 + sr) * Kd;
    const unsigned short* Yrh = Ybh + (long long)(tn0 + sr) * Kd;
    const unsigned short* Yrl = Ybl + (long long)(tn0 + sr) * Kd;
    const int swz = (sr >> 1) & 3;

    const int lane = tid & 63;
    const int wv   = tid >> 6;
    const int wm   = (wv >> 1) * 64, wn = (wv & 1) * 64;
    const int fr   = lane & 15;
    const int kq   = lane >> 4;

    floatx4 acc[4][4];
    #pragma unroll
    for (int i = 0; i < 4; ++i)
        #pragma unroll
        for (int j = 0; j < 4; ++j)
            acc[i][j] = (floatx4){0.f, 0.f, 0.f, 0.f};

    const short8x zz = {0,0,0,0,0,0,0,0};
    short8x pxh[2], pxl[2], pyh[2], pyl[2];
    auto loadK = [&](int k0) {
        #pragma unroll
        for (int c = 0; c < 2; ++c) {
            int kc = sc0 + c;
            pxh[c] = xok ? *(const short8x*)(Xrh + k0 + kc * 8) : zz;
            pxl[c] = xok ? *(const short8x*)(Xrl + k0 + kc * 8) : zz;
            pyh[c] = yok ? *(const short8x*)(Yrh + k0 + kc * 8) : zz;
            pyl[c] = yok ? *(const short8x*)(Yrl + k0 + kc * 8) : zz;
        }
    };

    loadK(0);
    for (int k0 = 0; k0 < Kd; k0 += 32) {
        #pragma unroll
        for (int c = 0; c < 2; ++c) {
            int pc = (sc0 + c) ^ swz;
            *(short8x*)&XsH[sr * 32 + pc * 8] = pxh[c];
            *(short8x*)&XsL[sr * 32 + pc * 8] = pxl[c];
            *(short8x*)&YsH[sr * 32 + pc * 8] = pyh[c];
            *(short8x*)&YsL[sr * 32 + pc * 8] = pyl[c];
        }
        __syncthreads();
        if (k0 + 32 < Kd) loadK(k0 + 32);
        short8x bh[4], bl[4];
        #pragma unroll
        for (int j = 0; j < 4; ++j) {
            int nr = wn + j * 16 + fr;
            int off = nr * 32 + ((kq ^ ((nr >> 1) & 3)) * 8);
            bh[j] = *(const short8x*)&YsH[off];
            bl[j] = *(const short8x*)&YsL[off];
        }
        #pragma unroll
        for (int i = 0; i < 4; ++i) {
            int mr = wm + i * 16 + fr;
            int off = mr * 32 + ((kq ^ ((mr >> 1) & 3)) * 8);
            short8x ah = *(const short8x*)&XsH[off];
            short8x al = *(const short8x*)&XsL[off];
            #pragma unroll
            for (int j = 0; j < 4; ++j) {
                acc[i][j] = __builtin_amdgcn_mfma_f32_16x16x32_bf16(ah, bh[j], acc[i][j], 0, 0, 0);
                acc[i][j] = __builtin_amdgcn_mfma_f32_16x16x32_bf16(ah, bl[j], acc[i][j], 0, 0, 0);
                acc[i][j] = __builtin_amdgcn_mfma_f32_16x16x32_bf16(al, bh[j], acc[i][j], 0, 0, 0);
            }
        }
        __syncthreads();
    }

    const float scale = 0.07142857142857142f;   // 196^-0.5
    if constexpr (MODE == 0) {
        // A fp32 [l][m]
        float* Ab = Afp + (long long)b * AB;
        #pragma unroll
        for (int j = 0; j < 4; ++j) {
            int m = tn0 + wn + j * 16 + fr;
            if (m >= 961) continue;
            #pragma unroll
            for (int i = 0; i < 4; ++i) {
                int lb = tm0 + wm + i * 16 + kq * 4;
                if (lb >= 961) continue;
                #pragma unroll
                for (int r = 0; r < 4; ++r) {
                    int l = lb + r;
                    if (l < 961) Ab[(long long)l * 961 + m] = acc[i][j][r];
                }
            }
        }
        // AT hi/lo via LDS transpose (coalesced 128B runs), writes full KP pad
        unsigned short* Th = AThi + (long long)b * ATB;
        unsigned short* Tl = ATlo + (long long)b * ATB;
        const int trow  = tid >> 1;
        const int thalf = tid & 1;
        const int gmT   = tn0 + trow;
        const bool wok  = gmT < 961;
        #pragma unroll
        for (int pass = 0; pass < 2; ++pass) {
            #pragma unroll
            for (int j = 0; j < 4; ++j) {
                int ml = wn + j * 16 + fr;
                #pragma unroll
                for (int i = 0; i < 4; ++i) {
                    int lbase = wm + i * 16 + kq * 4;
                    ushort4x v4;
                    #pragma unroll
                    for (int r = 0; r < 4; ++r) {
                        float v = acc[i][j][r];
                        unsigned short h = f2bf(v);
                        v4[r] = (pass == 0) ? h : f2bf(v - bf2f(h));
                    }
                    *(ushort4x*)&smem[ml * 136 + lbase] = v4;
                }
            }
            __syncthreads();
            if (wok) {
                unsigned short* dst = ((pass == 0) ? Th : Tl)
                                    + (long long)gmT * KP + tm0 + thalf * 64;
                const unsigned short* srcp = &smem[trow * 136 + thalf * 64];
                #pragma unroll
                for (int c = 0; c < 8; ++c) {
                    int l0 = tm0 + thalf * 64 + c * 8;
                    if (l0 < KP)
                        *(short8x*)(dst + c * 8) = *(const short8x*)(srcp + c * 8);
                }
            }
            __syncthreads();
        }
    } else {
        float* Sb = Afp + (long long)b * AB;
        #pragma unroll
        for (int j = 0; j < 4; ++j) {
            int m = tn0 + wn + j * 16 + fr;
            if (m >= 961) continue;
            #pragma unroll
            for (int i = 0; i < 4; ++i) {
                int lb = tm0 + wm + i * 16 + kq * 4;
                #pragma unroll
                for (int r = 0; r < 4; ++r) {
                    int l = lb + r;
                    if (l >= 961) continue;
                    float ti = acc[i][j][r] + Mb[l];
                    float a  = Sb[(long long)l * 961 + m];
                    float mask = 1.0f / (1.0f + expf(-ti));
                    Sb[(long long)l * 961 + m] = a * mask * scale;
                }
            }
        }
    }
}

// ---------------------------------------------------------------------------
// softmax over S rows (961): mb=(s!=0); Am fp32 -> d_out, bf16 (KP rows) -> ws
// ---------------------------------------------------------------------------
__global__ __launch_bounds__(256)
void softmax_mask_k(const float* __restrict__ S, float* __restrict__ Am,
                    unsigned short* __restrict__ Amb)
{
    int row = blockIdx.x;                // b*961 + l
    const float* srow = S + (long long)row * Lp;
    float*       orow = Am + (long long)row * Lp;
    unsigned short* brow = Amb + (long long)row * KP;
    int tid = threadIdx.x;

    float s[4], mb[4];
    float lmax = -INFINITY;
    #pragma unroll
    for (int j = 0; j < 4; ++j) {
        int m = tid + j * 256;
        if (m < Lp) {
            float v = srow[m];
            s[j]  = v;
            mb[j] = (v != 0.0f) ? 1.0f : 0.0f;
            lmax  = fmaxf(lmax, v);
        } else { s[j] = -INFINITY; mb[j] = 0.0f; }
    }
    __shared__ float red[256];
    red[tid] = lmax; __syncthreads();
    #pragma unroll
    for (int off = 128; off > 0; off >>= 1) {
        if (tid < off) red[tid] = fmaxf(red[tid], red[tid + off]);
        __syncthreads();
    }
    float rmax = red[0];
    __syncthreads();

    float e[4];
    float lsum = 0.0f;
    #pragma unroll
    for (int j = 0; j < 4; ++j) {
        int m = tid + j * 256;
        e[j] = (m < Lp) ? expf(s[j] - rmax) : 0.0f;
        lsum += e[j];
    }
    red[tid] = lsum; __syncthreads();
    #pragma unroll
    for (int off = 128; off > 0; off >>= 1) {
        if (tid < off) red[tid] += red[tid + off];
        __syncthreads();
    }
    float inv = 1.0f / red[0];
    #pragma unroll
    for (int j = 0; j < 4; ++j) {
        int m = tid + j * 256;
        if (m < Lp) {
            float v = e[j] * inv * mb[j];
            orow[m] = v;
            brow[m] = f2bf(v);
        } else if (m < KP) {
            brow[m] = 0;
        }
    }
}

// ---------------------------------------------------------------------------
// p62^T bf16: out[b][n][k] = x3[b, c(n), ih(k)*4+kh(n), iw(k)*4+kw(n)], ld KP.
// ---------------------------------------------------------------------------
__global__ __launch_bounds__(256)
void p62bt_k(const float* __restrict__ x3, unsigned short* __restrict__ out)
{
    int idx = blockIdx.x * 256 + threadIdx.x;      // 8*1568*124
    if (idx >= 8 * 1568 * 124) return;
    int ck = idx % 124;
    int t  = idx / 124;
    int n  = t % 1568;
    int b  = t / 1568;
    int c = n / 49, rr = n - c * 49;
    int kh = rr / 7, kw = rr - kh * 7;
    const float* src = x3 + (long long)b * 524288 + c * 16384 + kh * 128 + kw;
    int k = ck * 8;
    unsigned short v[8];
    #pragma unroll
    for (int j = 0; j < 8; ++j) {
        int kk = k + j;
        if (kk < Lp) {
            int ih = kk / 31, iw = kk - ih * 31;
            v[j] = f2bf(src[ih * 512 + iw * 4]);
        } else v[j] = 0;
    }
    *(short8x*)(out + ((long long)b * 1568 + n) * KP + k) = *(short8x*)v;
}

// ---------------------------------------------------------------------------
// y = Am @ p62 via bf16 MFMA, prefetched, writes yT bf16 [b][n][l] (ld YLD).
// ---------------------------------------------------------------------------
__global__ __launch_bounds__(256)
void ymfma_k(const unsigned short* __restrict__ Amb,
             const unsigned short* __restrict__ Pbt,
             unsigned short* __restrict__ yT)
{
    __shared__ unsigned short As[128 * 32];
    __shared__ unsigned short Bs[128 * 32];
    const int b   = blockIdx.x & 7;
    const int t   = blockIdx.x >> 3;            // 104 = 13 n x 8 m
    const int tn0 = (t % 13) * 128;
    const int tm0 = (t / 13) * 128;
    const unsigned short* Ab = Amb + (long long)b * AMBB;
    const unsigned short* Bb = Pbt + (long long)b * PBTB;
    const int tid = threadIdx.x;

    const int sr  = tid >> 1;
    const int sc0 = (tid & 1) * 2;
    const bool aok = (tm0 + sr) < Lp;
    const bool bok = (tn0 + sr) < F62;
    const unsigned short* Arow = Ab + (long long)(tm0 + sr) * KP;
    const unsigned short* Brow = Bb + (long long)(tn0 + sr) * KP;
    const int swz = (sr >> 1) & 3;

    const int lane = tid & 63;
    const int wv   = tid >> 6;
    const int wm   = (wv >> 1) * 64, wn = (wv & 1) * 64;
    const int fr   = lane & 15;
    const int kq   = lane >> 4;

    floatx4 acc[4][4];
    #pragma unroll
    for (int i = 0; i < 4; ++i)
        #pragma unroll
        for (int j = 0; j < 4; ++j)
            acc[i][j] = (floatx4){0.f, 0.f, 0.f, 0.f};

    const short8x zz = {0,0,0,0,0,0,0,0};
    short8x pa[2], pb[2];
    auto loadK = [&](int k0) {
        #pragma unroll
        for (int c = 0; c < 2; ++c) {
            int kc = sc0 + c;
            pa[c] = aok ? *(const short8x*)(Arow + k0 + kc * 8) : zz;
            pb[c] = bok ? *(const short8x*)(Brow + k0 + kc * 8) : zz;
        }
    };

    loadK(0);
    for (int k0 = 0; k0 < Lp; k0 += 32) {
        #pragma unroll
        for (int c = 0; c < 2; ++c) {
            int pc = (sc0 + c) ^ swz;
            *(short8x*)&As[sr * 32 + pc * 8] = pa[c];
            *(short8x*)&Bs[sr * 32 + pc * 8] = pb[c];
        }
        __syncthreads();
        if (k0 + 32 < Lp) loadK(k0 + 32);
        short8x af[4], bfr[4];
        #pragma unroll
        for (int i = 0; i < 4; ++i) {
            int mr = wm + i * 16 + fr;
            af[i] = *(const short8x*)&As[mr * 32 + ((kq ^ ((mr >> 1) & 3)) * 8)];
        }
        #pragma unroll
        for (int j = 0; j < 4; ++j) {
            int nr = wn + j * 16 + fr;
            bfr[j] = *(const short8x*)&Bs[nr * 32 + ((kq ^ ((nr >> 1) & 3)) * 8)];
        }
        #pragma unroll
        for (int i = 0; i < 4; ++i)
            #pragma unroll
            for (int j = 0; j < 4; ++j)
                acc[i][j] = __builtin_amdgcn_mfma_f32_16x16x32_bf16(
                                af[i], bfr[j], acc[i][j], 0, 0, 0);
        __syncthreads();
    }

    unsigned short* Yb = yT + (long long)b * YB;
    #pragma unroll
    for (int j = 0; j < 4; ++j) {
        int n = tn0 + wn + j * 16 + fr;
        if (n >= F62) continue;
        unsigned short* Yr = Yb + (long long)n * YLD;
        #pragma unroll
        for (int i = 0; i < 4; ++i) {
            int lb = tm0 + wm + i * 16 + kq * 4;
            if (lb >= Lp) continue;
            ushort4x hv;
            #pragma unroll
            for (int r = 0; r < 4; ++r) hv[r] = f2bf(acc[i][j][r]);
            if (lb + 3 < Lp) {
                *(ushort4x*)(Yr + lb) = hv;
            } else {
                #pragma unroll
                for (int r = 0; r < 4; ++r)
                    if (lb + r < Lp) Yr[lb + r] = hv[r];
            }
        }
    }
}

// ---------------------------------------------------------------------------
// fold gather from yT bf16 -> (B,32,128,128) image.
// ---------------------------------------------------------------------------
__global__ __launch_bounds__(256)
void foldg_k(const unsigned short* __restrict__ yT, float* __restrict__ out)
{
    int idx = blockIdx.x * 256 + threadIdx.x;   // B*32*16384 exact
    int wc = idx & 127;
    int hr = (idx >> 7) & 127;
    int c  = (idx >> 14) & 31;
    int b  = idx >> 19;
    int ih_lo = (hr >= 6) ? ((hr - 3) >> 2) : 0;
    int ih_hi = min(hr >> 2, 30);
    int iw_lo = (wc >= 6) ? ((wc - 3) >> 2) : 0;
    int iw_hi = min(wc >> 2, 30);
    const unsigned short* Yb = yT + (long long)b * YB + (long long)c * 49 * YLD;
    float acc = 0.0f;
    for (int ih = ih_lo; ih <= ih_hi; ++ih) {
        int kh = hr - 4 * ih;
        for (int iw = iw_lo; iw <= iw_hi; ++iw) {
            int kw = wc - 4 * iw;
            acc += bf2f(Yb[(kh * 7 + kw) * YLD + ih * 31 + iw]);
        }
    }
    out[idx] = acc;
}

// ---------------------------------------------------------------------------
// Launch
// ---------------------------------------------------------------------------
extern "C" void kernel_launch(void* const* d_in, const int* in_sizes, int n_in,
                              void* d_out, int out_size, void* d_ws, size_t ws_size,
                              hipStream_t stream)
{
    const float* x       = (const float*)d_in[0];
    const float* g_w     = (const float*)d_in[1];
    const float* g_b     = (const float*)d_in[2];
    const float* w_w     = (const float*)d_in[3];
    const float* w_b     = (const float*)d_in[4];
    const float* theta_w = (const float*)d_in[5];
    const float* theta_b = (const float*)d_in[6];
    const float* fc1_w   = (const float*)d_in[7];
    const float* fc1_b   = (const float*)d_in[8];
    const float* mconv_w = (const float*)d_in[9];
    const float* mconv_b = (const float*)d_in[10];
    const float* mfc_w   = (const float*)d_in[11];
    const float* mfc_b   = (const float*)d_in[12];
    const float* c1_w    = (const float*)d_in[13];
    const float* c2_w    = (const float*)d_in[14];

    float* Am_out    = (float*)d_out;
    float* final_out = Am_out + (size_t)Bn * Lp * Lp;

    // Workspace (floats), total ~28.03M floats = ~112 MB
    float* ws = (float*)d_ws;
    float* x1    = ws;                        // 2,097,152
    float* x2    = ws + 2097152;              // 2,097,152
    float* x3    = ws + 4194304;              // 4,194,304 (later fold target)
    unsigned short* xf_hi = (unsigned short*)(ws + 8388608);    // 1,722,112 shorts
    unsigned short* xf_lo = (unsigned short*)(ws + 9249664);
    unsigned short* wf_hi = (unsigned short*)(ws + 10110720);
    unsigned short* wf_lo = (unsigned short*)(ws + 10971776);
    float* Abuf  = ws + 11832832;             // 7,388,168 (A -> S -> p62bT alias)
    unsigned short* AT_hi = (unsigned short*)(ws + 19221000);   // 7,626,496 shorts
    unsigned short* AT_lo = (unsigned short*)(ws + 23034248);   // (AT region -> yT later)
    unsigned short* Mw_hi = (unsigned short*)(ws + 26847496);   // 953,312 shorts
    unsigned short* Mw_lo = (unsigned short*)(ws + 27324152);
    float* Mb    = ws + 27800808;             // 1,024
    unsigned short* fc1wh = (unsigned short*)(ws + 27801832);   // 204,800 shorts
    unsigned short* fc1wl = (unsigned short*)(ws + 27904232);   // 204,800 shorts
    float* wT1   = ws + 28006632;             // 4,608
    float* wT2   = ws + 28011240;             // 4,608
    float* wTc   = ws + 28015848;             // 4,608
    unsigned short* Am_bf16 = (unsigned short*)x1;      // aliases x1/x2
    unsigned short* p62bT   = (unsigned short*)Abuf;    // aliases Abuf
    unsigned short* yT      = AT_hi;                    // aliases AT (dead then)

    // merged prep (weights transpose, Mw hi/lo + pad, Mb, fc1_w hi/lo)
    prep_k<<<4582, 256, 0, stream>>>(
        g_w, w_w, c1_w, wT1, wT2, wTc,
        mconv_w, mfc_w, Mw_hi, Mw_lo,
        mconv_b, mfc_b, Mb, fc1_w, fc1wh, fc1wl);

    // x1, x2 = dual 3x3 convs (LDS-tiled)
    conv3x3t_k<true, true, false><<<512, 256, 0, stream>>>(
        x, wT1, g_b, wT2, w_b, x1, x2);

    // x3 = conv1x1(x1)
    conv1x1p_k<true, false, false><<<512, 256, 0, stream>>>(
        x1, theta_w, theta_b, nullptr, x3);

    // xf, wf as bf16 hi/lo via MFMA fc GEMM
    fcmfma_k<<<484, 256, 0, stream>>>(x1, fc1wh, fc1wl, fc1_b, xf_hi, xf_lo);
    fcmfma_k<<<484, 256, 0, stream>>>(x2, fc1wh, fc1wl, fc1_b, wf_hi, wf_lo);

    // A = wf @ xf^T; writes A fp32 + AT hi/lo (incl. pad)
    mfma3_k<0><<<512, 256, 0, stream>>>(
        wf_hi, wf_lo, xf_hi, xf_lo, Lp, Lp, FCP, FCB, FCB,
        Abuf, AT_hi, AT_lo, nullptr);

    // Ti = Mw @ A + Mb; S = A*sigmoid(Ti)*scale in-place over A
    mfma3_k<1><<<512, 256, 0, stream>>>(
        Mw_hi, Mw_lo, AT_hi, AT_lo, Lp, Lp, KP, 0LL, ATB,
        Abuf, nullptr, nullptr, Mb);

    // Am = softmax(S)*(S!=0) -> d_out fp32 + bf16
    softmax_mask_k<<<7688, 256, 0, stream>>>(Abuf, Am_out, Am_bf16);

    // p62^T bf16 (aliases Abuf; S dead)
    p62bt_k<<<6077, 256, 0, stream>>>(x3, p62bT);

    // y = Am @ p62 -> yT bf16 (AT region dead after mfma3<1>)
    ymfma_k<<<832, 256, 0, stream>>>(Am_bf16, p62bT, yT);

    // fold gather yT -> x3
    foldg_k<<<16384, 256, 0, stream>>>(yT, x3);

    // o1 = leaky(conv3x3(refpad(fold)))
    conv3x3t_k<false, false, true><<<512, 256, 0, stream>>>(
        x3, wTc, nullptr, nullptr, nullptr, x1, nullptr);

    // final = x + leaky(conv1x1(o1))
    conv1x1p_k<false, true, true><<<512, 256, 0, stream>>>(
        x1, c2_w, nullptr, x, final_out);
}

// Round 8
// 541.548 us; speedup vs baseline: 3.6562x; 1.0663x over previous
//
#include <hip/hip_runtime.h>
#include <math.h>

namespace {
constexpr int Bn   = 8;
constexpr int CIN  = 32;
constexpr int CI   = 16;
constexpr int Lp   = 961;     // 31*31 patches
constexpr int FIN  = 784;     // 16*49
constexpr int FOUT = 196;
constexpr int F62  = 1568;    // 32*49

constexpr int FCP  = 224;                 // fc K-pad (196 -> 7*32)
constexpr long long FCB = 961LL * FCP;    // wf/xf/W2 per-batch (shorts)
constexpr int KP   = 992;                 // L K-pad (961 -> 31*32)
constexpr long long WFTB = 196LL * KP;    // wfT per-batch (shorts)
constexpr long long AMBB = 961LL * KP;    // Am_bf16 per-batch (shorts)
constexpr long long PBTB = 1568LL * KP;   // p62bT per-batch (shorts)
constexpr long long AB   = 961LL * 961;   // S per-batch (floats)
constexpr int YLD  = 964;                 // yT leading dim (shorts)
constexpr long long YB = 1568LL * YLD;    // yT per-batch (shorts)
}

typedef __attribute__((ext_vector_type(8))) short short8x;
typedef __attribute__((ext_vector_type(4))) float floatx4;
typedef __attribute__((ext_vector_type(4))) unsigned short ushort4x;

static __device__ __forceinline__ unsigned short f2bf(float x) {
    unsigned int u = __builtin_bit_cast(unsigned int, x);
    u += 0x7fffu + ((u >> 16) & 1u);           // RNE
    return (unsigned short)(u >> 16);
}
static __device__ __forceinline__ float bf2f(unsigned short h) {
    return __builtin_bit_cast(float, ((unsigned int)h) << 16);
}

// ---------------------------------------------------------------------------
// Merged prep: conv wT + Mw hi/lo (KP rows) + Mb + fc1_w hi/lo + wfT pad zero
// ---------------------------------------------------------------------------
__global__ __launch_bounds__(256)
void prep_k(const float* __restrict__ g_w, const float* __restrict__ w_w,
            const float* __restrict__ c1_w,
            float* __restrict__ wT1, float* __restrict__ wT2,
            float* __restrict__ wTc,
            const float* __restrict__ mconv_w, const float* __restrict__ mfc_w,
            unsigned short* __restrict__ Mwh, unsigned short* __restrict__ Mwl,
            const float* __restrict__ mconv_b, const float* __restrict__ mfc_b,
            float* __restrict__ Mb,
            const float* __restrict__ fc1w,
            unsigned short* __restrict__ Wh, unsigned short* __restrict__ Wl,
            unsigned short* __restrict__ wfTh, unsigned short* __restrict__ wfTl)
{
    int i = blockIdx.x * 256 + threadIdx.x;
    if (i < 13824) {
        int sel = i / 4608, r = i - sel * 4608;
        int tapidx = r >> 4, co = r & 15;
        const float* w = (sel == 0) ? g_w : (sel == 1) ? w_w : c1_w;
        float* t = (sel == 0) ? wT1 : (sel == 1) ? wT2 : wTc;
        t[r] = w[co * 288 + tapidx];
    } else if (i < 967136) {
        int k = i - 13824;                      // 961*KP
        int n = k / KP, c = k - n * KP;
        float v = (c < 961) ? (mconv_w[n * 961 + c] + mfc_w[n * 961 + c]) : 0.0f;
        unsigned short h = f2bf(v);
        Mwh[k] = h; Mwl[k] = f2bf(v - bf2f(h));
    } else if (i < 968097) {
        int k = i - 967136;
        Mb[k] = mconv_b[k] + mfc_b[k];
    } else if (i < 1172897) {
        int k = i - 968097;                     // 256*800
        int n = k / 800, kk = k - n * 800;
        float v = (n < 196 && kk < 784) ? fc1w[n * 784 + kk] : 0.0f;
        unsigned short h = f2bf(v);
        Wh[k] = h; Wl[k] = f2bf(v - bf2f(h));
    } else if (i < 1223073) {
        int k = i - 1172897;                    // 8*196*32 wfT K-pad cols
        int row = k >> 5, c = k & 31;
        long long pos = (long long)row * KP + 960 + c;
        wfTh[pos] = 0; wfTl[pos] = 0;
    }
}

// ---------------------------------------------------------------------------
// 3x3 conv, reflect-pad(1), 32ch -> 16ch, LDS-tiled.
// ---------------------------------------------------------------------------
template<bool DUAL, bool BIAS, bool LEAKY>
__global__ __launch_bounds__(256)
void conv3x3t_k(const float* __restrict__ x,
                const float* __restrict__ wT1, const float* __restrict__ b1,
                const float* __restrict__ wT2, const float* __restrict__ b2,
                float* __restrict__ o1, float* __restrict__ o2)
{
    __shared__ float Ls[10880];                 // 32ch x 10 x 34
    const int tid = threadIdx.x;
    const int t  = blockIdx.x;                  // 512 = 4w x 16h x 8b
    const int wt = t & 3, ht = (t >> 2) & 15, b = t >> 6;
    const int h0 = ht * 8, w0 = wt * 32;
    const float* xb = x + (size_t)b * CIN * 16384;

    for (int i = tid; i < 10880; i += 256) {
        int ci  = i / 340;
        int rem = i - ci * 340;
        int row = rem / 34;
        int col = rem - row * 34;
        int gh = h0 + row - 1; gh = (gh < 0) ? 1 : (gh > 127 ? 126 : gh);
        int gw = w0 + col - 1; gw = (gw < 0) ? 1 : (gw > 127 ? 126 : gw);
        Ls[i] = xb[ci * 16384 + gh * 128 + gw];
    }
    __syncthreads();

    const int px = tid & 31, py = tid >> 5;
    float acc1[16], acc2[16];
    #pragma unroll
    for (int co = 0; co < 16; ++co) {
        acc1[co] = BIAS ? b1[co] : 0.0f;
        acc2[co] = (DUAL && BIAS) ? b2[co] : 0.0f;
    }

    for (int ci = 0; ci < 32; ++ci) {
        const float* lp = &Ls[ci * 340 + py * 34 + px];
        float vv[9];
        #pragma unroll
        for (int r = 0; r < 3; ++r)
            #pragma unroll
            for (int c = 0; c < 3; ++c)
                vv[r * 3 + c] = lp[r * 34 + c];
        const float* wr1 = wT1 + ci * 144;
        const float* wr2 = DUAL ? (wT2 + ci * 144) : nullptr;
        #pragma unroll
        for (int tp = 0; tp < 9; ++tp) {
            float v = vv[tp];
            #pragma unroll
            for (int co = 0; co < 16; ++co) {
                acc1[co] += v * wr1[tp * 16 + co];
                if constexpr (DUAL) acc2[co] += v * wr2[tp * 16 + co];
            }
        }
    }

    const int h = h0 + py, w = w0 + px;
    size_t ob = (((size_t)b * 16) * 128 + h) * 128 + w;
    #pragma unroll
    for (int co = 0; co < 16; ++co) {
        float v = acc1[co];
        if constexpr (LEAKY) v = (v >= 0.0f) ? v : 0.2f * v;
        o1[ob + (size_t)co * 16384] = v;
        if constexpr (DUAL) o2[ob + (size_t)co * 16384] = acc2[co];
    }
}

// ---------------------------------------------------------------------------
// 1x1 conv, 16ch -> 32ch, pixel-per-thread.
// ---------------------------------------------------------------------------
template<bool BIAS, bool LEAKY, bool RESID>
__global__ __launch_bounds__(256)
void conv1x1p_k(const float* __restrict__ src, const float* __restrict__ wgt,
                const float* __restrict__ bias, const float* __restrict__ resid,
                float* __restrict__ out)
{
    int idx = blockIdx.x * 256 + threadIdx.x;   // 131072 exact (512 blocks)
    int pix = idx & 16383;
    int b   = idx >> 14;
    const float* sb = src + (size_t)b * CI * 16384 + pix;
    float s[16];
    #pragma unroll
    for (int ci = 0; ci < CI; ++ci) s[ci] = sb[ci * 16384];
    size_t ob = (size_t)b * 32 * 16384 + pix;
    #pragma unroll
    for (int co = 0; co < 32; ++co) {
        const float* wrow = wgt + co * CI;
        float acc = BIAS ? bias[co] : 0.0f;
        #pragma unroll
        for (int ci = 0; ci < CI; ++ci) acc += wrow[ci] * s[ci];
        if constexpr (LEAKY) acc = (acc >= 0.0f) ? acc : 0.2f * acc;
        if constexpr (RESID) acc += resid[ob + (size_t)co * 16384];
        out[ob + (size_t)co * 16384] = acc;
    }
}

// ---------------------------------------------------------------------------
// fc GEMM via split-bf16 MFMA (3-term), 64x64 tile, gather-A, prefetched.
// WRT: additionally write D transposed (wfT hi/lo, f-major rows ld KP).
// ---------------------------------------------------------------------------
template<bool WRT>
__global__ __launch_bounds__(256)
void fcmfma_k(const float* __restrict__ xsrc,
              const unsigned short* __restrict__ Wh,
              const unsigned short* __restrict__ Wl,
              const float* __restrict__ bias,
              unsigned short* __restrict__ Dh, unsigned short* __restrict__ Dl,
              unsigned short* __restrict__ DTh, unsigned short* __restrict__ DTl)
{
    __shared__ unsigned short AsH[64*32], AsL[64*32], BsH[64*32], BsL[64*32];
    const int tid = threadIdx.x;
    const int tm0 = (blockIdx.x >> 2) * 64;     // 121 m-tiles
    const int tn0 = (blockIdx.x & 3) * 64;      // 4 n-tiles

    const int lr = tid >> 2;
    const int lc = tid & 3;
    const int gm = tm0 + lr;
    const bool mok = gm < 7688;
    int gbase = 0;
    if (mok) {
        int b = gm / 961, pi = gm - b * 961;
        int ih = pi / 31, iw = pi - ih * 31;
        gbase = b * 262144 + ih * 512 + iw * 4;
    }
    const int pc = ((lc ^ ((lr >> 1) & 3))) * 8;
    const unsigned short* Whr = Wh + (tn0 + lr) * 800;
    const unsigned short* Wlr = Wl + (tn0 + lr) * 800;

    const int lane = tid & 63, wv = tid >> 6;
    const int wm = (wv >> 1) * 32, wn = (wv & 1) * 32;
    const int fr = lane & 15, kq = lane >> 4;

    floatx4 acc[2][2];
    #pragma unroll
    for (int i = 0; i < 2; ++i)
        #pragma unroll
        for (int j = 0; j < 2; ++j)
            acc[i][j] = (floatx4){0.f, 0.f, 0.f, 0.f};

    float pv[8];
    short8x pwh, pwl;
    auto loadA = [&](int k0) {
        #pragma unroll
        for (int j = 0; j < 8; ++j) {
            int k = k0 + lc * 8 + j;
            float v = 0.0f;
            if (mok && k < 784) {
                int c  = k / 49, r = k - c * 49;
                int kh = r / 7,  kw = r - kh * 7;
                v = xsrc[gbase + c * 16384 + kh * 128 + kw];
            }
            pv[j] = v;
        }
    };
    auto loadW = [&](int k0) {
        pwh = *(const short8x*)(Whr + k0 + lc * 8);
        pwl = *(const short8x*)(Wlr + k0 + lc * 8);
    };

    loadA(0); loadW(0);
    for (int k0 = 0; k0 < 800; k0 += 32) {
        unsigned short hv[8], lv[8];
        #pragma unroll
        for (int j = 0; j < 8; ++j) {
            unsigned short h = f2bf(pv[j]);
            hv[j] = h; lv[j] = f2bf(pv[j] - bf2f(h));
        }
        *(short8x*)&AsH[lr * 32 + pc] = *(short8x*)hv;
        *(short8x*)&AsL[lr * 32 + pc] = *(short8x*)lv;
        *(short8x*)&BsH[lr * 32 + pc] = pwh;
        *(short8x*)&BsL[lr * 32 + pc] = pwl;
        __syncthreads();
        if (k0 + 32 < 800) { loadA(k0 + 32); loadW(k0 + 32); }
        short8x ah[2], al[2], bh[2], bl[2];
        #pragma unroll
        for (int i = 0; i < 2; ++i) {
            int mr = wm + i * 16 + fr;
            int off = mr * 32 + ((kq ^ ((mr >> 1) & 3)) * 8);
            ah[i] = *(const short8x*)&AsH[off];
            al[i] = *(const short8x*)&AsL[off];
        }
        #pragma unroll
        for (int j = 0; j < 2; ++j) {
            int nr = wn + j * 16 + fr;
            int off = nr * 32 + ((kq ^ ((nr >> 1) & 3)) * 8);
            bh[j] = *(const short8x*)&BsH[off];
            bl[j] = *(const short8x*)&BsL[off];
        }
        #pragma unroll
        for (int i = 0; i < 2; ++i)
            #pragma unroll
            for (int j = 0; j < 2; ++j) {
                acc[i][j] = __builtin_amdgcn_mfma_f32_16x16x32_bf16(ah[i], bh[j], acc[i][j], 0, 0, 0);
                acc[i][j] = __builtin_amdgcn_mfma_f32_16x16x32_bf16(ah[i], bl[j], acc[i][j], 0, 0, 0);
                acc[i][j] = __builtin_amdgcn_mfma_f32_16x16x32_bf16(al[i], bh[j], acc[i][j], 0, 0, 0);
            }
        __syncthreads();
    }

    #pragma unroll
    for (int j = 0; j < 2; ++j) {
        int n = tn0 + wn + j * 16 + fr;
        if (n >= FCP) continue;
        float bn = (n < 196) ? bias[n] : 0.0f;
        #pragma unroll
        for (int i = 0; i < 2; ++i) {
            #pragma unroll
            for (int r = 0; r < 4; ++r) {
                int l = tm0 + wm + i * 16 + kq * 4 + r;
                if (l >= 7688) continue;
                int b = l / 961, pi = l - b * 961;
                float v = (n < 196) ? (acc[i][j][r] + bn) : 0.0f;
                unsigned short h = f2bf(v);
                unsigned short lo = f2bf(v - bf2f(h));
                long long base = (long long)b * FCB + (long long)pi * FCP + n;
                Dh[base] = h;
                Dl[base] = lo;
                if constexpr (WRT) {
                    if (n < 196) {
                        long long tb = (long long)b * WFTB + (long long)n * KP + pi;
                        DTh[tb] = h;
                        DTl[tb] = lo;
                    }
                }
            }
        }
    }
}

// ---------------------------------------------------------------------------
// W2 = Mw @ wf  (per batch): M=961 (Mw rows, ld KP), N=196 (wfT rows, ld KP),
// K=KP. 3-term split. Writes W2 hi/lo rows (l, f) ld FCP incl. f-pad zeros.
// ---------------------------------------------------------------------------
__global__ __launch_bounds__(256)
void w2mfma_k(const unsigned short* __restrict__ Xhi,
              const unsigned short* __restrict__ Xlo,
              const unsigned short* __restrict__ Yhi,
              const unsigned short* __restrict__ Ylo,
              unsigned short* __restrict__ W2h,
              unsigned short* __restrict__ W2l)
{
    __shared__ unsigned short XsH[4096], XsL[4096], YsH[4096], YsL[4096];
    const int b   = blockIdx.x & 7;
    const int t   = blockIdx.x >> 3;            // 16 = 8 m x 2 n
    const int tm0 = (t >> 1) * 128;
    const int tn0 = (t & 1) * 128;
    const unsigned short* Ybh = Yhi + (long long)b * WFTB;
    const unsigned short* Ybl = Ylo + (long long)b * WFTB;
    const int tid = threadIdx.x;

    const int sr  = tid >> 1;
    const int sc0 = (tid & 1) * 2;
    const bool xok = (tm0 + sr) < 961;
    const bool yok = (tn0 + sr) < 196;
    const unsigned short* Xrh = Xhi + (long long)(tm0 + sr) * KP;
    const unsigned short* Xrl = Xlo + (long long)(tm0 + sr) * KP;
    const unsigned short* Yrh = Ybh + (long long)(tn0 + sr) * KP;
    const unsigned short* Yrl = Ybl + (long long)(tn0 + sr) * KP;
    const int swz = (sr >> 1) & 3;

    const int lane = tid & 63;
    const int wv   = tid >> 6;
    const int wm   = (wv >> 1) * 64, wn = (wv & 1) * 64;
    const int fr   = lane & 15;
    const int kq   = lane >> 4;

    floatx4 acc[4][4];
    #pragma unroll
    for (int i = 0; i < 4; ++i)
        #pragma unroll
        for (int j = 0; j < 4; ++j)
            acc[i][j] = (floatx4){0.f, 0.f, 0.f, 0.f};

    const short8x zz = {0,0,0,0,0,0,0,0};
    short8x pxh[2], pxl[2], pyh[2], pyl[2];
    auto loadK = [&](int k0) {
        #pragma unroll
        for (int c = 0; c < 2; ++c) {
            int kc = sc0 + c;
            pxh[c] = xok ? *(const short8x*)(Xrh + k0 + kc * 8) : zz;
            pxl[c] = xok ? *(const short8x*)(Xrl + k0 + kc * 8) : zz;
            pyh[c] = yok ? *(const short8x*)(Yrh + k0 + kc * 8) : zz;
            pyl[c] = yok ? *(const short8x*)(Yrl + k0 + kc * 8) : zz;
        }
    };

    loadK(0);
    for (int k0 = 0; k0 < KP; k0 += 32) {
        #pragma unroll
        for (int c = 0; c < 2; ++c) {
            int pc = (sc0 + c) ^ swz;
            *(short8x*)&XsH[sr * 32 + pc * 8] = pxh[c];
            *(short8x*)&XsL[sr * 32 + pc * 8] = pxl[c];
            *(short8x*)&YsH[sr * 32 + pc * 8] = pyh[c];
            *(short8x*)&YsL[sr * 32 + pc * 8] = pyl[c];
        }
        __syncthreads();
        if (k0 + 32 < KP) loadK(k0 + 32);
        short8x bh[4], bl[4];
        #pragma unroll
        for (int j = 0; j < 4; ++j) {
            int nr = wn + j * 16 + fr;
            int off = nr * 32 + ((kq ^ ((nr >> 1) & 3)) * 8);
            bh[j] = *(const short8x*)&YsH[off];
            bl[j] = *(const short8x*)&YsL[off];
        }
        #pragma unroll
        for (int i = 0; i < 4; ++i) {
            int mr = wm + i * 16 + fr;
            int off = mr * 32 + ((kq ^ ((mr >> 1) & 3)) * 8);
            short8x ah = *(const short8x*)&XsH[off];
            short8x al = *(const short8x*)&XsL[off];
            #pragma unroll
            for (int j = 0; j < 4; ++j) {
                acc[i][j] = __builtin_amdgcn_mfma_f32_16x16x32_bf16(ah, bh[j], acc[i][j], 0, 0, 0);
                acc[i][j] = __builtin_amdgcn_mfma_f32_16x16x32_bf16(ah, bl[j], acc[i][j], 0, 0, 0);
                acc[i][j] = __builtin_amdgcn_mfma_f32_16x16x32_bf16(al, bh[j], acc[i][j], 0, 0, 0);
            }
        }
        __syncthreads();
    }

    unsigned short* Wh2 = W2h + (long long)b * FCB;
    unsigned short* Wl2 = W2l + (long long)b * FCB;
    #pragma unroll
    for (int j = 0; j < 4; ++j) {
        int f = tn0 + wn + j * 16 + fr;
        if (f >= FCP) continue;
        #pragma unroll
        for (int i = 0; i < 4; ++i) {
            int lb = tm0 + wm + i * 16 + kq * 4;
            #pragma unroll
            for (int r = 0; r < 4; ++r) {
                int l = lb + r;
                if (l >= 961) continue;
                float v = acc[i][j][r];
                unsigned short h = f2bf(v);
                long long pos = (long long)l * FCP + f;
                Wh2[pos] = h;
                Wl2[pos] = f2bf(v - bf2f(h));
            }
        }
    }
}

// ---------------------------------------------------------------------------
// Fused A+Ti+S: A = wf@xf^T, Ti = W2@xf^T + Mb[l],
// S[l][m] = A * sigmoid(Ti) * scale. K=FCP (7 iters), two acc sets.
// ---------------------------------------------------------------------------
__global__ __launch_bounds__(256)
void atimfma_k(const unsigned short* __restrict__ Wfh,
               const unsigned short* __restrict__ Wfl,
               const unsigned short* __restrict__ W2h,
               const unsigned short* __restrict__ W2l,
               const unsigned short* __restrict__ Xfh,
               const unsigned short* __restrict__ Xfl,
               const float* __restrict__ Mb,
               float* __restrict__ Sout)
{
    __shared__ unsigned short smem[24576];      // 6 x 4096
    unsigned short* X1H = smem;
    unsigned short* X1L = smem + 4096;
    unsigned short* X2H = smem + 8192;
    unsigned short* X2L = smem + 12288;
    unsigned short* YH  = smem + 16384;
    unsigned short* YL  = smem + 20480;

    const int b   = blockIdx.x & 7;
    const int t   = blockIdx.x >> 3;            // 64 = 8 m x 8 n
    const int tm0 = (t >> 3) * 128;             // l
    const int tn0 = (t & 7) * 128;              // m
    const int tid = threadIdx.x;

    const int sr  = tid >> 1;
    const int sc0 = (tid & 1) * 2;
    const bool xok = (tm0 + sr) < 961;
    const bool yok = (tn0 + sr) < 961;
    const unsigned short* X1rh = Wfh + (long long)b * FCB + (long long)(tm0 + sr) * FCP;
    const unsigned short* X1rl = Wfl + (long long)b * FCB + (long long)(tm0 + sr) * FCP;
    const unsigned short* X2rh = W2h + (long long)b * FCB + (long long)(tm0 + sr) * FCP;
    const unsigned short* X2rl = W2l + (long long)b * FCB + (long long)(tm0 + sr) * FCP;
    const unsigned short* Yrh  = Xfh + (long long)b * FCB + (long long)(tn0 + sr) * FCP;
    const unsigned short* Yrl  = Xfl + (long long)b * FCB + (long long)(tn0 + sr) * FCP;
    const int swz = (sr >> 1) & 3;

    const int lane = tid & 63;
    const int wv   = tid >> 6;
    const int wm   = (wv >> 1) * 64, wn = (wv & 1) * 64;
    const int fr   = lane & 15;
    const int kq   = lane >> 4;

    floatx4 accA[4][4], accT[4][4];
    #pragma unroll
    for (int i = 0; i < 4; ++i)
        #pragma unroll
        for (int j = 0; j < 4; ++j) {
            accA[i][j] = (floatx4){0.f, 0.f, 0.f, 0.f};
            accT[i][j] = (floatx4){0.f, 0.f, 0.f, 0.f};
        }

    const short8x zz = {0,0,0,0,0,0,0,0};
    short8x p1h[2], p1l[2], p2h[2], p2l[2], pyh[2], pyl[2];
    auto loadK = [&](int k0) {
        #pragma unroll
        for (int c = 0; c < 2; ++c) {
            int kc = sc0 + c;
            p1h[c] = xok ? *(const short8x*)(X1rh + k0 + kc * 8) : zz;
            p1l[c] = xok ? *(const short8x*)(X1rl + k0 + kc * 8) : zz;
            p2h[c] = xok ? *(const short8x*)(X2rh + k0 + kc * 8) : zz;
            p2l[c] = xok ? *(const short8x*)(X2rl + k0 + kc * 8) : zz;
            pyh[c] = yok ? *(const short8x*)(Yrh  + k0 + kc * 8) : zz;
            pyl[c] = yok ? *(const short8x*)(Yrl  + k0 + kc * 8) : zz;
        }
    };

    loadK(0);
    for (int k0 = 0; k0 < FCP; k0 += 32) {
        #pragma unroll
        for (int c = 0; c < 2; ++c) {
            int pc = (sc0 + c) ^ swz;
            *(short8x*)&X1H[sr * 32 + pc * 8] = p1h[c];
            *(short8x*)&X1L[sr * 32 + pc * 8] = p1l[c];
            *(short8x*)&X2H[sr * 32 + pc * 8] = p2h[c];
            *(short8x*)&X2L[sr * 32 + pc * 8] = p2l[c];
            *(short8x*)&YH[sr * 32 + pc * 8]  = pyh[c];
            *(short8x*)&YL[sr * 32 + pc * 8]  = pyl[c];
        }
        __syncthreads();
        if (k0 + 32 < FCP) loadK(k0 + 32);
        short8x bh[4], bl[4];
        #pragma unroll
        for (int j = 0; j < 4; ++j) {
            int nr = wn + j * 16 + fr;
            int off = nr * 32 + ((kq ^ ((nr >> 1) & 3)) * 8);
            bh[j] = *(const short8x*)&YH[off];
            bl[j] = *(const short8x*)&YL[off];
        }
        #pragma unroll
        for (int i = 0; i < 4; ++i) {
            int mr = wm + i * 16 + fr;
            int off = mr * 32 + ((kq ^ ((mr >> 1) & 3)) * 8);
            short8x a1h = *(const short8x*)&X1H[off];
            short8x a1l = *(const short8x*)&X1L[off];
            short8x a2h = *(const short8x*)&X2H[off];
            short8x a2l = *(const short8x*)&X2L[off];
            #pragma unroll
            for (int j = 0; j < 4; ++j) {
                accA[i][j] = __builtin_amdgcn_mfma_f32_16x16x32_bf16(a1h, bh[j], accA[i][j], 0, 0, 0);
                accA[i][j] = __builtin_amdgcn_mfma_f32_16x16x32_bf16(a1h, bl[j], accA[i][j], 0, 0, 0);
                accA[i][j] = __builtin_amdgcn_mfma_f32_16x16x32_bf16(a1l, bh[j], accA[i][j], 0, 0, 0);
                accT[i][j] = __builtin_amdgcn_mfma_f32_16x16x32_bf16(a2h, bh[j], accT[i][j], 0, 0, 0);
                accT[i][j] = __builtin_amdgcn_mfma_f32_16x16x32_bf16(a2h, bl[j], accT[i][j], 0, 0, 0);
                accT[i][j] = __builtin_amdgcn_mfma_f32_16x16x32_bf16(a2l, bh[j], accT[i][j], 0, 0, 0);
            }
        }
        __syncthreads();
    }

    const float scale = 0.07142857142857142f;   // 196^-0.5
    float* Sb = Sout + (long long)b * AB;
    #pragma unroll
    for (int j = 0; j < 4; ++j) {
        int m = tn0 + wn + j * 16 + fr;
        if (m >= 961) continue;
        #pragma unroll
        for (int i = 0; i < 4; ++i) {
            int lb = tm0 + wm + i * 16 + kq * 4;
            #pragma unroll
            for (int r = 0; r < 4; ++r) {
                int l = lb + r;
                if (l >= 961) continue;
                float ti = accT[i][j][r] + Mb[l];
                float mask = 1.0f / (1.0f + expf(-ti));
                Sb[(long long)l * 961 + m] = accA[i][j][r] * mask * scale;
            }
        }
    }
}

// ---------------------------------------------------------------------------
// softmax over S rows (961): mb=(s!=0); Am fp32 -> d_out, bf16 (KP rows) -> ws
// ---------------------------------------------------------------------------
__global__ __launch_bounds__(256)
void softmax_mask_k(const float* __restrict__ S, float* __restrict__ Am,
                    unsigned short* __restrict__ Amb)
{
    int row = blockIdx.x;                // b*961 + l
    const float* srow = S + (long long)row * Lp;
    float*       orow = Am + (long long)row * Lp;
    unsigned short* brow = Amb + (long long)row * KP;
    int tid = threadIdx.x;

    float s[4], mb[4];
    float lmax = -INFINITY;
    #pragma unroll
    for (int j = 0; j < 4; ++j) {
        int m = tid + j * 256;
        if (m < Lp) {
            float v = srow[m];
            s[j]  = v;
            mb[j] = (v != 0.0f) ? 1.0f : 0.0f;
            lmax  = fmaxf(lmax, v);
        } else { s[j] = -INFINITY; mb[j] = 0.0f; }
    }
    __shared__ float red[256];
    red[tid] = lmax; __syncthreads();
    #pragma unroll
    for (int off = 128; off > 0; off >>= 1) {
        if (tid < off) red[tid] = fmaxf(red[tid], red[tid + off]);
        __syncthreads();
    }
    float rmax = red[0];
    __syncthreads();

    float e[4];
    float lsum = 0.0f;
    #pragma unroll
    for (int j = 0; j < 4; ++j) {
        int m = tid + j * 256;
        e[j] = (m < Lp) ? expf(s[j] - rmax) : 0.0f;
        lsum += e[j];
    }
    red[tid] = lsum; __syncthreads();
    #pragma unroll
    for (int off = 128; off > 0; off >>= 1) {
        if (tid < off) red[tid] += red[tid + off];
        __syncthreads();
    }
    float inv = 1.0f / red[0];
    #pragma unroll
    for (int j = 0; j < 4; ++j) {
        int m = tid + j * 256;
        if (m < Lp) {
            float v = e[j] * inv * mb[j];
            orow[m] = v;
            brow[m] = f2bf(v);
        } else if (m < KP) {
            brow[m] = 0;
        }
    }
}

// ---------------------------------------------------------------------------
// p62^T bf16: out[b][n][k] = x3[b, c(n), ih(k)*4+kh(n), iw(k)*4+kw(n)], ld KP.
// ---------------------------------------------------------------------------
__global__ __launch_bounds__(256)
void p62bt_k(const float* __restrict__ x3, unsigned short* __restrict__ out)
{
    int idx = blockIdx.x * 256 + threadIdx.x;      // 8*1568*124
    if (idx >= 8 * 1568 * 124) return;
    int ck = idx % 124;
    int t  = idx / 124;
    int n  = t % 1568;
    int b  = t / 1568;
    int c = n / 49, rr = n - c * 49;
    int kh = rr / 7, kw = rr - kh * 7;
    const float* src = x3 + (long long)b * 524288 + c * 16384 + kh * 128 + kw;
    int k = ck * 8;
    unsigned short v[8];
    #pragma unroll
    for (int j = 0; j < 8; ++j) {
        int kk = k + j;
        if (kk < Lp) {
            int ih = kk / 31, iw = kk - ih * 31;
            v[j] = f2bf(src[ih * 512 + iw * 4]);
        } else v[j] = 0;
    }
    *(short8x*)(out + ((long long)b * 1568 + n) * KP + k) = *(short8x*)v;
}

// ---------------------------------------------------------------------------
// y = Am @ p62 via bf16 MFMA, prefetched, writes yT bf16 [b][n][l] (ld YLD).
// ---------------------------------------------------------------------------
__global__ __launch_bounds__(256)
void ymfma_k(const unsigned short* __restrict__ Amb,
             const unsigned short* __restrict__ Pbt,
             unsigned short* __restrict__ yT)
{
    __shared__ unsigned short As[128 * 32];
    __shared__ unsigned short Bs[128 * 32];
    const int b   = blockIdx.x & 7;
    const int t   = blockIdx.x >> 3;            // 104 = 13 n x 8 m
    const int tn0 = (t % 13) * 128;
    const int tm0 = (t / 13) * 128;
    const unsigned short* Ab = Amb + (long long)b * AMBB;
    const unsigned short* Bb = Pbt + (long long)b * PBTB;
    const int tid = threadIdx.x;

    const int sr  = tid >> 1;
    const int sc0 = (tid & 1) * 2;
    const bool aok = (tm0 + sr) < Lp;
    const bool bok = (tn0 + sr) < F62;
    const unsigned short* Arow = Ab + (long long)(tm0 + sr) * KP;
    const unsigned short* Brow = Bb + (long long)(tn0 + sr) * KP;
    const int swz = (sr >> 1) & 3;

    const int lane = tid & 63;
    const int wv   = tid >> 6;
    const int wm   = (wv >> 1) * 64, wn = (wv & 1) * 64;
    const int fr   = lane & 15;
    const int kq   = lane >> 4;

    floatx4 acc[4][4];
    #pragma unroll
    for (int i = 0; i < 4; ++i)
        #pragma unroll
        for (int j = 0; j < 4; ++j)
            acc[i][j] = (floatx4){0.f, 0.f, 0.f, 0.f};

    const short8x zz = {0,0,0,0,0,0,0,0};
    short8x pa[2], pb[2];
    auto loadK = [&](int k0) {
        #pragma unroll
        for (int c = 0; c < 2; ++c) {
            int kc = sc0 + c;
            pa[c] = aok ? *(const short8x*)(Arow + k0 + kc * 8) : zz;
            pb[c] = bok ? *(const short8x*)(Brow + k0 + kc * 8) : zz;
        }
    };

    loadK(0);
    for (int k0 = 0; k0 < Lp; k0 += 32) {
        #pragma unroll
        for (int c = 0; c < 2; ++c) {
            int pc = (sc0 + c) ^ swz;
            *(short8x*)&As[sr * 32 + pc * 8] = pa[c];
            *(short8x*)&Bs[sr * 32 + pc * 8] = pb[c];
        }
        __syncthreads();
        if (k0 + 32 < Lp) loadK(k0 + 32);
        short8x af[4], bfr[4];
        #pragma unroll
        for (int i = 0; i < 4; ++i) {
            int mr = wm + i * 16 + fr;
            af[i] = *(const short8x*)&As[mr * 32 + ((kq ^ ((mr >> 1) & 3)) * 8)];
        }
        #pragma unroll
        for (int j = 0; j < 4; ++j) {
            int nr = wn + j * 16 + fr;
            bfr[j] = *(const short8x*)&Bs[nr * 32 + ((kq ^ ((nr >> 1) & 3)) * 8)];
        }
        #pragma unroll
        for (int i = 0; i < 4; ++i)
            #pragma unroll
            for (int j = 0; j < 4; ++j)
                acc[i][j] = __builtin_amdgcn_mfma_f32_16x16x32_bf16(
                                af[i], bfr[j], acc[i][j], 0, 0, 0);
        __syncthreads();
    }

    unsigned short* Yb = yT + (long long)b * YB;
    #pragma unroll
    for (int j = 0; j < 4; ++j) {
        int n = tn0 + wn + j * 16 + fr;
        if (n >= F62) continue;
        unsigned short* Yr = Yb + (long long)n * YLD;
        #pragma unroll
        for (int i = 0; i < 4; ++i) {
            int lb = tm0 + wm + i * 16 + kq * 4;
            if (lb >= Lp) continue;
            ushort4x hv;
            #pragma unroll
            for (int r = 0; r < 4; ++r) hv[r] = f2bf(acc[i][j][r]);
            if (lb + 3 < Lp) {
                *(ushort4x*)(Yr + lb) = hv;
            } else {
                #pragma unroll
                for (int r = 0; r < 4; ++r)
                    if (lb + r < Lp) Yr[lb + r] = hv[r];
            }
        }
    }
}

// ---------------------------------------------------------------------------
// fold gather from yT bf16 -> (B,32,128,128) image.
// ---------------------------------------------------------------------------
__global__ __launch_bounds__(256)
void foldg_k(const unsigned short* __restrict__ yT, float* __restrict__ out)
{
    int idx = blockIdx.x * 256 + threadIdx.x;   // B*32*16384 exact
    int wc = idx & 127;
    int hr = (idx >> 7) & 127;
    int c  = (idx >> 14) & 31;
    int b  = idx >> 19;
    int ih_lo = (hr >= 6) ? ((hr - 3) >> 2) : 0;
    int ih_hi = min(hr >> 2, 30);
    int iw_lo = (wc >= 6) ? ((wc - 3) >> 2) : 0;
    int iw_hi = min(wc >> 2, 30);
    const unsigned short* Yb = yT + (long long)b * YB + (long long)c * 49 * YLD;
    float acc = 0.0f;
    for (int ih = ih_lo; ih <= ih_hi; ++ih) {
        int kh = hr - 4 * ih;
        for (int iw = iw_lo; iw <= iw_hi; ++iw) {
            int kw = wc - 4 * iw;
            acc += bf2f(Yb[(kh * 7 + kw) * YLD + ih * 31 + iw]);
        }
    }
    out[idx] = acc;
}

// ---------------------------------------------------------------------------
// Launch
// ---------------------------------------------------------------------------
extern "C" void kernel_launch(void* const* d_in, const int* in_sizes, int n_in,
                              void* d_out, int out_size, void* d_ws, size_t ws_size,
                              hipStream_t stream)
{
    const float* x       = (const float*)d_in[0];
    const float* g_w     = (const float*)d_in[1];
    const float* g_b     = (const float*)d_in[2];
    const float* w_w     = (const float*)d_in[3];
    const float* w_b     = (const float*)d_in[4];
    const float* theta_w = (const float*)d_in[5];
    const float* theta_b = (const float*)d_in[6];
    const float* fc1_w   = (const float*)d_in[7];
    const float* fc1_b   = (const float*)d_in[8];
    const float* mconv_w = (const float*)d_in[9];
    const float* mconv_b = (const float*)d_in[10];
    const float* mfc_w   = (const float*)d_in[11];
    const float* mfc_b   = (const float*)d_in[12];
    const float* c1_w    = (const float*)d_in[13];
    const float* c2_w    = (const float*)d_in[14];

    float* Am_out    = (float*)d_out;
    float* final_out = Am_out + (size_t)Bn * Lp * Lp;

    // Workspace (floats), ~112 MB
    float* ws = (float*)d_ws;
    float* x1    = ws;                        // 2,097,152
    float* x2    = ws + 2097152;              // 2,097,152
    float* x3    = ws + 4194304;              // 4,194,304 (later fold target)
    unsigned short* xf_hi = (unsigned short*)(ws + 8388608);    // 1,722,112 shorts
    unsigned short* xf_lo = (unsigned short*)(ws + 9249664);
    unsigned short* wf_hi = (unsigned short*)(ws + 10110720);
    unsigned short* wf_lo = (unsigned short*)(ws + 10971776);
    float* Abuf  = ws + 11832832;             // 7,388,168 (S -> p62bT alias)
    unsigned short* wfT_hi = (unsigned short*)(ws + 19221000); // 1,555,456 shorts
    unsigned short* wfT_lo = (unsigned short*)(ws + 19998728);
    unsigned short* W2_hi  = (unsigned short*)(ws + 20776456); // 1,722,112 shorts
    unsigned short* W2_lo  = (unsigned short*)(ws + 21637512);
    unsigned short* Mw_hi = (unsigned short*)(ws + 26847496);  // 953,312 shorts
    unsigned short* Mw_lo = (unsigned short*)(ws + 27324152);
    float* Mb    = ws + 27800808;             // 1,024
    unsigned short* fc1wh = (unsigned short*)(ws + 27801832);  // 204,800 shorts
    unsigned short* fc1wl = (unsigned short*)(ws + 27904232);  // 204,800 shorts
    float* wT1   = ws + 28006632;             // 4,608
    float* wT2   = ws + 28011240;             // 4,608
    float* wTc   = ws + 28015848;             // 4,608
    unsigned short* Am_bf16 = (unsigned short*)x1;   // aliases x1/x2
    unsigned short* p62bT   = (unsigned short*)Abuf; // aliases Abuf (S dead)
    unsigned short* yT      = wfT_hi;                // aliases wfT/W2 (dead)

    // merged prep
    prep_k<<<4778, 256, 0, stream>>>(
        g_w, w_w, c1_w, wT1, wT2, wTc,
        mconv_w, mfc_w, Mw_hi, Mw_lo,
        mconv_b, mfc_b, Mb, fc1_w, fc1wh, fc1wl,
        wfT_hi, wfT_lo);

    // x1, x2 = dual 3x3 convs (LDS-tiled)
    conv3x3t_k<true, true, false><<<512, 256, 0, stream>>>(
        x, wT1, g_b, wT2, w_b, x1, x2);

    // x3 = conv1x1(x1)
    conv1x1p_k<true, false, false><<<512, 256, 0, stream>>>(
        x1, theta_w, theta_b, nullptr, x3);

    // xf (rows), wf (rows + transposed) as bf16 hi/lo
    fcmfma_k<false><<<484, 256, 0, stream>>>(
        x1, fc1wh, fc1wl, fc1_b, xf_hi, xf_lo, nullptr, nullptr);
    fcmfma_k<true><<<484, 256, 0, stream>>>(
        x2, fc1wh, fc1wl, fc1_b, wf_hi, wf_lo, wfT_hi, wfT_lo);

    // W2 = Mw @ wf (assoc. trick: Ti = (Mw@wf)@xf^T)
    w2mfma_k<<<128, 256, 0, stream>>>(
        Mw_hi, Mw_lo, wfT_hi, wfT_lo, W2_hi, W2_lo);

    // Fused: A = wf@xf^T, Ti = W2@xf^T + Mb, S = A*sigmoid(Ti)*scale
    atimfma_k<<<512, 256, 0, stream>>>(
        wf_hi, wf_lo, W2_hi, W2_lo, xf_hi, xf_lo, Mb, Abuf);

    // Am = softmax(S)*(S!=0) -> d_out fp32 + bf16
    softmax_mask_k<<<7688, 256, 0, stream>>>(Abuf, Am_out, Am_bf16);

    // p62^T bf16 (aliases Abuf; S dead)
    p62bt_k<<<6077, 256, 0, stream>>>(x3, p62bT);

    // y = Am @ p62 -> yT bf16 (wfT/W2 region dead)
    ymfma_k<<<832, 256, 0, stream>>>(Am_bf16, p62bT, yT);

    // fold gather yT -> x3
    foldg_k<<<16384, 256, 0, stream>>>(yT, x3);

    // o1 = leaky(conv3x3(refpad(fold)))
    conv3x3t_k<false, false, true><<<512, 256, 0, stream>>>(
        x3, wTc, nullptr, nullptr, nullptr, x1, nullptr);

    // final = x + leaky(conv1x1(o1))
    conv1x1p_k<false, true, true><<<512, 256, 0, stream>>>(
        x1, c2_w, nullptr, x, final_out);
}